// Round 17
// baseline (1029.629 us; speedup 1.0000x reference)
//
#include <hip/hip_runtime.h>
#include <hip/hip_bf16.h>

#define DIMC   128
#define HEADS  8
#define BATCH  8
#define XLEN   4096
#define NHEAD  64
#define EPSV   1e-5f
#define SCALEF 0.08838834764831845f   // 128^-0.5
#define TX     64
#define KSPL   8                       // kat x-splits per b

typedef __attribute__((ext_vector_type(8))) short bf16x8;
typedef __attribute__((ext_vector_type(4))) float f32x4;
#define MFMA(a,b,c) __builtin_amdgcn_mfma_f32_16x16x32_bf16((a),(b),(c),0,0,0)
// weight B-frag load from GLOBAL table laid out [(kt*8+nt)][lane][8]
#define LDW(tbl, kt, nt) (*(const bf16x8*)&(tbl)[(((kt) * 8 + (nt)) * 64 + l) * 8])

__device__ __forceinline__ short f2bf(float f) {
  union { float f; unsigned u; } v; v.f = f;
  return (short)((v.u + 0x7fffu + ((v.u >> 16) & 1u)) >> 16);
}
__device__ __forceinline__ float bf2f(short h) {
  union { unsigned u; float f; } v; v.u = ((unsigned)(unsigned short)h) << 16;
  return v.f;
}
__device__ __forceinline__ unsigned pk2(float a, float b) {
  return (unsigned)(unsigned short)f2bf(a) | ((unsigned)(unsigned short)f2bf(b) << 16);
}

// LDS fragment loads. Row-major bf16 tiles, XOR-swizzled: byte ^= (row&7)<<4.
// ldY: row stride 256 B; ldT: row stride 128 B.
__device__ __forceinline__ bf16x8 ldY(const short* Y, int row, int kcb) {
  return *(const bf16x8*)((const char*)Y + row*256 + (kcb ^ ((row&7)<<4)));
}
__device__ __forceinline__ bf16x8 ldT(const short* Y, int row, int kcb) {
  return *(const bf16x8*)((const char*)Y + row*128 + (kcb ^ ((row&7)<<4)));
}

// ---------------------------------------------------------------------------
// prep kernels (3 launches) — unchanged from round 11
// ---------------------------------------------------------------------------
__global__ void k_prep1(const float* dw0, const float* g0, const float* b0, const float* m0, const float* v0,
                        const float* dw1, const float* g1, const float* b1, const float* m1, const float* v1,
                        const float* dw2, const float* g2, const float* b2, const float* m2, const float* v2,
                        const float* gt_pw, const float* gt_dw, const float* gt_g,
                        const float* gt_b, const float* gt_m, const float* gt_v,
                        float* __restrict__ dwf, float* __restrict__ bfl,
                        float* __restrict__ Gt, float* __restrict__ c0) {
  int p = blockIdx.x, c = threadIdx.x;
  if (p < 3) {
    const float* dw = p == 0 ? dw0 : p == 1 ? dw1 : dw2;
    const float* g  = p == 0 ? g0  : p == 1 ? g1  : g2;
    const float* bb = p == 0 ? b0  : p == 1 ? b1  : b2;
    const float* m  = p == 0 ? m0  : p == 1 ? m1  : m2;
    const float* vv = p == 0 ? v0  : p == 1 ? v1  : v2;
    float a = g[c] * rsqrtf(vv[c] + EPSV);
    dwf[(p * DIMC + c) * 3 + 0] = dw[c * 3 + 0] * a;
    dwf[(p * DIMC + c) * 3 + 1] = dw[c * 3 + 1] * a;
    dwf[(p * DIMC + c) * 3 + 2] = dw[c * 3 + 2] * a;
    bfl[p * DIMC + c] = bb[c] - m[c] * a;
  } else {
    int d = c;
    float s = 0.f;
    for (int i = 0; i < DIMC; ++i) {
      float a  = gt_g[i] * rsqrtf(gt_v[i] + EPSV);
      float w1 = gt_dw[i] * a;
      float w0 = gt_b[i] - gt_m[i] * a;
      float pw = gt_pw[d * DIMC + i];
      Gt[i * DIMC + d] = pw * w1;
      s += pw * w0;
    }
    c0[d] = s;
  }
}

__global__ void k_wg(const float* __restrict__ q_pw, const float* __restrict__ Gt,
                     float* __restrict__ WgF) {
  const int h = blockIdx.x, cb = blockIdx.y, t = threadIdx.x;
  const int c = cb * 16 + (t >> 4);
  const int e0 = (t & 15) * 8;
  float acc[8] = {0.f,0.f,0.f,0.f,0.f,0.f,0.f,0.f};
  for (int d = 0; d < DIMC; ++d) {
    float wq = q_pw[((size_t)(h * DIMC + d)) * DIMC + c];
    const float* gr = Gt + d * DIMC + e0;
    #pragma unroll
    for (int j = 0; j < 8; ++j) acc[j] += wq * gr[j];
  }
  float* out = WgF + ((size_t)h * DIMC + c) * DIMC + e0;
  #pragma unroll
  for (int j = 0; j < 8; ++j) out[j] = acc[j];
}

__global__ void k_pack(const float* __restrict__ q_pw, const float* __restrict__ k_pw,
                       const float* __restrict__ v_pw, const float* __restrict__ out_w,
                       const float* __restrict__ WgF,
                       short* __restrict__ Wpk, short* __restrict__ Opk,
                       short* __restrict__ Gpk) {
  const int blk = blockIdx.x, t = threadIdx.x;
  if (blk < 48) {
    const int p = blk / 16, h = (blk / 2) & 7, hl = blk & 1;
    const float* pw = p == 0 ? q_pw : p == 1 ? k_pw : v_pw;
    short* dst = Wpk + (size_t)((p * 8 + h) * 2 + hl) * 16384;
    for (int s = t; s < 2048; s += 256) {
      const int l = s & 63, kt = (s >> 6) >> 3, nt = (s >> 6) & 7;
      const int o = h * DIMC + nt * 16 + (l & 15);
      const int cb = kt * 32 + (l >> 4) * 8;
      #pragma unroll
      for (int j = 0; j < 8; ++j) {
        float wv = pw[(size_t)o * DIMC + cb + j];
        short hi = f2bf(wv);
        dst[s * 8 + j] = (hl == 0) ? hi : f2bf(wv - bf2f(hi));
      }
    }
  } else if (blk < 64) {
    const int m = blk - 48, h = m >> 1, hl = m & 1;
    short* dst = Opk + (size_t)(h * 2 + hl) * 16384;
    for (int s = t; s < 2048; s += 256) {
      const int l = s & 63, mt = (s >> 6) >> 2, kt = (s >> 6) & 3;
      const int o = mt * 16 + (l & 15);
      const int ib = h * DIMC + kt * 32 + (l >> 4) * 8;
      #pragma unroll
      for (int j = 0; j < 8; ++j) {
        float wv = out_w[(size_t)o * (DIMC * HEADS) + ib + j];
        short hi = f2bf(wv);
        dst[s * 8 + j] = (hl == 0) ? hi : f2bf(wv - bf2f(hi));
      }
    }
  } else {
    const int h = blk - 64;
    const float* src = WgF + (size_t)h * 16384;
    short* dst = Gpk + (size_t)h * 16384;
    for (int s = t; s < 2048; s += 256) {
      const int l = s & 63, kt = (s >> 6) >> 3, nt = (s >> 6) & 7;
      const int cb = kt * 32 + (l >> 4) * 8, e = nt * 16 + (l & 15);
      #pragma unroll
      for (int j = 0; j < 8; ++j) dst[s * 8 + j] = f2bf(src[(size_t)(cb + j) * DIMC + e]);
    }
  }
}

// sum `splits` bf16 partial kat tiles, scale, pack frags. grid(64)
__global__ __launch_bounds__(256) void k_red(const short* __restrict__ part16,
                                             short* __restrict__ katpk, int splits) {
  __shared__ float sm[DIMC * DIMC];
  const int n = blockIdx.x, t = threadIdx.x;
  for (int i0 = t * 8; i0 < DIMC * DIMC; i0 += 256 * 8) {
    float a[8] = {0.f,0.f,0.f,0.f,0.f,0.f,0.f,0.f};
    for (int s8 = 0; s8 < splits; ++s8) {
      bf16x8 pv = *(const bf16x8*)&part16[((size_t)(s8 * NHEAD + n)) * 16384 + i0];
      #pragma unroll
      for (int j = 0; j < 8; ++j) a[j] += bf2f(pv[j]);
    }
    #pragma unroll
    for (int j = 0; j < 8; ++j) sm[i0 + j] = a[j] * SCALEF;
  }
  __syncthreads();
  short* dst = katpk + (size_t)n * 16384;
  for (int s = t; s < 2048; s += 256) {
    const int l = s & 63, kt = (s >> 6) >> 3, nt = (s >> 6) & 7;
    const int db = kt * 32 + (l >> 4) * 8, e = nt * 16 + (l & 15);
    #pragma unroll
    for (int j = 0; j < 8; ++j) dst[s * 8 + j] = f2bf(sm[(db + j) * DIMC + e]);
  }
}

// ---------------------------------------------------------------------------
// stage Y tiles: dwconv+BN for two projections -> swizzled bf16 LDS [64 x][128 c]
// ---------------------------------------------------------------------------
__device__ __forceinline__ void stage2(const float* __restrict__ x,
    const float* __restrict__ dwf, const float* __restrict__ bfl,
    int b, int xg0, int t, short* Y0, short* Y1, int p0, int p1)
{
  const int xl = t & 63, cg = t >> 6;
  const int xg = xg0 + xl;
  #pragma unroll
  for (int i = 0; i < 16; ++i) {
    const int c = 2 * (cg + 4 * i);
    float v0[2], v1[2];
    #pragma unroll
    for (int u = 0; u < 2; ++u) {
      const int cc = c + u;
      const float* xr = x + ((size_t)b * DIMC + cc) * XLEN + xg;
      float xm = (xg > 0) ? xr[-1] : 0.f;
      float xc = xr[0];
      float xp = (xg < XLEN - 1) ? xr[1] : 0.f;
      const float* d0 = dwf + (p0 * DIMC + cc) * 3;
      const float* d1 = dwf + (p1 * DIMC + cc) * 3;
      v0[u] = xm * d0[0] + xc * d0[1] + xp * d0[2] + bfl[p0 * DIMC + cc];
      v1[u] = xm * d1[0] + xc * d1[1] + xp * d1[2] + bfl[p1 * DIMC + cc];
    }
    const unsigned off = xl * 256 + ((c * 2) ^ ((xl & 7) << 4));
    *(unsigned*)((char*)Y0 + off) = pk2(v0[0], v0[1]);
    *(unsigned*)((char*)Y1 + off) = pk2(v1[0], v1[1]);
  }
}

// ---------------------------------------------------------------------------
// Fused kat (r9 k_kat3 + XCD-locality swizzle): one launch, 512 blocks 1-D.
// Decode: XCD (d&7) handles exactly ONE b (8 xs-splits x 8 heads = 64 slots),
// so the per-XCD L2 working set is 2 MB of x + 0.5 MB weights (L2-resident).
// Per block: loop 8 chunks of 64 x: stage Y; Q/K GEMM (hi/lo, register-
// prefetched); softmax; kat MFMA accumulate in registers; bf16 partial store.
// ---------------------------------------------------------------------------
__global__ __launch_bounds__(256) void k_kat4(
    const float* __restrict__ x, const float* __restrict__ dwf,
    const float* __restrict__ bfl, const short* __restrict__ Wpk,
    short* __restrict__ part16)
{
  __shared__ __align__(16) short Yq[TX * 128], Yk[TX * 128];
  __shared__ __align__(16) short QT[128 * TX], ST[128 * TX];
  const int t = threadIdx.x, w = t >> 6, l = t & 63;
  const int l15 = l & 15, lq = l >> 4;
  // XCD-locality decode (perf heuristic; correctness independent of mapping)
  const int d = blockIdx.x;
  const int xcd = d & 7, slot = d >> 3;
  const int h = slot & 7, p = slot >> 3;
  const int pid = xcd * 8 + p;
  const int b = pid >> 3, xs = pid & 7;
  const int n = b * HEADS + h;
  const int xbase = xs * (XLEN / KSPL);

  const short* WqHi = Wpk + (size_t)((0 * 8 + h) * 2 + 0) * 16384;
  const short* WqLo = Wpk + (size_t)((0 * 8 + h) * 2 + 1) * 16384;
  const short* WkHi = Wpk + (size_t)((1 * 8 + h) * 2 + 0) * 16384;
  const short* WkLo = Wpk + (size_t)((1 * 8 + h) * 2 + 1) * 16384;

  f32x4 ka[2][8];
  #pragma unroll
  for (int i = 0; i < 2; ++i)
    #pragma unroll
    for (int j = 0; j < 8; ++j) ka[i][j] = {0.f, 0.f, 0.f, 0.f};

  for (int ch = 0; ch < (XLEN / KSPL) / TX; ++ch) {
    __syncthreads();               // prev chunk's QT/ST & Yq/Yk reads done
    stage2(x, dwf, bfl, b, xbase + ch * TX, t, Yq, Yk, 0, 1);
    __syncthreads();

    f32x4 qa[8];
    // ---- Q GEMM, register-prefetched ----
    #pragma unroll
    for (int j = 0; j < 8; ++j) qa[j] = {0.f, 0.f, 0.f, 0.f};
    {
      bf16x8 a0 = ldY(Yq, w * 16 + l15, 0 * 64 + lq * 16);
      bf16x8 a1 = ldY(Yq, w * 16 + l15, 1 * 64 + lq * 16);
      bf16x8 a2 = ldY(Yq, w * 16 + l15, 2 * 64 + lq * 16);
      bf16x8 a3 = ldY(Yq, w * 16 + l15, 3 * 64 + lq * 16);
      bf16x8 h0[8], l0[8], h1[8], l1[8];
      #pragma unroll
      for (int nt = 0; nt < 8; ++nt) { h0[nt] = LDW(WqHi,0,nt); l0[nt] = LDW(WqLo,0,nt); }
      #pragma unroll
      for (int nt = 0; nt < 8; ++nt) { h1[nt] = LDW(WqHi,1,nt); l1[nt] = LDW(WqLo,1,nt); }
      #pragma unroll
      for (int nt = 0; nt < 8; ++nt) { qa[nt]=MFMA(a0,h0[nt],qa[nt]); qa[nt]=MFMA(a0,l0[nt],qa[nt]); }
      #pragma unroll
      for (int nt = 0; nt < 8; ++nt) { h0[nt] = LDW(WqHi,2,nt); l0[nt] = LDW(WqLo,2,nt); }
      #pragma unroll
      for (int nt = 0; nt < 8; ++nt) { qa[nt]=MFMA(a1,h1[nt],qa[nt]); qa[nt]=MFMA(a1,l1[nt],qa[nt]); }
      #pragma unroll
      for (int nt = 0; nt < 8; ++nt) { h1[nt] = LDW(WqHi,3,nt); l1[nt] = LDW(WqLo,3,nt); }
      #pragma unroll
      for (int nt = 0; nt < 8; ++nt) { qa[nt]=MFMA(a2,h0[nt],qa[nt]); qa[nt]=MFMA(a2,l0[nt],qa[nt]); }
      #pragma unroll
      for (int nt = 0; nt < 8; ++nt) { qa[nt]=MFMA(a3,h1[nt],qa[nt]); qa[nt]=MFMA(a3,l1[nt],qa[nt]); }
    }
    #pragma unroll
    for (int nt = 0; nt < 8; ++nt) {
      const int dd = nt * 16 + l15;
      #pragma unroll
      for (int rp = 0; rp < 2; ++rp) {
        const int x2 = w * 16 + lq * 4 + rp * 2;
        *(unsigned*)((char*)QT + dd * 128 + ((x2 * 2) ^ ((dd & 7) << 4))) =
            pk2(qa[nt][rp * 2], qa[nt][rp * 2 + 1]);
      }
    }

    // ---- K GEMM, same pattern ----
    #pragma unroll
    for (int j = 0; j < 8; ++j) qa[j] = {0.f, 0.f, 0.f, 0.f};
    {
      bf16x8 a0 = ldY(Yk, w * 16 + l15, 0 * 64 + lq * 16);
      bf16x8 a1 = ldY(Yk, w * 16 + l15, 1 * 64 + lq * 16);
      bf16x8 a2 = ldY(Yk, w * 16 + l15, 2 * 64 + lq * 16);
      bf16x8 a3 = ldY(Yk, w * 16 + l15, 3 * 64 + lq * 16);
      bf16x8 h0[8], l0[8], h1[8], l1[8];
      #pragma unroll
      for (int nt = 0; nt < 8; ++nt) { h0[nt] = LDW(WkHi,0,nt); l0[nt] = LDW(WkLo,0,nt); }
      #pragma unroll
      for (int nt = 0; nt < 8; ++nt) { h1[nt] = LDW(WkHi,1,nt); l1[nt] = LDW(WkLo,1,nt); }
      #pragma unroll
      for (int nt = 0; nt < 8; ++nt) { qa[nt]=MFMA(a0,h0[nt],qa[nt]); qa[nt]=MFMA(a0,l0[nt],qa[nt]); }
      #pragma unroll
      for (int nt = 0; nt < 8; ++nt) { h0[nt] = LDW(WkHi,2,nt); l0[nt] = LDW(WkLo,2,nt); }
      #pragma unroll
      for (int nt = 0; nt < 8; ++nt) { qa[nt]=MFMA(a1,h1[nt],qa[nt]); qa[nt]=MFMA(a1,l1[nt],qa[nt]); }
      #pragma unroll
      for (int nt = 0; nt < 8; ++nt) { h1[nt] = LDW(WkHi,3,nt); l1[nt] = LDW(WkLo,3,nt); }
      #pragma unroll
      for (int nt = 0; nt < 8; ++nt) { qa[nt]=MFMA(a2,h0[nt],qa[nt]); qa[nt]=MFMA(a2,l0[nt],qa[nt]); }
      #pragma unroll
      for (int nt = 0; nt < 8; ++nt) { qa[nt]=MFMA(a3,h1[nt],qa[nt]); qa[nt]=MFMA(a3,l1[nt],qa[nt]); }
    }
    // in-register row softmax over e
    float inv[4];
    #pragma unroll
    for (int r = 0; r < 4; ++r) {
      float m = qa[0][r];
      #pragma unroll
      for (int nt = 1; nt < 8; ++nt) m = fmaxf(m, qa[nt][r]);
      m = fmaxf(m, __shfl_xor(m, 1)); m = fmaxf(m, __shfl_xor(m, 2));
      m = fmaxf(m, __shfl_xor(m, 4)); m = fmaxf(m, __shfl_xor(m, 8));
      float s = 0.f;
      #pragma unroll
      for (int nt = 0; nt < 8; ++nt) { float e = __expf(qa[nt][r] - m); qa[nt][r] = e; s += e; }
      s += __shfl_xor(s, 1); s += __shfl_xor(s, 2); s += __shfl_xor(s, 4); s += __shfl_xor(s, 8);
      inv[r] = 1.f / s;
    }
    #pragma unroll
    for (int nt = 0; nt < 8; ++nt) {
      const int e = nt * 16 + l15;
      #pragma unroll
      for (int rp = 0; rp < 2; ++rp) {
        const int x2 = w * 16 + lq * 4 + rp * 2;
        *(unsigned*)((char*)ST + e * 128 + ((x2 * 2) ^ ((e & 7) << 4))) =
            pk2(qa[nt][rp * 2] * inv[rp * 2], qa[nt][rp * 2 + 1] * inv[rp * 2 + 1]);
      }
    }
    __syncthreads();               // QT/ST ready

    // kat accumulate: ka[mt][nt] += QT_A(d,x) x ST_B(x,e), K = 64
    #pragma unroll
    for (int kt2 = 0; kt2 < 2; ++kt2) {
      bf16x8 a0 = ldT(QT, w * 32 + l15,      kt2 * 64 + lq * 16);
      bf16x8 a1 = ldT(QT, w * 32 + 16 + l15, kt2 * 64 + lq * 16);
      #pragma unroll
      for (int nt = 0; nt < 8; ++nt) {
        bf16x8 bs = ldT(ST, nt * 16 + l15, kt2 * 64 + lq * 16);
        ka[0][nt] = MFMA(a0, bs, ka[0][nt]);
        ka[1][nt] = MFMA(a1, bs, ka[1][nt]);
      }
    }
  }
  short* dst = part16 + ((size_t)(xs * NHEAD + n)) * 16384;
  #pragma unroll
  for (int mt = 0; mt < 2; ++mt)
    #pragma unroll
    for (int nt = 0; nt < 8; ++nt)
      #pragma unroll
      for (int r = 0; r < 4; ++r) {
        const int dd = w * 32 + mt * 16 + lq * 4 + r;
        const int e = nt * 16 + l15;
        dst[dd * DIMC + e] = f2bf(ka[mt][nt][r]);
      }
}

// ---------------------------------------------------------------------------
// Phase 3: k_out10 — unchanged from round 16 (tied-best 170 us).
// ---------------------------------------------------------------------------
__global__ __launch_bounds__(256) void k_out10(
    const float* __restrict__ x, const float* __restrict__ dwf,
    const float* __restrict__ bfl, const short* __restrict__ Wpk,
    const short* __restrict__ Gpk, const short* __restrict__ katpk,
    const short* __restrict__ Opk, const float* __restrict__ c0,
    const float* __restrict__ outb, float* __restrict__ outp)
{
  __shared__ __align__(16) short Yq[TX * 128], Yv[TX * 128];
  __shared__ __align__(16) short Vx[TX * 128], Tn[TX * 128];
  const int t = threadIdx.x, w = t >> 6, l = t & 63;
  const int l15 = l & 15, lq = l >> 4;
  const int b = blockIdx.y;
  const int x0 = blockIdx.x * TX;

  f32x4 oacc[2][4];
  #pragma unroll
  for (int i = 0; i < 2; ++i)
    #pragma unroll
    for (int j = 0; j < 4; ++j) oacc[i][j] = {0.f, 0.f, 0.f, 0.f};
  float c0v[8];
  #pragma unroll
  for (int nt = 0; nt < 8; ++nt) c0v[nt] = c0[nt * 16 + l15];

  stage2(x, dwf, bfl, b, x0, t, Yq, Yv, 0, 2);
  __syncthreads();

  for (int h = 0; h < HEADS; ++h) {
    const int n = b * HEADS + h;
    const short* WvHi = Wpk + (size_t)((2 * 8 + h) * 2 + 0) * 16384;
    const short* WvLo = Wpk + (size_t)((2 * 8 + h) * 2 + 1) * 16384;
    const short* Wg   = Gpk + (size_t)h * 16384;
    const short* Kp   = katpk + (size_t)n * 16384;
    const short* OHi  = Opk + (size_t)(h * 2 + 0) * 16384;
    const short* OLo  = Opk + (size_t)(h * 2 + 1) * 16384;

    bf16x8 P0[8], P1[8], Q0[8], Q1[8];
    #pragma unroll
    for (int i = 0; i < 8; ++i) P0[i] = LDW(WvHi, 0, i);
    #pragma unroll
    for (int i = 0; i < 8; ++i) P1[i] = LDW(WvHi, 1, i);
    #pragma unroll
    for (int i = 0; i < 8; ++i) Q0[i] = LDW(WvHi, 2, i);
    #pragma unroll
    for (int i = 0; i < 8; ++i) Q1[i] = LDW(WvHi, 3, i);

    // ---- V GEMM hi (rotate buffers -> WvLo) ----
    f32x4 va[8];
    #pragma unroll
    for (int j = 0; j < 8; ++j) va[j] = {0.f, 0.f, 0.f, 0.f};
    {
      bf16x8 a = ldY(Yv, w * 16 + l15, 0 * 64 + lq * 16);
      #pragma unroll
      for (int nt = 0; nt < 8; ++nt) va[nt] = MFMA(a, P0[nt], va[nt]);
    }
    #pragma unroll
    for (int i = 0; i < 8; ++i) P0[i] = LDW(WvLo, 0, i);
    {
      bf16x8 a = ldY(Yv, w * 16 + l15, 1 * 64 + lq * 16);
      #pragma unroll
      for (int nt = 0; nt < 8; ++nt) va[nt] = MFMA(a, P1[nt], va[nt]);
    }
    #pragma unroll
    for (int i = 0; i < 8; ++i) P1[i] = LDW(WvLo, 1, i);
    {
      bf16x8 a = ldY(Yv, w * 16 + l15, 2 * 64 + lq * 16);
      #pragma unroll
      for (int nt = 0; nt < 8; ++nt) va[nt] = MFMA(a, Q0[nt], va[nt]);
    }
    #pragma unroll
    for (int i = 0; i < 8; ++i) Q0[i] = LDW(WvLo, 2, i);
    {
      bf16x8 a = ldY(Yv, w * 16 + l15, 3 * 64 + lq * 16);
      #pragma unroll
      for (int nt = 0; nt < 8; ++nt) va[nt] = MFMA(a, Q1[nt], va[nt]);
    }
    #pragma unroll
    for (int i = 0; i < 8; ++i) Q1[i] = LDW(WvLo, 3, i);

    // ---- V GEMM lo (rotate -> Wg) ----
    {
      bf16x8 a = ldY(Yv, w * 16 + l15, 0 * 64 + lq * 16);
      #pragma unroll
      for (int nt = 0; nt < 8; ++nt) va[nt] = MFMA(a, P0[nt], va[nt]);
    }
    #pragma unroll
    for (int i = 0; i < 8; ++i) P0[i] = LDW(Wg, 0, i);
    {
      bf16x8 a = ldY(Yv, w * 16 + l15, 1 * 64 + lq * 16);
      #pragma unroll
      for (int nt = 0; nt < 8; ++nt) va[nt] = MFMA(a, P1[nt], va[nt]);
    }
    #pragma unroll
    for (int i = 0; i < 8; ++i) P1[i] = LDW(Wg, 1, i);
    {
      bf16x8 a = ldY(Yv, w * 16 + l15, 2 * 64 + lq * 16);
      #pragma unroll
      for (int nt = 0; nt < 8; ++nt) va[nt] = MFMA(a, Q0[nt], va[nt]);
    }
    #pragma unroll
    for (int i = 0; i < 8; ++i) Q0[i] = LDW(Wg, 2, i);
    {
      bf16x8 a = ldY(Yv, w * 16 + l15, 3 * 64 + lq * 16);
      #pragma unroll
      for (int nt = 0; nt < 8; ++nt) va[nt] = MFMA(a, Q1[nt], va[nt]);
    }
    #pragma unroll
    for (int i = 0; i < 8; ++i) Q1[i] = LDW(Wg, 3, i);

    // ---- write V[x][d] (own wave rows; va dies here) ----
    #pragma unroll
    for (int nt = 0; nt < 8; ++nt) {
      const int dd = nt * 16 + l15;
      #pragma unroll
      for (int r = 0; r < 4; ++r) {
        const int xr = w * 16 + lq * 4 + r;
        *(short*)((char*)Vx + xr * 256 + ((dd * 2) ^ ((xr & 7) << 4))) = f2bf(va[nt][r]);
      }
    }

    // ---- gate GEMM (rotate -> Kp) ----
    f32x4 ga[8];
    #pragma unroll
    for (int j = 0; j < 8; ++j) ga[j] = {0.f, 0.f, 0.f, 0.f};
    {
      bf16x8 a = ldY(Yq, w * 16 + l15, 0 * 64 + lq * 16);
      #pragma unroll
      for (int nt = 0; nt < 8; ++nt) ga[nt] = MFMA(a, P0[nt], ga[nt]);
    }
    #pragma unroll
    for (int i = 0; i < 8; ++i) P0[i] = LDW(Kp, 0, i);
    {
      bf16x8 a = ldY(Yq, w * 16 + l15, 1 * 64 + lq * 16);
      #pragma unroll
      for (int nt = 0; nt < 8; ++nt) ga[nt] = MFMA(a, P1[nt], ga[nt]);
    }
    #pragma unroll
    for (int i = 0; i < 8; ++i) P1[i] = LDW(Kp, 1, i);
    {
      bf16x8 a = ldY(Yq, w * 16 + l15, 2 * 64 + lq * 16);
      #pragma unroll
      for (int nt = 0; nt < 8; ++nt) ga[nt] = MFMA(a, Q0[nt], ga[nt]);
    }
    #pragma unroll
    for (int i = 0; i < 8; ++i) Q0[i] = LDW(Kp, 2, i);
    {
      bf16x8 a = ldY(Yq, w * 16 + l15, 3 * 64 + lq * 16);
      #pragma unroll
      for (int nt = 0; nt < 8; ++nt) ga[nt] = MFMA(a, Q1[nt], ga[nt]);
    }
    #pragma unroll
    for (int i = 0; i < 8; ++i) Q1[i] = LDW(Kp, 3, i);

    // ---- fold sigmoid into ga ----
    #pragma unroll
    for (int nt = 0; nt < 8; ++nt)
      #pragma unroll
      for (int r = 0; r < 4; ++r)
        ga[nt][r] = 1.f / (1.f + __expf(-(ga[nt][r] + c0v[nt])));

    // ---- KV GEMM (A = own Vx rows; rotate P -> O frags) ----
    f32x4 kv[8];
    #pragma unroll
    for (int j = 0; j < 8; ++j) kv[j] = {0.f, 0.f, 0.f, 0.f};
    {
      bf16x8 a = ldY(Vx, w * 16 + l15, 0 * 64 + lq * 16);
      #pragma unroll
      for (int nt = 0; nt < 8; ++nt) kv[nt] = MFMA(a, P0[nt], kv[nt]);
    }
    #pragma unroll
    for (int i = 0; i < 8; ++i)
      P0[i] = (*(const bf16x8*)&OHi[((((w * 2 + (i >> 2)) * 4 + (i & 3))) * 64 + l) * 8]);
    {
      bf16x8 a = ldY(Vx, w * 16 + l15, 1 * 64 + lq * 16);
      #pragma unroll
      for (int nt = 0; nt < 8; ++nt) kv[nt] = MFMA(a, P1[nt], kv[nt]);
    }
    #pragma unroll
    for (int i = 0; i < 8; ++i)
      P1[i] = (*(const bf16x8*)&OLo[((((w * 2 + (i >> 2)) * 4 + (i & 3))) * 64 + l) * 8]);
    {
      bf16x8 a = ldY(Vx, w * 16 + l15, 2 * 64 + lq * 16);
      #pragma unroll
      for (int nt = 0; nt < 8; ++nt) kv[nt] = MFMA(a, Q0[nt], kv[nt]);
    }
    {
      bf16x8 a = ldY(Vx, w * 16 + l15, 3 * 64 + lq * 16);
      #pragma unroll
      for (int nt = 0; nt < 8; ++nt) kv[nt] = MFMA(a, Q1[nt], kv[nt]);
    }

    // ---- combine: T = KV + sig * V (V re-read from own Vx rows) ----
    #pragma unroll
    for (int nt = 0; nt < 8; ++nt) {
      const int e = nt * 16 + l15;
      #pragma unroll
      for (int r = 0; r < 4; ++r) {
        const int xr = w * 16 + lq * 4 + r;
        float vv = bf2f(*(const short*)((const char*)Vx + xr * 256 + ((e * 2) ^ ((xr & 7) << 4))));
        *(short*)((char*)Tn + xr * 256 + ((e * 2) ^ ((xr & 7) << 4))) =
            f2bf(kv[nt][r] + ga[nt][r] * vv);
      }
    }
    __syncthreads();                                   // Tn complete

    // ---- out-projection accumulate from P0 (hi) / P1 (lo) ----
    #pragma unroll
    for (int kt = 0; kt < 4; ++kt) {
      #pragma unroll
      for (int nt4 = 0; nt4 < 4; ++nt4) {
        bf16x8 bt = ldY(Tn, nt4 * 16 + l15, kt * 64 + lq * 16);
        oacc[0][nt4] = MFMA(P0[0 * 4 + kt], bt, oacc[0][nt4]);
        oacc[0][nt4] = MFMA(P1[0 * 4 + kt], bt, oacc[0][nt4]);
        oacc[1][nt4] = MFMA(P0[1 * 4 + kt], bt, oacc[1][nt4]);
        oacc[1][nt4] = MFMA(P1[1 * 4 + kt], bt, oacc[1][nt4]);
      }
    }
    __syncthreads();   // Tn reads done before next head's combine overwrites
  }
  #pragma unroll
  for (int mt = 0; mt < 2; ++mt) {
    #pragma unroll
    for (int nt4 = 0; nt4 < 4; ++nt4) {
      #pragma unroll
      for (int r = 0; r < 4; ++r) {
        const int o = w * 32 + mt * 16 + lq * 4 + r;
        const int xx = x0 + nt4 * 16 + l15;
        outp[((size_t)b * DIMC + o) * XLEN + xx] = oacc[mt][nt4][r] + outb[o];
      }
    }
  }
}

// ---------------------------------------------------------------------------
extern "C" void kernel_launch(void* const* d_in, const int* in_sizes, int n_in,
                              void* d_out, int out_size, void* d_ws, size_t ws_size,
                              hipStream_t stream) {
  (void)in_sizes; (void)n_in; (void)out_size;
  const float* x = (const float*)d_in[0];
  // q: 1..6, k: 7..12, v: 13..18 (dw,g,b,m,v,pw), gt: 19..24, out_w:25, out_b:26

  char* ws = (char*)d_ws;
  short* katpk = (short*)(ws);                       // 2 MB
  short* Wpk   = (short*)(ws + 2097152);             // 1.5 MB
  short* Opk   = (short*)(ws + 3670016);             // 512 KB
  short* Gpk   = (short*)(ws + 4194304);             // 256 KB
  float* WgF   = (float*)(ws + 4456448);             // 512 KB
  float* Gt    = (float*)(ws + 4980736);             // 64 KB
  float* c0    = (float*)(ws + 5046272);             // 512 B
  float* dwf   = (float*)(ws + 5046784);             // 4.6 KB
  float* bfl   = (float*)(ws + 5051392);             // 1.5 KB
  constexpr size_t BASE = 5052928;
  short* part16 = (short*)(ws + BASE);               // 16 MB (8 splits x 64 n x 16K x 2B)
  // need BASE + 16 MB = 21.8 MB; proven ws >= 30.2 MB
  if (ws_size < (size_t)30218752) return;   // loud-fail (proven bound)

  k_prep1<<<4, 128, 0, stream>>>(
      (const float*)d_in[1],  (const float*)d_in[2],  (const float*)d_in[3],
      (const float*)d_in[4],  (const float*)d_in[5],
      (const float*)d_in[7],  (const float*)d_in[8],  (const float*)d_in[9],
      (const float*)d_in[10], (const float*)d_in[11],
      (const float*)d_in[13], (const float*)d_in[14], (const float*)d_in[15],
      (const float*)d_in[16], (const float*)d_in[17],
      (const float*)d_in[24], (const float*)d_in[19], (const float*)d_in[20],
      (const float*)d_in[21], (const float*)d_in[22], (const float*)d_in[23],
      dwf, bfl, Gt, c0);

  k_wg<<<dim3(8, 8), 256, 0, stream>>>((const float*)d_in[6], Gt, WgF);

  k_pack<<<72, 256, 0, stream>>>((const float*)d_in[6], (const float*)d_in[12],
                                 (const float*)d_in[18], (const float*)d_in[25],
                                 WgF, Wpk, Opk, Gpk);

  k_kat4<<<KSPL * NHEAD, 256, 0, stream>>>(x, dwf, bfl, Wpk, part16);
  k_red<<<NHEAD, 256, 0, stream>>>(part16, katpk, KSPL);
  k_out10<<<dim3(XLEN / TX, BATCH), 256, 0, stream>>>(x, dwf, bfl, Wpk, Gpk, katpk,
                                                      Opk, c0, (const float*)d_in[26],
                                                      (float*)d_out);
}

// Round 18
// 460.197 us; speedup vs baseline: 2.2374x; 2.2374x over previous
//
#include <hip/hip_runtime.h>
#include <hip/hip_bf16.h>

#define DIMC   128
#define HEADS  8
#define BATCH  8
#define XLEN   4096
#define NHEAD  64
#define EPSV   1e-5f
#define SCALEF 0.08838834764831845f   // 128^-0.5
#define TX     64

typedef __attribute__((ext_vector_type(8))) short bf16x8;
typedef __attribute__((ext_vector_type(4))) float f32x4;
#define MFMA(a,b,c) __builtin_amdgcn_mfma_f32_16x16x32_bf16((a),(b),(c),0,0,0)
// weight B-frag load from GLOBAL table laid out [(kt*8+nt)][lane][8]
#define LDW(tbl, kt, nt) (*(const bf16x8*)&(tbl)[(((kt) * 8 + (nt)) * 64 + l) * 8])

__device__ __forceinline__ short f2bf(float f) {
  union { float f; unsigned u; } v; v.f = f;
  return (short)((v.u + 0x7fffu + ((v.u >> 16) & 1u)) >> 16);
}
__device__ __forceinline__ float bf2f(short h) {
  union { unsigned u; float f; } v; v.u = ((unsigned)(unsigned short)h) << 16;
  return v.f;
}
__device__ __forceinline__ unsigned pk2(float a, float b) {
  return (unsigned)(unsigned short)f2bf(a) | ((unsigned)(unsigned short)f2bf(b) << 16);
}

// LDS fragment loads. Row-major bf16 tiles, XOR-swizzled: byte ^= (row&7)<<4.
__device__ __forceinline__ bf16x8 ldY(const short* Y, int row, int kcb) {
  return *(const bf16x8*)((const char*)Y + row*256 + (kcb ^ ((row&7)<<4)));
}

// ---------------------------------------------------------------------------
// prep kernels (merged: 3 launches total) — unchanged from round 11
// ---------------------------------------------------------------------------
__global__ void k_prep1(const float* dw0, const float* g0, const float* b0, const float* m0, const float* v0,
                        const float* dw1, const float* g1, const float* b1, const float* m1, const float* v1,
                        const float* dw2, const float* g2, const float* b2, const float* m2, const float* v2,
                        const float* gt_pw, const float* gt_dw, const float* gt_g,
                        const float* gt_b, const float* gt_m, const float* gt_v,
                        float* __restrict__ dwf, float* __restrict__ bfl,
                        float* __restrict__ Gt, float* __restrict__ c0) {
  int p = blockIdx.x, c = threadIdx.x;
  if (p < 3) {
    const float* dw = p == 0 ? dw0 : p == 1 ? dw1 : dw2;
    const float* g  = p == 0 ? g0  : p == 1 ? g1  : g2;
    const float* bb = p == 0 ? b0  : p == 1 ? b1  : b2;
    const float* m  = p == 0 ? m0  : p == 1 ? m1  : m2;
    const float* vv = p == 0 ? v0  : p == 1 ? v1  : v2;
    float a = g[c] * rsqrtf(vv[c] + EPSV);
    dwf[(p * DIMC + c) * 3 + 0] = dw[c * 3 + 0] * a;
    dwf[(p * DIMC + c) * 3 + 1] = dw[c * 3 + 1] * a;
    dwf[(p * DIMC + c) * 3 + 2] = dw[c * 3 + 2] * a;
    bfl[p * DIMC + c] = bb[c] - m[c] * a;
  } else {
    int d = c;
    float s = 0.f;
    for (int i = 0; i < DIMC; ++i) {
      float a  = gt_g[i] * rsqrtf(gt_v[i] + EPSV);
      float w1 = gt_dw[i] * a;
      float w0 = gt_b[i] - gt_m[i] * a;
      float pw = gt_pw[d * DIMC + i];
      Gt[i * DIMC + d] = pw * w1;
      s += pw * w0;
    }
    c0[d] = s;
  }
}

__global__ void k_wg(const float* __restrict__ q_pw, const float* __restrict__ Gt,
                     float* __restrict__ WgF) {
  const int h = blockIdx.x, cb = blockIdx.y, t = threadIdx.x;
  const int c = cb * 16 + (t >> 4);
  const int e0 = (t & 15) * 8;
  float acc[8] = {0.f,0.f,0.f,0.f,0.f,0.f,0.f,0.f};
  for (int d = 0; d < DIMC; ++d) {
    float wq = q_pw[((size_t)(h * DIMC + d)) * DIMC + c];
    const float* gr = Gt + d * DIMC + e0;
    #pragma unroll
    for (int j = 0; j < 8; ++j) acc[j] += wq * gr[j];
  }
  float* out = WgF + ((size_t)h * DIMC + c) * DIMC + e0;
  #pragma unroll
  for (int j = 0; j < 8; ++j) out[j] = acc[j];
}

__global__ void k_pack(const float* __restrict__ q_pw, const float* __restrict__ k_pw,
                       const float* __restrict__ v_pw, const float* __restrict__ out_w,
                       const float* __restrict__ WgF,
                       short* __restrict__ Wpk, short* __restrict__ Opk,
                       short* __restrict__ Gpk) {
  const int blk = blockIdx.x, t = threadIdx.x;
  if (blk < 48) {
    const int p = blk / 16, h = (blk / 2) & 7, hl = blk & 1;
    const float* pw = p == 0 ? q_pw : p == 1 ? k_pw : v_pw;
    short* dst = Wpk + (size_t)((p * 8 + h) * 2 + hl) * 16384;
    for (int s = t; s < 2048; s += 256) {
      const int l = s & 63, kt = (s >> 6) >> 3, nt = (s >> 6) & 7;
      const int o = h * DIMC + nt * 16 + (l & 15);
      const int cb = kt * 32 + (l >> 4) * 8;
      #pragma unroll
      for (int j = 0; j < 8; ++j) {
        float wv = pw[(size_t)o * DIMC + cb + j];
        short hi = f2bf(wv);
        dst[s * 8 + j] = (hl == 0) ? hi : f2bf(wv - bf2f(hi));
      }
    }
  } else if (blk < 64) {
    const int m = blk - 48, h = m >> 1, hl = m & 1;
    short* dst = Opk + (size_t)(h * 2 + hl) * 16384;
    for (int s = t; s < 2048; s += 256) {
      const int l = s & 63, mt = (s >> 6) >> 2, kt = (s >> 6) & 3;
      const int o = mt * 16 + (l & 15);
      const int ib = h * DIMC + kt * 32 + (l >> 4) * 8;
      #pragma unroll
      for (int j = 0; j < 8; ++j) {
        float wv = out_w[(size_t)o * (DIMC * HEADS) + ib + j];
        short hi = f2bf(wv);
        dst[s * 8 + j] = (hl == 0) ? hi : f2bf(wv - bf2f(hi));
      }
    }
  } else {
    const int h = blk - 64;
    const float* src = WgF + (size_t)h * 16384;
    short* dst = Gpk + (size_t)h * 16384;
    for (int s = t; s < 2048; s += 256) {
      const int l = s & 63, kt = (s >> 6) >> 3, nt = (s >> 6) & 7;
      const int cb = kt * 32 + (l >> 4) * 8, e = nt * 16 + (l & 15);
      #pragma unroll
      for (int j = 0; j < 8; ++j) dst[s * 8 + j] = f2bf(src[(size_t)(cb + j) * DIMC + e]);
    }
  }
}

// sum `splits` bf16 partial kat tiles, scale, pack frags. grid(64)
__global__ __launch_bounds__(256) void k_red(const short* __restrict__ part16,
                                             short* __restrict__ katpk, int splits) {
  __shared__ float sm[DIMC * DIMC];
  const int n = blockIdx.x, t = threadIdx.x;
  for (int i0 = t * 8; i0 < DIMC * DIMC; i0 += 256 * 8) {
    float a[8] = {0.f,0.f,0.f,0.f,0.f,0.f,0.f,0.f};
    for (int s8 = 0; s8 < splits; ++s8) {
      bf16x8 pv = *(const bf16x8*)&part16[((size_t)(s8 * NHEAD + n)) * 16384 + i0];
      #pragma unroll
      for (int j = 0; j < 8; ++j) a[j] += bf2f(pv[j]);
    }
    #pragma unroll
    for (int j = 0; j < 8; ++j) sm[i0 + j] = a[j] * SCALEF;
  }
  __syncthreads();
  short* dst = katpk + (size_t)n * 16384;
  for (int s = t; s < 2048; s += 256) {
    const int l = s & 63, kt = (s >> 6) >> 3, nt = (s >> 6) & 7;
    const int db = kt * 32 + (l >> 4) * 8, e = nt * 16 + (l & 15);
    #pragma unroll
    for (int j = 0; j < 8; ++j) dst[s * 8 + j] = f2bf(sm[(db + j) * DIMC + e]);
  }
}

// ---------------------------------------------------------------------------
// stage Y tiles: dwconv+BN for two projections -> swizzled bf16 LDS [64 x][128 c]
// ---------------------------------------------------------------------------
__device__ __forceinline__ void stage2(const float* __restrict__ x,
    const float* __restrict__ dwf, const float* __restrict__ bfl,
    int b, int xg0, int t, short* Y0, short* Y1, int p0, int p1)
{
  const int xl = t & 63, cg = t >> 6;
  const int xg = xg0 + xl;
  #pragma unroll
  for (int i = 0; i < 16; ++i) {
    const int c = 2 * (cg + 4 * i);
    float v0[2], v1[2];
    #pragma unroll
    for (int u = 0; u < 2; ++u) {
      const int cc = c + u;
      const float* xr = x + ((size_t)b * DIMC + cc) * XLEN + xg;
      float xm = (xg > 0) ? xr[-1] : 0.f;
      float xc = xr[0];
      float xp = (xg < XLEN - 1) ? xr[1] : 0.f;
      const float* d0 = dwf + (p0 * DIMC + cc) * 3;
      const float* d1 = dwf + (p1 * DIMC + cc) * 3;
      v0[u] = xm * d0[0] + xc * d0[1] + xp * d0[2] + bfl[p0 * DIMC + cc];
      v1[u] = xm * d1[0] + xc * d1[1] + xp * d1[2] + bfl[p1 * DIMC + cc];
    }
    const unsigned off = xl * 256 + ((c * 2) ^ ((xl & 7) << 4));
    *(unsigned*)((char*)Y0 + off) = pk2(v0[0], v0[1]);
    *(unsigned*)((char*)Y1 + off) = pk2(v1[0], v1[1]);
  }
}

// ---------------------------------------------------------------------------
// Phase 1: k_proj — per (x-tile, head) for one b: Q/K GEMM (hi/lo, register-
// prefetched), softmax; dump qT[h][d][x], sT[h][e][x]. grid (64, 8), 256 thr.
// ---------------------------------------------------------------------------
__global__ __launch_bounds__(256) void k_proj(
    const float* __restrict__ x, const float* __restrict__ dwf,
    const float* __restrict__ bfl, const short* __restrict__ Wpk,
    short* __restrict__ qT, short* __restrict__ sT, int b)
{
  __shared__ __align__(16) short Yq[TX * 128], Yk[TX * 128];
  __shared__ __align__(16) short QT[128 * TX], ST[128 * TX];
  const int t = threadIdx.x, w = t >> 6, l = t & 63;
  const int l15 = l & 15, lq = l >> 4;
  const int h = blockIdx.y;
  const int x0 = blockIdx.x * TX;

  stage2(x, dwf, bfl, b, x0, t, Yq, Yk, 0, 1);
  __syncthreads();

  const short* WqHi = Wpk + (size_t)((0 * 8 + h) * 2 + 0) * 16384;
  const short* WqLo = Wpk + (size_t)((0 * 8 + h) * 2 + 1) * 16384;
  const short* WkHi = Wpk + (size_t)((1 * 8 + h) * 2 + 0) * 16384;
  const short* WkLo = Wpk + (size_t)((1 * 8 + h) * 2 + 1) * 16384;

  f32x4 qa[8];

  // ---- Q GEMM, register-prefetched ----
  #pragma unroll
  for (int j = 0; j < 8; ++j) qa[j] = {0.f, 0.f, 0.f, 0.f};
  {
    bf16x8 a0 = ldY(Yq, w * 16 + l15, 0 * 64 + lq * 16);
    bf16x8 a1 = ldY(Yq, w * 16 + l15, 1 * 64 + lq * 16);
    bf16x8 a2 = ldY(Yq, w * 16 + l15, 2 * 64 + lq * 16);
    bf16x8 a3 = ldY(Yq, w * 16 + l15, 3 * 64 + lq * 16);
    bf16x8 h0[8], l0[8], h1[8], l1[8];
    #pragma unroll
    for (int nt = 0; nt < 8; ++nt) { h0[nt] = LDW(WqHi,0,nt); l0[nt] = LDW(WqLo,0,nt); }
    #pragma unroll
    for (int nt = 0; nt < 8; ++nt) { h1[nt] = LDW(WqHi,1,nt); l1[nt] = LDW(WqLo,1,nt); }
    #pragma unroll
    for (int nt = 0; nt < 8; ++nt) { qa[nt]=MFMA(a0,h0[nt],qa[nt]); qa[nt]=MFMA(a0,l0[nt],qa[nt]); }
    #pragma unroll
    for (int nt = 0; nt < 8; ++nt) { h0[nt] = LDW(WqHi,2,nt); l0[nt] = LDW(WqLo,2,nt); }
    #pragma unroll
    for (int nt = 0; nt < 8; ++nt) { qa[nt]=MFMA(a1,h1[nt],qa[nt]); qa[nt]=MFMA(a1,l1[nt],qa[nt]); }
    #pragma unroll
    for (int nt = 0; nt < 8; ++nt) { h1[nt] = LDW(WqHi,3,nt); l1[nt] = LDW(WqLo,3,nt); }
    #pragma unroll
    for (int nt = 0; nt < 8; ++nt) { qa[nt]=MFMA(a2,h0[nt],qa[nt]); qa[nt]=MFMA(a2,l0[nt],qa[nt]); }
    #pragma unroll
    for (int nt = 0; nt < 8; ++nt) { qa[nt]=MFMA(a3,h1[nt],qa[nt]); qa[nt]=MFMA(a3,l1[nt],qa[nt]); }
  }
  #pragma unroll
  for (int nt = 0; nt < 8; ++nt) {
    const int d = nt * 16 + l15;
    #pragma unroll
    for (int rp = 0; rp < 2; ++rp) {
      const int x2 = w * 16 + lq * 4 + rp * 2;
      *(unsigned*)((char*)QT + d * 128 + ((x2 * 2) ^ ((d & 7) << 4))) =
          pk2(qa[nt][rp * 2], qa[nt][rp * 2 + 1]);
    }
  }

  // ---- K GEMM, same pattern ----
  #pragma unroll
  for (int j = 0; j < 8; ++j) qa[j] = {0.f, 0.f, 0.f, 0.f};
  {
    bf16x8 a0 = ldY(Yk, w * 16 + l15, 0 * 64 + lq * 16);
    bf16x8 a1 = ldY(Yk, w * 16 + l15, 1 * 64 + lq * 16);
    bf16x8 a2 = ldY(Yk, w * 16 + l15, 2 * 64 + lq * 16);
    bf16x8 a3 = ldY(Yk, w * 16 + l15, 3 * 64 + lq * 16);
    bf16x8 h0[8], l0[8], h1[8], l1[8];
    #pragma unroll
    for (int nt = 0; nt < 8; ++nt) { h0[nt] = LDW(WkHi,0,nt); l0[nt] = LDW(WkLo,0,nt); }
    #pragma unroll
    for (int nt = 0; nt < 8; ++nt) { h1[nt] = LDW(WkHi,1,nt); l1[nt] = LDW(WkLo,1,nt); }
    #pragma unroll
    for (int nt = 0; nt < 8; ++nt) { qa[nt]=MFMA(a0,h0[nt],qa[nt]); qa[nt]=MFMA(a0,l0[nt],qa[nt]); }
    #pragma unroll
    for (int nt = 0; nt < 8; ++nt) { h0[nt] = LDW(WkHi,2,nt); l0[nt] = LDW(WkLo,2,nt); }
    #pragma unroll
    for (int nt = 0; nt < 8; ++nt) { qa[nt]=MFMA(a1,h1[nt],qa[nt]); qa[nt]=MFMA(a1,l1[nt],qa[nt]); }
    #pragma unroll
    for (int nt = 0; nt < 8; ++nt) { h1[nt] = LDW(WkHi,3,nt); l1[nt] = LDW(WkLo,3,nt); }
    #pragma unroll
    for (int nt = 0; nt < 8; ++nt) { qa[nt]=MFMA(a2,h0[nt],qa[nt]); qa[nt]=MFMA(a2,l0[nt],qa[nt]); }
    #pragma unroll
    for (int nt = 0; nt < 8; ++nt) { qa[nt]=MFMA(a3,h1[nt],qa[nt]); qa[nt]=MFMA(a3,l1[nt],qa[nt]); }
  }
  // in-register row softmax over e
  float inv[4];
  #pragma unroll
  for (int r = 0; r < 4; ++r) {
    float m = qa[0][r];
    #pragma unroll
    for (int nt = 1; nt < 8; ++nt) m = fmaxf(m, qa[nt][r]);
    m = fmaxf(m, __shfl_xor(m, 1)); m = fmaxf(m, __shfl_xor(m, 2));
    m = fmaxf(m, __shfl_xor(m, 4)); m = fmaxf(m, __shfl_xor(m, 8));
    float s = 0.f;
    #pragma unroll
    for (int nt = 0; nt < 8; ++nt) { float e = __expf(qa[nt][r] - m); qa[nt][r] = e; s += e; }
    s += __shfl_xor(s, 1); s += __shfl_xor(s, 2); s += __shfl_xor(s, 4); s += __shfl_xor(s, 8);
    inv[r] = 1.f / s;
  }
  #pragma unroll
  for (int nt = 0; nt < 8; ++nt) {
    const int e = nt * 16 + l15;
    #pragma unroll
    for (int rp = 0; rp < 2; ++rp) {
      const int x2 = w * 16 + lq * 4 + rp * 2;
      *(unsigned*)((char*)ST + e * 128 + ((x2 * 2) ^ ((e & 7) << 4))) =
          pk2(qa[nt][rp * 2] * inv[rp * 2], qa[nt][rp * 2 + 1] * inv[rp * 2 + 1]);
    }
  }
  __syncthreads();

  // coalesced dump: thread t handles row r = t>>1, half = t&1 (64 B each)
  {
    const int r = t >> 1, half = t & 1;
    const size_t row = ((size_t)h * DIMC + r) * XLEN + x0 + half * 32;
    #pragma unroll
    for (int i = 0; i < 4; ++i) {
      const int off = r * 128 + (((half * 64) + i * 16) ^ ((r & 7) << 4));
      *(int4*)(qT + row + i * 8) = *(const int4*)((const char*)QT + off);
      *(int4*)(sT + row + i * 8) = *(const int4*)((const char*)ST + off);
    }
  }
}

// ---------------------------------------------------------------------------
// Phase 2: k_katg — kat partial GEMM over x. grid (splits, 8 h, 4 eq).
// ---------------------------------------------------------------------------
__global__ __launch_bounds__(256) void k_katg(
    const short* __restrict__ qT, const short* __restrict__ sT,
    short* __restrict__ part16, int b)
{
  __shared__ __align__(16) short QL[128 * 128];   // 32 KB
  __shared__ __align__(16) short SL[32 * 128];    //  8 KB
  const int t = threadIdx.x, w = t >> 6, l = t & 63;
  const int l15 = l & 15, lq = l >> 4;
  const int h = blockIdx.y, eq = blockIdx.z;
  const int n = b * HEADS + h;
  const int xspan = XLEN / gridDim.x;

  f32x4 ka[2][2];
  #pragma unroll
  for (int i = 0; i < 2; ++i)
    #pragma unroll
    for (int j = 0; j < 2; ++j) ka[i][j] = {0.f, 0.f, 0.f, 0.f};

  for (int ch = 0; ch < xspan / 128; ++ch) {
    const int xl0 = blockIdx.x * xspan + ch * 128;
    __syncthreads();
    #pragma unroll
    for (int R = 0; R < 8; ++R) {
      const int idx = R * 256 + t;
      const int d = idx >> 4, c = idx & 15;
      const size_t rb = (((size_t)h * DIMC + d) * XLEN + xl0) * 2;
      *(int4*)((char*)QL + idx * 16) =
          *(const int4*)((const char*)qT + rb + ((c * 16) ^ ((d & 7) << 4)));
    }
    #pragma unroll
    for (int R = 0; R < 2; ++R) {
      const int idx = R * 256 + t;
      const int er = idx >> 4, c = idx & 15;
      const size_t rb = (((size_t)h * DIMC + eq * 32 + er) * XLEN + xl0) * 2;
      *(int4*)((char*)SL + idx * 16) =
          *(const int4*)((const char*)sT + rb + ((c * 16) ^ ((er & 7) << 4)));
    }
    __syncthreads();
    #pragma unroll
    for (int kt2 = 0; kt2 < 4; ++kt2) {
      bf16x8 a0 = ldY(QL, w * 32 + l15,      kt2 * 64 + lq * 16);
      bf16x8 a1 = ldY(QL, w * 32 + 16 + l15, kt2 * 64 + lq * 16);
      #pragma unroll
      for (int nt = 0; nt < 2; ++nt) {
        bf16x8 bs = ldY(SL, nt * 16 + l15, kt2 * 64 + lq * 16);
        ka[0][nt] = MFMA(a0, bs, ka[0][nt]);
        ka[1][nt] = MFMA(a1, bs, ka[1][nt]);
      }
    }
  }
  short* dst = part16 + ((size_t)(blockIdx.x * NHEAD + n)) * 16384;
  #pragma unroll
  for (int mt = 0; mt < 2; ++mt)
    #pragma unroll
    for (int nt = 0; nt < 2; ++nt)
      #pragma unroll
      for (int r = 0; r < 4; ++r) {
        const int d = w * 32 + mt * 16 + lq * 4 + r;
        const int e = eq * 32 + nt * 16 + l15;
        dst[d * DIMC + e] = f2bf(ka[mt][nt][r]);
      }
}

// ---------------------------------------------------------------------------
// Phase 3: k_out10 — continuous 8-frag prefetch rotation (round-16, best).
// 2 barriers/head. 256 thr, grid (64, 8).
// ---------------------------------------------------------------------------
__global__ __launch_bounds__(256) void k_out10(
    const float* __restrict__ x, const float* __restrict__ dwf,
    const float* __restrict__ bfl, const short* __restrict__ Wpk,
    const short* __restrict__ Gpk, const short* __restrict__ katpk,
    const short* __restrict__ Opk, const float* __restrict__ c0,
    const float* __restrict__ outb, float* __restrict__ outp)
{
  __shared__ __align__(16) short Yq[TX * 128], Yv[TX * 128];
  __shared__ __align__(16) short Vx[TX * 128], Tn[TX * 128];
  const int t = threadIdx.x, w = t >> 6, l = t & 63;
  const int l15 = l & 15, lq = l >> 4;
  const int b = blockIdx.y;
  const int x0 = blockIdx.x * TX;

  f32x4 oacc[2][4];
  #pragma unroll
  for (int i = 0; i < 2; ++i)
    #pragma unroll
    for (int j = 0; j < 4; ++j) oacc[i][j] = {0.f, 0.f, 0.f, 0.f};
  float c0v[8];
  #pragma unroll
  for (int nt = 0; nt < 8; ++nt) c0v[nt] = c0[nt * 16 + l15];

  stage2(x, dwf, bfl, b, x0, t, Yq, Yv, 0, 2);
  __syncthreads();

  for (int h = 0; h < HEADS; ++h) {
    const int n = b * HEADS + h;
    const short* WvHi = Wpk + (size_t)((2 * 8 + h) * 2 + 0) * 16384;
    const short* WvLo = Wpk + (size_t)((2 * 8 + h) * 2 + 1) * 16384;
    const short* Wg   = Gpk + (size_t)h * 16384;
    const short* Kp   = katpk + (size_t)n * 16384;
    const short* OHi  = Opk + (size_t)(h * 2 + 0) * 16384;
    const short* OLo  = Opk + (size_t)(h * 2 + 1) * 16384;

    bf16x8 P0[8], P1[8], Q0[8], Q1[8];
    #pragma unroll
    for (int i = 0; i < 8; ++i) P0[i] = LDW(WvHi, 0, i);
    #pragma unroll
    for (int i = 0; i < 8; ++i) P1[i] = LDW(WvHi, 1, i);
    #pragma unroll
    for (int i = 0; i < 8; ++i) Q0[i] = LDW(WvHi, 2, i);
    #pragma unroll
    for (int i = 0; i < 8; ++i) Q1[i] = LDW(WvHi, 3, i);

    // ---- V GEMM hi (rotate buffers -> WvLo) ----
    f32x4 va[8];
    #pragma unroll
    for (int j = 0; j < 8; ++j) va[j] = {0.f, 0.f, 0.f, 0.f};
    {
      bf16x8 a = ldY(Yv, w * 16 + l15, 0 * 64 + lq * 16);
      #pragma unroll
      for (int nt = 0; nt < 8; ++nt) va[nt] = MFMA(a, P0[nt], va[nt]);
    }
    #pragma unroll
    for (int i = 0; i < 8; ++i) P0[i] = LDW(WvLo, 0, i);
    {
      bf16x8 a = ldY(Yv, w * 16 + l15, 1 * 64 + lq * 16);
      #pragma unroll
      for (int nt = 0; nt < 8; ++nt) va[nt] = MFMA(a, P1[nt], va[nt]);
    }
    #pragma unroll
    for (int i = 0; i < 8; ++i) P1[i] = LDW(WvLo, 1, i);
    {
      bf16x8 a = ldY(Yv, w * 16 + l15, 2 * 64 + lq * 16);
      #pragma unroll
      for (int nt = 0; nt < 8; ++nt) va[nt] = MFMA(a, Q0[nt], va[nt]);
    }
    #pragma unroll
    for (int i = 0; i < 8; ++i) Q0[i] = LDW(WvLo, 2, i);
    {
      bf16x8 a = ldY(Yv, w * 16 + l15, 3 * 64 + lq * 16);
      #pragma unroll
      for (int nt = 0; nt < 8; ++nt) va[nt] = MFMA(a, Q1[nt], va[nt]);
    }
    #pragma unroll
    for (int i = 0; i < 8; ++i) Q1[i] = LDW(WvLo, 3, i);

    // ---- V GEMM lo (rotate -> Wg) ----
    {
      bf16x8 a = ldY(Yv, w * 16 + l15, 0 * 64 + lq * 16);
      #pragma unroll
      for (int nt = 0; nt < 8; ++nt) va[nt] = MFMA(a, P0[nt], va[nt]);
    }
    #pragma unroll
    for (int i = 0; i < 8; ++i) P0[i] = LDW(Wg, 0, i);
    {
      bf16x8 a = ldY(Yv, w * 16 + l15, 1 * 64 + lq * 16);
      #pragma unroll
      for (int nt = 0; nt < 8; ++nt) va[nt] = MFMA(a, P1[nt], va[nt]);
    }
    #pragma unroll
    for (int i = 0; i < 8; ++i) P1[i] = LDW(Wg, 1, i);
    {
      bf16x8 a = ldY(Yv, w * 16 + l15, 2 * 64 + lq * 16);
      #pragma unroll
      for (int nt = 0; nt < 8; ++nt) va[nt] = MFMA(a, Q0[nt], va[nt]);
    }
    #pragma unroll
    for (int i = 0; i < 8; ++i) Q0[i] = LDW(Wg, 2, i);
    {
      bf16x8 a = ldY(Yv, w * 16 + l15, 3 * 64 + lq * 16);
      #pragma unroll
      for (int nt = 0; nt < 8; ++nt) va[nt] = MFMA(a, Q1[nt], va[nt]);
    }
    #pragma unroll
    for (int i = 0; i < 8; ++i) Q1[i] = LDW(Wg, 3, i);

    // ---- write V[x][d] (own wave rows; va dies here) ----
    #pragma unroll
    for (int nt = 0; nt < 8; ++nt) {
      const int dd = nt * 16 + l15;
      #pragma unroll
      for (int r = 0; r < 4; ++r) {
        const int xr = w * 16 + lq * 4 + r;
        *(short*)((char*)Vx + xr * 256 + ((dd * 2) ^ ((xr & 7) << 4))) = f2bf(va[nt][r]);
      }
    }

    // ---- gate GEMM (rotate -> Kp) ----
    f32x4 ga[8];
    #pragma unroll
    for (int j = 0; j < 8; ++j) ga[j] = {0.f, 0.f, 0.f, 0.f};
    {
      bf16x8 a = ldY(Yq, w * 16 + l15, 0 * 64 + lq * 16);
      #pragma unroll
      for (int nt = 0; nt < 8; ++nt) ga[nt] = MFMA(a, P0[nt], ga[nt]);
    }
    #pragma unroll
    for (int i = 0; i < 8; ++i) P0[i] = LDW(Kp, 0, i);
    {
      bf16x8 a = ldY(Yq, w * 16 + l15, 1 * 64 + lq * 16);
      #pragma unroll
      for (int nt = 0; nt < 8; ++nt) ga[nt] = MFMA(a, P1[nt], ga[nt]);
    }
    #pragma unroll
    for (int i = 0; i < 8; ++i) P1[i] = LDW(Kp, 1, i);
    {
      bf16x8 a = ldY(Yq, w * 16 + l15, 2 * 64 + lq * 16);
      #pragma unroll
      for (int nt = 0; nt < 8; ++nt) ga[nt] = MFMA(a, Q0[nt], ga[nt]);
    }
    #pragma unroll
    for (int i = 0; i < 8; ++i) Q0[i] = LDW(Kp, 2, i);
    {
      bf16x8 a = ldY(Yq, w * 16 + l15, 3 * 64 + lq * 16);
      #pragma unroll
      for (int nt = 0; nt < 8; ++nt) ga[nt] = MFMA(a, Q1[nt], ga[nt]);
    }
    #pragma unroll
    for (int i = 0; i < 8; ++i) Q1[i] = LDW(Kp, 3, i);

    // ---- fold sigmoid into ga ----
    #pragma unroll
    for (int nt = 0; nt < 8; ++nt)
      #pragma unroll
      for (int r = 0; r < 4; ++r)
        ga[nt][r] = 1.f / (1.f + __expf(-(ga[nt][r] + c0v[nt])));

    // ---- KV GEMM (A = own Vx rows; rotate P -> O frags) ----
    f32x4 kv[8];
    #pragma unroll
    for (int j = 0; j < 8; ++j) kv[j] = {0.f, 0.f, 0.f, 0.f};
    {
      bf16x8 a = ldY(Vx, w * 16 + l15, 0 * 64 + lq * 16);
      #pragma unroll
      for (int nt = 0; nt < 8; ++nt) kv[nt] = MFMA(a, P0[nt], kv[nt]);
    }
    #pragma unroll
    for (int i = 0; i < 8; ++i)
      P0[i] = (*(const bf16x8*)&OHi[((((w * 2 + (i >> 2)) * 4 + (i & 3))) * 64 + l) * 8]);
    {
      bf16x8 a = ldY(Vx, w * 16 + l15, 1 * 64 + lq * 16);
      #pragma unroll
      for (int nt = 0; nt < 8; ++nt) kv[nt] = MFMA(a, P1[nt], kv[nt]);
    }
    #pragma unroll
    for (int i = 0; i < 8; ++i)
      P1[i] = (*(const bf16x8*)&OLo[((((w * 2 + (i >> 2)) * 4 + (i & 3))) * 64 + l) * 8]);
    {
      bf16x8 a = ldY(Vx, w * 16 + l15, 2 * 64 + lq * 16);
      #pragma unroll
      for (int nt = 0; nt < 8; ++nt) kv[nt] = MFMA(a, Q0[nt], kv[nt]);
    }
    {
      bf16x8 a = ldY(Vx, w * 16 + l15, 3 * 64 + lq * 16);
      #pragma unroll
      for (int nt = 0; nt < 8; ++nt) kv[nt] = MFMA(a, Q1[nt], kv[nt]);
    }

    // ---- combine: T = KV + sig * V (V re-read from own Vx rows) ----
    #pragma unroll
    for (int nt = 0; nt < 8; ++nt) {
      const int e = nt * 16 + l15;
      #pragma unroll
      for (int r = 0; r < 4; ++r) {
        const int xr = w * 16 + lq * 4 + r;
        float vv = bf2f(*(const short*)((const char*)Vx + xr * 256 + ((e * 2) ^ ((xr & 7) << 4))));
        *(short*)((char*)Tn + xr * 256 + ((e * 2) ^ ((xr & 7) << 4))) =
            f2bf(kv[nt][r] + ga[nt][r] * vv);
      }
    }
    __syncthreads();                                   // Tn complete

    // ---- out-projection accumulate from P0 (hi) / P1 (lo) ----
    #pragma unroll
    for (int kt = 0; kt < 4; ++kt) {
      #pragma unroll
      for (int nt4 = 0; nt4 < 4; ++nt4) {
        bf16x8 bt = ldY(Tn, nt4 * 16 + l15, kt * 64 + lq * 16);
        oacc[0][nt4] = MFMA(P0[0 * 4 + kt], bt, oacc[0][nt4]);
        oacc[0][nt4] = MFMA(P1[0 * 4 + kt], bt, oacc[0][nt4]);
        oacc[1][nt4] = MFMA(P0[1 * 4 + kt], bt, oacc[1][nt4]);
        oacc[1][nt4] = MFMA(P1[1 * 4 + kt], bt, oacc[1][nt4]);
      }
    }
    __syncthreads();   // Tn reads done before next head's combine overwrites
  }
  #pragma unroll
  for (int mt = 0; mt < 2; ++mt) {
    #pragma unroll
    for (int nt4 = 0; nt4 < 4; ++nt4) {
      #pragma unroll
      for (int r = 0; r < 4; ++r) {
        const int o = w * 32 + mt * 16 + lq * 4 + r;
        const int xx = x0 + nt4 * 16 + l15;
        outp[((size_t)b * DIMC + o) * XLEN + xx] = oacc[mt][nt4][r] + outb[o];
      }
    }
  }
}

// ---------------------------------------------------------------------------
extern "C" void kernel_launch(void* const* d_in, const int* in_sizes, int n_in,
                              void* d_out, int out_size, void* d_ws, size_t ws_size,
                              hipStream_t stream) {
  (void)in_sizes; (void)n_in; (void)out_size;
  const float* x = (const float*)d_in[0];
  // q: 1..6, k: 7..12, v: 13..18 (dw,g,b,m,v,pw), gt: 19..24, out_w:25, out_b:26

  char* ws = (char*)d_ws;
  short* katpk = (short*)(ws);                       // 2 MB
  short* Wpk   = (short*)(ws + 2097152);             // 1.5 MB
  short* Opk   = (short*)(ws + 3670016);             // 512 KB
  short* Gpk   = (short*)(ws + 4194304);             // 256 KB
  float* WgF   = (float*)(ws + 4456448);             // 512 KB
  float* Gt    = (float*)(ws + 4980736);             // 64 KB
  float* c0    = (float*)(ws + 5046272);             // 512 B
  float* dwf   = (float*)(ws + 5046784);             // 4.6 KB
  float* bfl   = (float*)(ws + 5051392);             // 1.5 KB
  constexpr size_t BASE = 5052928;
  const int splits = (ws_size >= (size_t)38607360) ? 8 : 4;
  short* part16 = (short*)(ws + BASE);
  short* qT = (short*)(ws + BASE + (size_t)splits * 2097152);
  short* sT = (short*)((char*)qT + 8388608);
  if (ws_size < (size_t)30218752) return;   // loud-fail (proven bound)

  k_prep1<<<4, 128, 0, stream>>>(
      (const float*)d_in[1],  (const float*)d_in[2],  (const float*)d_in[3],
      (const float*)d_in[4],  (const float*)d_in[5],
      (const float*)d_in[7],  (const float*)d_in[8],  (const float*)d_in[9],
      (const float*)d_in[10], (const float*)d_in[11],
      (const float*)d_in[13], (const float*)d_in[14], (const float*)d_in[15],
      (const float*)d_in[16], (const float*)d_in[17],
      (const float*)d_in[24], (const float*)d_in[19], (const float*)d_in[20],
      (const float*)d_in[21], (const float*)d_in[22], (const float*)d_in[23],
      dwf, bfl, Gt, c0);

  k_wg<<<dim3(8, 8), 256, 0, stream>>>((const float*)d_in[6], Gt, WgF);

  k_pack<<<72, 256, 0, stream>>>((const float*)d_in[6], (const float*)d_in[12],
                                 (const float*)d_in[18], (const float*)d_in[25],
                                 WgF, Wpk, Opk, Gpk);

  for (int b = 0; b < BATCH; ++b) {
    k_proj<<<dim3(XLEN / TX, HEADS), 256, 0, stream>>>(x, dwf, bfl, Wpk, qT, sT, b);
    k_katg<<<dim3(splits, HEADS, 4), 256, 0, stream>>>(qT, sT, part16, b);
  }
  k_red<<<NHEAD, 256, 0, stream>>>(part16, katpk, splits);
  k_out10<<<dim3(XLEN / TX, BATCH), 256, 0, stream>>>(x, dwf, bfl, Wpk, Gpk, katpk,
                                                      Opk, c0, (const float*)d_in[26],
                                                      (float*)d_out);
}

// Round 19
// 437.151 us; speedup vs baseline: 2.3553x; 1.0527x over previous
//
#include <hip/hip_runtime.h>
#include <hip/hip_bf16.h>

#define DIMC   128
#define HEADS  8
#define BATCH  8
#define XLEN   4096
#define NHEAD  64
#define EPSV   1e-5f
#define SCALEF 0.08838834764831845f   // 128^-0.5
#define TX     64

typedef __attribute__((ext_vector_type(8))) short bf16x8;
typedef __attribute__((ext_vector_type(4))) float f32x4;
#define MFMA(a,b,c) __builtin_amdgcn_mfma_f32_16x16x32_bf16((a),(b),(c),0,0,0)
// weight B-frag load from GLOBAL table laid out [(kt*8+nt)][lane][8]
#define LDW(tbl, kt, nt) (*(const bf16x8*)&(tbl)[(((kt) * 8 + (nt)) * 64 + l) * 8])

__device__ __forceinline__ short f2bf(float f) {
  union { float f; unsigned u; } v; v.f = f;
  return (short)((v.u + 0x7fffu + ((v.u >> 16) & 1u)) >> 16);
}
__device__ __forceinline__ float bf2f(short h) {
  union { unsigned u; float f; } v; v.u = ((unsigned)(unsigned short)h) << 16;
  return v.f;
}
__device__ __forceinline__ unsigned pk2(float a, float b) {
  return (unsigned)(unsigned short)f2bf(a) | ((unsigned)(unsigned short)f2bf(b) << 16);
}

// LDS fragment loads. Row-major bf16 tiles, XOR-swizzled: byte ^= (row&7)<<4.
__device__ __forceinline__ bf16x8 ldY(const short* Y, int row, int kcb) {
  return *(const bf16x8*)((const char*)Y + row*256 + (kcb ^ ((row&7)<<4)));
}

// ---------------------------------------------------------------------------
// prep kernels (merged: 3 launches total) — unchanged from round 11
// ---------------------------------------------------------------------------
__global__ void k_prep1(const float* dw0, const float* g0, const float* b0, const float* m0, const float* v0,
                        const float* dw1, const float* g1, const float* b1, const float* m1, const float* v1,
                        const float* dw2, const float* g2, const float* b2, const float* m2, const float* v2,
                        const float* gt_pw, const float* gt_dw, const float* gt_g,
                        const float* gt_b, const float* gt_m, const float* gt_v,
                        float* __restrict__ dwf, float* __restrict__ bfl,
                        float* __restrict__ Gt, float* __restrict__ c0) {
  int p = blockIdx.x, c = threadIdx.x;
  if (p < 3) {
    const float* dw = p == 0 ? dw0 : p == 1 ? dw1 : dw2;
    const float* g  = p == 0 ? g0  : p == 1 ? g1  : g2;
    const float* bb = p == 0 ? b0  : p == 1 ? b1  : b2;
    const float* m  = p == 0 ? m0  : p == 1 ? m1  : m2;
    const float* vv = p == 0 ? v0  : p == 1 ? v1  : v2;
    float a = g[c] * rsqrtf(vv[c] + EPSV);
    dwf[(p * DIMC + c) * 3 + 0] = dw[c * 3 + 0] * a;
    dwf[(p * DIMC + c) * 3 + 1] = dw[c * 3 + 1] * a;
    dwf[(p * DIMC + c) * 3 + 2] = dw[c * 3 + 2] * a;
    bfl[p * DIMC + c] = bb[c] - m[c] * a;
  } else {
    int d = c;
    float s = 0.f;
    for (int i = 0; i < DIMC; ++i) {
      float a  = gt_g[i] * rsqrtf(gt_v[i] + EPSV);
      float w1 = gt_dw[i] * a;
      float w0 = gt_b[i] - gt_m[i] * a;
      float pw = gt_pw[d * DIMC + i];
      Gt[i * DIMC + d] = pw * w1;
      s += pw * w0;
    }
    c0[d] = s;
  }
}

__global__ void k_wg(const float* __restrict__ q_pw, const float* __restrict__ Gt,
                     float* __restrict__ WgF) {
  const int h = blockIdx.x, cb = blockIdx.y, t = threadIdx.x;
  const int c = cb * 16 + (t >> 4);
  const int e0 = (t & 15) * 8;
  float acc[8] = {0.f,0.f,0.f,0.f,0.f,0.f,0.f,0.f};
  for (int d = 0; d < DIMC; ++d) {
    float wq = q_pw[((size_t)(h * DIMC + d)) * DIMC + c];
    const float* gr = Gt + d * DIMC + e0;
    #pragma unroll
    for (int j = 0; j < 8; ++j) acc[j] += wq * gr[j];
  }
  float* out = WgF + ((size_t)h * DIMC + c) * DIMC + e0;
  #pragma unroll
  for (int j = 0; j < 8; ++j) out[j] = acc[j];
}

__global__ void k_pack(const float* __restrict__ q_pw, const float* __restrict__ k_pw,
                       const float* __restrict__ v_pw, const float* __restrict__ out_w,
                       const float* __restrict__ WgF,
                       short* __restrict__ Wpk, short* __restrict__ Opk,
                       short* __restrict__ Gpk) {
  const int blk = blockIdx.x, t = threadIdx.x;
  if (blk < 48) {
    const int p = blk / 16, h = (blk / 2) & 7, hl = blk & 1;
    const float* pw = p == 0 ? q_pw : p == 1 ? k_pw : v_pw;
    short* dst = Wpk + (size_t)((p * 8 + h) * 2 + hl) * 16384;
    for (int s = t; s < 2048; s += 256) {
      const int l = s & 63, kt = (s >> 6) >> 3, nt = (s >> 6) & 7;
      const int o = h * DIMC + nt * 16 + (l & 15);
      const int cb = kt * 32 + (l >> 4) * 8;
      #pragma unroll
      for (int j = 0; j < 8; ++j) {
        float wv = pw[(size_t)o * DIMC + cb + j];
        short hi = f2bf(wv);
        dst[s * 8 + j] = (hl == 0) ? hi : f2bf(wv - bf2f(hi));
      }
    }
  } else if (blk < 64) {
    const int m = blk - 48, h = m >> 1, hl = m & 1;
    short* dst = Opk + (size_t)(h * 2 + hl) * 16384;
    for (int s = t; s < 2048; s += 256) {
      const int l = s & 63, mt = (s >> 6) >> 2, kt = (s >> 6) & 3;
      const int o = mt * 16 + (l & 15);
      const int ib = h * DIMC + kt * 32 + (l >> 4) * 8;
      #pragma unroll
      for (int j = 0; j < 8; ++j) {
        float wv = out_w[(size_t)o * (DIMC * HEADS) + ib + j];
        short hi = f2bf(wv);
        dst[s * 8 + j] = (hl == 0) ? hi : f2bf(wv - bf2f(hi));
      }
    }
  } else {
    const int h = blk - 64;
    const float* src = WgF + (size_t)h * 16384;
    short* dst = Gpk + (size_t)h * 16384;
    for (int s = t; s < 2048; s += 256) {
      const int l = s & 63, kt = (s >> 6) >> 3, nt = (s >> 6) & 7;
      const int cb = kt * 32 + (l >> 4) * 8, e = nt * 16 + (l & 15);
      #pragma unroll
      for (int j = 0; j < 8; ++j) dst[s * 8 + j] = f2bf(src[(size_t)(cb + j) * DIMC + e]);
    }
  }
}

// sum `splits` bf16 partial kat tiles, scale, pack frags. grid(64)
__global__ __launch_bounds__(256) void k_red(const short* __restrict__ part16,
                                             short* __restrict__ katpk, int splits) {
  __shared__ float sm[DIMC * DIMC];
  const int n = blockIdx.x, t = threadIdx.x;
  for (int i0 = t * 8; i0 < DIMC * DIMC; i0 += 256 * 8) {
    float a[8] = {0.f,0.f,0.f,0.f,0.f,0.f,0.f,0.f};
    for (int s8 = 0; s8 < splits; ++s8) {
      bf16x8 pv = *(const bf16x8*)&part16[((size_t)(s8 * NHEAD + n)) * 16384 + i0];
      #pragma unroll
      for (int j = 0; j < 8; ++j) a[j] += bf2f(pv[j]);
    }
    #pragma unroll
    for (int j = 0; j < 8; ++j) sm[i0 + j] = a[j] * SCALEF;
  }
  __syncthreads();
  short* dst = katpk + (size_t)n * 16384;
  for (int s = t; s < 2048; s += 256) {
    const int l = s & 63, kt = (s >> 6) >> 3, nt = (s >> 6) & 7;
    const int db = kt * 32 + (l >> 4) * 8, e = nt * 16 + (l & 15);
    #pragma unroll
    for (int j = 0; j < 8; ++j) dst[s * 8 + j] = f2bf(sm[(db + j) * DIMC + e]);
  }
}

// ---------------------------------------------------------------------------
// stage Y tiles: dwconv+BN for two projections -> swizzled bf16 LDS [64 x][128 c]
// ---------------------------------------------------------------------------
__device__ __forceinline__ void stage2(const float* __restrict__ x,
    const float* __restrict__ dwf, const float* __restrict__ bfl,
    int b, int xg0, int t, short* Y0, short* Y1, int p0, int p1)
{
  const int xl = t & 63, cg = t >> 6;
  const int xg = xg0 + xl;
  #pragma unroll
  for (int i = 0; i < 16; ++i) {
    const int c = 2 * (cg + 4 * i);
    float v0[2], v1[2];
    #pragma unroll
    for (int u = 0; u < 2; ++u) {
      const int cc = c + u;
      const float* xr = x + ((size_t)b * DIMC + cc) * XLEN + xg;
      float xm = (xg > 0) ? xr[-1] : 0.f;
      float xc = xr[0];
      float xp = (xg < XLEN - 1) ? xr[1] : 0.f;
      const float* d0 = dwf + (p0 * DIMC + cc) * 3;
      const float* d1 = dwf + (p1 * DIMC + cc) * 3;
      v0[u] = xm * d0[0] + xc * d0[1] + xp * d0[2] + bfl[p0 * DIMC + cc];
      v1[u] = xm * d1[0] + xc * d1[1] + xp * d1[2] + bfl[p1 * DIMC + cc];
    }
    const unsigned off = xl * 256 + ((c * 2) ^ ((xl & 7) << 4));
    *(unsigned*)((char*)Y0 + off) = pk2(v0[0], v0[1]);
    *(unsigned*)((char*)Y1 + off) = pk2(v1[0], v1[1]);
  }
}

// ---------------------------------------------------------------------------
// Phase 1: k_proj — per (x-tile, head) for one b: Q/K GEMM (HI-ONLY weights;
// V/gate/out keep hi+lo elsewhere), softmax; dump qT[h][d][x], sT[h][e][x].
// grid (64, 8), 256 thr.
// ---------------------------------------------------------------------------
__global__ __launch_bounds__(256) void k_proj(
    const float* __restrict__ x, const float* __restrict__ dwf,
    const float* __restrict__ bfl, const short* __restrict__ Wpk,
    short* __restrict__ qT, short* __restrict__ sT, int b)
{
  __shared__ __align__(16) short Yq[TX * 128], Yk[TX * 128];
  __shared__ __align__(16) short QT[128 * TX], ST[128 * TX];
  const int t = threadIdx.x, w = t >> 6, l = t & 63;
  const int l15 = l & 15, lq = l >> 4;
  const int h = blockIdx.y;
  const int x0 = blockIdx.x * TX;

  stage2(x, dwf, bfl, b, x0, t, Yq, Yk, 0, 1);
  __syncthreads();

  const short* WqHi = Wpk + (size_t)((0 * 8 + h) * 2 + 0) * 16384;
  const short* WkHi = Wpk + (size_t)((1 * 8 + h) * 2 + 0) * 16384;

  f32x4 qa[8];

  // ---- Q GEMM (hi only), register-prefetched ----
  #pragma unroll
  for (int j = 0; j < 8; ++j) qa[j] = {0.f, 0.f, 0.f, 0.f};
  {
    bf16x8 a0 = ldY(Yq, w * 16 + l15, 0 * 64 + lq * 16);
    bf16x8 a1 = ldY(Yq, w * 16 + l15, 1 * 64 + lq * 16);
    bf16x8 a2 = ldY(Yq, w * 16 + l15, 2 * 64 + lq * 16);
    bf16x8 a3 = ldY(Yq, w * 16 + l15, 3 * 64 + lq * 16);
    bf16x8 h0[8], h1[8];
    #pragma unroll
    for (int nt = 0; nt < 8; ++nt) h0[nt] = LDW(WqHi, 0, nt);
    #pragma unroll
    for (int nt = 0; nt < 8; ++nt) h1[nt] = LDW(WqHi, 1, nt);
    #pragma unroll
    for (int nt = 0; nt < 8; ++nt) qa[nt] = MFMA(a0, h0[nt], qa[nt]);
    #pragma unroll
    for (int nt = 0; nt < 8; ++nt) h0[nt] = LDW(WqHi, 2, nt);
    #pragma unroll
    for (int nt = 0; nt < 8; ++nt) qa[nt] = MFMA(a1, h1[nt], qa[nt]);
    #pragma unroll
    for (int nt = 0; nt < 8; ++nt) h1[nt] = LDW(WqHi, 3, nt);
    #pragma unroll
    for (int nt = 0; nt < 8; ++nt) qa[nt] = MFMA(a2, h0[nt], qa[nt]);
    #pragma unroll
    for (int nt = 0; nt < 8; ++nt) qa[nt] = MFMA(a3, h1[nt], qa[nt]);
  }
  #pragma unroll
  for (int nt = 0; nt < 8; ++nt) {
    const int d = nt * 16 + l15;
    #pragma unroll
    for (int rp = 0; rp < 2; ++rp) {
      const int x2 = w * 16 + lq * 4 + rp * 2;
      *(unsigned*)((char*)QT + d * 128 + ((x2 * 2) ^ ((d & 7) << 4))) =
          pk2(qa[nt][rp * 2], qa[nt][rp * 2 + 1]);
    }
  }

  // ---- K GEMM (hi only), same pattern ----
  #pragma unroll
  for (int j = 0; j < 8; ++j) qa[j] = {0.f, 0.f, 0.f, 0.f};
  {
    bf16x8 a0 = ldY(Yk, w * 16 + l15, 0 * 64 + lq * 16);
    bf16x8 a1 = ldY(Yk, w * 16 + l15, 1 * 64 + lq * 16);
    bf16x8 a2 = ldY(Yk, w * 16 + l15, 2 * 64 + lq * 16);
    bf16x8 a3 = ldY(Yk, w * 16 + l15, 3 * 64 + lq * 16);
    bf16x8 h0[8], h1[8];
    #pragma unroll
    for (int nt = 0; nt < 8; ++nt) h0[nt] = LDW(WkHi, 0, nt);
    #pragma unroll
    for (int nt = 0; nt < 8; ++nt) h1[nt] = LDW(WkHi, 1, nt);
    #pragma unroll
    for (int nt = 0; nt < 8; ++nt) qa[nt] = MFMA(a0, h0[nt], qa[nt]);
    #pragma unroll
    for (int nt = 0; nt < 8; ++nt) h0[nt] = LDW(WkHi, 2, nt);
    #pragma unroll
    for (int nt = 0; nt < 8; ++nt) qa[nt] = MFMA(a1, h1[nt], qa[nt]);
    #pragma unroll
    for (int nt = 0; nt < 8; ++nt) h1[nt] = LDW(WkHi, 3, nt);
    #pragma unroll
    for (int nt = 0; nt < 8; ++nt) qa[nt] = MFMA(a2, h0[nt], qa[nt]);
    #pragma unroll
    for (int nt = 0; nt < 8; ++nt) qa[nt] = MFMA(a3, h1[nt], qa[nt]);
  }
  // in-register row softmax over e
  float inv[4];
  #pragma unroll
  for (int r = 0; r < 4; ++r) {
    float m = qa[0][r];
    #pragma unroll
    for (int nt = 1; nt < 8; ++nt) m = fmaxf(m, qa[nt][r]);
    m = fmaxf(m, __shfl_xor(m, 1)); m = fmaxf(m, __shfl_xor(m, 2));
    m = fmaxf(m, __shfl_xor(m, 4)); m = fmaxf(m, __shfl_xor(m, 8));
    float s = 0.f;
    #pragma unroll
    for (int nt = 0; nt < 8; ++nt) { float e = __expf(qa[nt][r] - m); qa[nt][r] = e; s += e; }
    s += __shfl_xor(s, 1); s += __shfl_xor(s, 2); s += __shfl_xor(s, 4); s += __shfl_xor(s, 8);
    inv[r] = 1.f / s;
  }
  #pragma unroll
  for (int nt = 0; nt < 8; ++nt) {
    const int e = nt * 16 + l15;
    #pragma unroll
    for (int rp = 0; rp < 2; ++rp) {
      const int x2 = w * 16 + lq * 4 + rp * 2;
      *(unsigned*)((char*)ST + e * 128 + ((x2 * 2) ^ ((e & 7) << 4))) =
          pk2(qa[nt][rp * 2] * inv[rp * 2], qa[nt][rp * 2 + 1] * inv[rp * 2 + 1]);
    }
  }
  __syncthreads();

  // coalesced dump: thread t handles row r = t>>1, half = t&1 (64 B each)
  {
    const int r = t >> 1, half = t & 1;
    const size_t row = ((size_t)h * DIMC + r) * XLEN + x0 + half * 32;
    #pragma unroll
    for (int i = 0; i < 4; ++i) {
      const int off = r * 128 + (((half * 64) + i * 16) ^ ((r & 7) << 4));
      *(int4*)(qT + row + i * 8) = *(const int4*)((const char*)QT + off);
      *(int4*)(sT + row + i * 8) = *(const int4*)((const char*)ST + off);
    }
  }
}

// ---------------------------------------------------------------------------
// Phase 2: k_katg — kat partial GEMM over x. grid (splits, 8 h, 4 eq).
// ---------------------------------------------------------------------------
__global__ __launch_bounds__(256) void k_katg(
    const short* __restrict__ qT, const short* __restrict__ sT,
    short* __restrict__ part16, int b)
{
  __shared__ __align__(16) short QL[128 * 128];   // 32 KB
  __shared__ __align__(16) short SL[32 * 128];    //  8 KB
  const int t = threadIdx.x, w = t >> 6, l = t & 63;
  const int l15 = l & 15, lq = l >> 4;
  const int h = blockIdx.y, eq = blockIdx.z;
  const int n = b * HEADS + h;
  const int xspan = XLEN / gridDim.x;

  f32x4 ka[2][2];
  #pragma unroll
  for (int i = 0; i < 2; ++i)
    #pragma unroll
    for (int j = 0; j < 2; ++j) ka[i][j] = {0.f, 0.f, 0.f, 0.f};

  for (int ch = 0; ch < xspan / 128; ++ch) {
    const int xl0 = blockIdx.x * xspan + ch * 128;
    __syncthreads();
    #pragma unroll
    for (int R = 0; R < 8; ++R) {
      const int idx = R * 256 + t;
      const int d = idx >> 4, c = idx & 15;
      const size_t rb = (((size_t)h * DIMC + d) * XLEN + xl0) * 2;
      *(int4*)((char*)QL + idx * 16) =
          *(const int4*)((const char*)qT + rb + ((c * 16) ^ ((d & 7) << 4)));
    }
    #pragma unroll
    for (int R = 0; R < 2; ++R) {
      const int idx = R * 256 + t;
      const int er = idx >> 4, c = idx & 15;
      const size_t rb = (((size_t)h * DIMC + eq * 32 + er) * XLEN + xl0) * 2;
      *(int4*)((char*)SL + idx * 16) =
          *(const int4*)((const char*)sT + rb + ((c * 16) ^ ((er & 7) << 4)));
    }
    __syncthreads();
    #pragma unroll
    for (int kt2 = 0; kt2 < 4; ++kt2) {
      bf16x8 a0 = ldY(QL, w * 32 + l15,      kt2 * 64 + lq * 16);
      bf16x8 a1 = ldY(QL, w * 32 + 16 + l15, kt2 * 64 + lq * 16);
      #pragma unroll
      for (int nt = 0; nt < 2; ++nt) {
        bf16x8 bs = ldY(SL, nt * 16 + l15, kt2 * 64 + lq * 16);
        ka[0][nt] = MFMA(a0, bs, ka[0][nt]);
        ka[1][nt] = MFMA(a1, bs, ka[1][nt]);
      }
    }
  }
  short* dst = part16 + ((size_t)(blockIdx.x * NHEAD + n)) * 16384;
  #pragma unroll
  for (int mt = 0; mt < 2; ++mt)
    #pragma unroll
    for (int nt = 0; nt < 2; ++nt)
      #pragma unroll
      for (int r = 0; r < 4; ++r) {
        const int d = w * 32 + mt * 16 + lq * 4 + r;
        const int e = eq * 32 + nt * 16 + l15;
        dst[d * DIMC + e] = f2bf(ka[mt][nt][r]);
      }
}

// ---------------------------------------------------------------------------
// Phase 3: k_out10 — continuous 8-frag prefetch rotation (round-16, best).
// 2 barriers/head. 256 thr, grid (64, 8). Unchanged.
// ---------------------------------------------------------------------------
__global__ __launch_bounds__(256) void k_out10(
    const float* __restrict__ x, const float* __restrict__ dwf,
    const float* __restrict__ bfl, const short* __restrict__ Wpk,
    const short* __restrict__ Gpk, const short* __restrict__ katpk,
    const short* __restrict__ Opk, const float* __restrict__ c0,
    const float* __restrict__ outb, float* __restrict__ outp)
{
  __shared__ __align__(16) short Yq[TX * 128], Yv[TX * 128];
  __shared__ __align__(16) short Vx[TX * 128], Tn[TX * 128];
  const int t = threadIdx.x, w = t >> 6, l = t & 63;
  const int l15 = l & 15, lq = l >> 4;
  const int b = blockIdx.y;
  const int x0 = blockIdx.x * TX;

  f32x4 oacc[2][4];
  #pragma unroll
  for (int i = 0; i < 2; ++i)
    #pragma unroll
    for (int j = 0; j < 4; ++j) oacc[i][j] = {0.f, 0.f, 0.f, 0.f};
  float c0v[8];
  #pragma unroll
  for (int nt = 0; nt < 8; ++nt) c0v[nt] = c0[nt * 16 + l15];

  stage2(x, dwf, bfl, b, x0, t, Yq, Yv, 0, 2);
  __syncthreads();

  for (int h = 0; h < HEADS; ++h) {
    const int n = b * HEADS + h;
    const short* WvHi = Wpk + (size_t)((2 * 8 + h) * 2 + 0) * 16384;
    const short* WvLo = Wpk + (size_t)((2 * 8 + h) * 2 + 1) * 16384;
    const short* Wg   = Gpk + (size_t)h * 16384;
    const short* Kp   = katpk + (size_t)n * 16384;
    const short* OHi  = Opk + (size_t)(h * 2 + 0) * 16384;
    const short* OLo  = Opk + (size_t)(h * 2 + 1) * 16384;

    bf16x8 P0[8], P1[8], Q0[8], Q1[8];
    #pragma unroll
    for (int i = 0; i < 8; ++i) P0[i] = LDW(WvHi, 0, i);
    #pragma unroll
    for (int i = 0; i < 8; ++i) P1[i] = LDW(WvHi, 1, i);
    #pragma unroll
    for (int i = 0; i < 8; ++i) Q0[i] = LDW(WvHi, 2, i);
    #pragma unroll
    for (int i = 0; i < 8; ++i) Q1[i] = LDW(WvHi, 3, i);

    // ---- V GEMM hi (rotate buffers -> WvLo) ----
    f32x4 va[8];
    #pragma unroll
    for (int j = 0; j < 8; ++j) va[j] = {0.f, 0.f, 0.f, 0.f};
    {
      bf16x8 a = ldY(Yv, w * 16 + l15, 0 * 64 + lq * 16);
      #pragma unroll
      for (int nt = 0; nt < 8; ++nt) va[nt] = MFMA(a, P0[nt], va[nt]);
    }
    #pragma unroll
    for (int i = 0; i < 8; ++i) P0[i] = LDW(WvLo, 0, i);
    {
      bf16x8 a = ldY(Yv, w * 16 + l15, 1 * 64 + lq * 16);
      #pragma unroll
      for (int nt = 0; nt < 8; ++nt) va[nt] = MFMA(a, P1[nt], va[nt]);
    }
    #pragma unroll
    for (int i = 0; i < 8; ++i) P1[i] = LDW(WvLo, 1, i);
    {
      bf16x8 a = ldY(Yv, w * 16 + l15, 2 * 64 + lq * 16);
      #pragma unroll
      for (int nt = 0; nt < 8; ++nt) va[nt] = MFMA(a, Q0[nt], va[nt]);
    }
    #pragma unroll
    for (int i = 0; i < 8; ++i) Q0[i] = LDW(WvLo, 2, i);
    {
      bf16x8 a = ldY(Yv, w * 16 + l15, 3 * 64 + lq * 16);
      #pragma unroll
      for (int nt = 0; nt < 8; ++nt) va[nt] = MFMA(a, Q1[nt], va[nt]);
    }
    #pragma unroll
    for (int i = 0; i < 8; ++i) Q1[i] = LDW(WvLo, 3, i);

    // ---- V GEMM lo (rotate -> Wg) ----
    {
      bf16x8 a = ldY(Yv, w * 16 + l15, 0 * 64 + lq * 16);
      #pragma unroll
      for (int nt = 0; nt < 8; ++nt) va[nt] = MFMA(a, P0[nt], va[nt]);
    }
    #pragma unroll
    for (int i = 0; i < 8; ++i) P0[i] = LDW(Wg, 0, i);
    {
      bf16x8 a = ldY(Yv, w * 16 + l15, 1 * 64 + lq * 16);
      #pragma unroll
      for (int nt = 0; nt < 8; ++nt) va[nt] = MFMA(a, P1[nt], va[nt]);
    }
    #pragma unroll
    for (int i = 0; i < 8; ++i) P1[i] = LDW(Wg, 1, i);
    {
      bf16x8 a = ldY(Yv, w * 16 + l15, 2 * 64 + lq * 16);
      #pragma unroll
      for (int nt = 0; nt < 8; ++nt) va[nt] = MFMA(a, Q0[nt], va[nt]);
    }
    #pragma unroll
    for (int i = 0; i < 8; ++i) Q0[i] = LDW(Wg, 2, i);
    {
      bf16x8 a = ldY(Yv, w * 16 + l15, 3 * 64 + lq * 16);
      #pragma unroll
      for (int nt = 0; nt < 8; ++nt) va[nt] = MFMA(a, Q1[nt], va[nt]);
    }
    #pragma unroll
    for (int i = 0; i < 8; ++i) Q1[i] = LDW(Wg, 3, i);

    // ---- write V[x][d] (own wave rows; va dies here) ----
    #pragma unroll
    for (int nt = 0; nt < 8; ++nt) {
      const int dd = nt * 16 + l15;
      #pragma unroll
      for (int r = 0; r < 4; ++r) {
        const int xr = w * 16 + lq * 4 + r;
        *(short*)((char*)Vx + xr * 256 + ((dd * 2) ^ ((xr & 7) << 4))) = f2bf(va[nt][r]);
      }
    }

    // ---- gate GEMM (rotate -> Kp) ----
    f32x4 ga[8];
    #pragma unroll
    for (int j = 0; j < 8; ++j) ga[j] = {0.f, 0.f, 0.f, 0.f};
    {
      bf16x8 a = ldY(Yq, w * 16 + l15, 0 * 64 + lq * 16);
      #pragma unroll
      for (int nt = 0; nt < 8; ++nt) ga[nt] = MFMA(a, P0[nt], ga[nt]);
    }
    #pragma unroll
    for (int i = 0; i < 8; ++i) P0[i] = LDW(Kp, 0, i);
    {
      bf16x8 a = ldY(Yq, w * 16 + l15, 1 * 64 + lq * 16);
      #pragma unroll
      for (int nt = 0; nt < 8; ++nt) ga[nt] = MFMA(a, P1[nt], ga[nt]);
    }
    #pragma unroll
    for (int i = 0; i < 8; ++i) P1[i] = LDW(Kp, 1, i);
    {
      bf16x8 a = ldY(Yq, w * 16 + l15, 2 * 64 + lq * 16);
      #pragma unroll
      for (int nt = 0; nt < 8; ++nt) ga[nt] = MFMA(a, Q0[nt], ga[nt]);
    }
    #pragma unroll
    for (int i = 0; i < 8; ++i) Q0[i] = LDW(Kp, 2, i);
    {
      bf16x8 a = ldY(Yq, w * 16 + l15, 3 * 64 + lq * 16);
      #pragma unroll
      for (int nt = 0; nt < 8; ++nt) ga[nt] = MFMA(a, Q1[nt], ga[nt]);
    }
    #pragma unroll
    for (int i = 0; i < 8; ++i) Q1[i] = LDW(Kp, 3, i);

    // ---- fold sigmoid into ga ----
    #pragma unroll
    for (int nt = 0; nt < 8; ++nt)
      #pragma unroll
      for (int r = 0; r < 4; ++r)
        ga[nt][r] = 1.f / (1.f + __expf(-(ga[nt][r] + c0v[nt])));

    // ---- KV GEMM (A = own Vx rows; rotate P -> O frags) ----
    f32x4 kv[8];
    #pragma unroll
    for (int j = 0; j < 8; ++j) kv[j] = {0.f, 0.f, 0.f, 0.f};
    {
      bf16x8 a = ldY(Vx, w * 16 + l15, 0 * 64 + lq * 16);
      #pragma unroll
      for (int nt = 0; nt < 8; ++nt) kv[nt] = MFMA(a, P0[nt], kv[nt]);
    }
    #pragma unroll
    for (int i = 0; i < 8; ++i)
      P0[i] = (*(const bf16x8*)&OHi[((((w * 2 + (i >> 2)) * 4 + (i & 3))) * 64 + l) * 8]);
    {
      bf16x8 a = ldY(Vx, w * 16 + l15, 1 * 64 + lq * 16);
      #pragma unroll
      for (int nt = 0; nt < 8; ++nt) kv[nt] = MFMA(a, P1[nt], kv[nt]);
    }
    #pragma unroll
    for (int i = 0; i < 8; ++i)
      P1[i] = (*(const bf16x8*)&OLo[((((w * 2 + (i >> 2)) * 4 + (i & 3))) * 64 + l) * 8]);
    {
      bf16x8 a = ldY(Vx, w * 16 + l15, 2 * 64 + lq * 16);
      #pragma unroll
      for (int nt = 0; nt < 8; ++nt) kv[nt] = MFMA(a, Q0[nt], kv[nt]);
    }
    {
      bf16x8 a = ldY(Vx, w * 16 + l15, 3 * 64 + lq * 16);
      #pragma unroll
      for (int nt = 0; nt < 8; ++nt) kv[nt] = MFMA(a, Q1[nt], kv[nt]);
    }

    // ---- combine: T = KV + sig * V (V re-read from own Vx rows) ----
    #pragma unroll
    for (int nt = 0; nt < 8; ++nt) {
      const int e = nt * 16 + l15;
      #pragma unroll
      for (int r = 0; r < 4; ++r) {
        const int xr = w * 16 + lq * 4 + r;
        float vv = bf2f(*(const short*)((const char*)Vx + xr * 256 + ((e * 2) ^ ((xr & 7) << 4))));
        *(short*)((char*)Tn + xr * 256 + ((e * 2) ^ ((xr & 7) << 4))) =
            f2bf(kv[nt][r] + ga[nt][r] * vv);
      }
    }
    __syncthreads();                                   // Tn complete

    // ---- out-projection accumulate from P0 (hi) / P1 (lo) ----
    #pragma unroll
    for (int kt = 0; kt < 4; ++kt) {
      #pragma unroll
      for (int nt4 = 0; nt4 < 4; ++nt4) {
        bf16x8 bt = ldY(Tn, nt4 * 16 + l15, kt * 64 + lq * 16);
        oacc[0][nt4] = MFMA(P0[0 * 4 + kt], bt, oacc[0][nt4]);
        oacc[0][nt4] = MFMA(P1[0 * 4 + kt], bt, oacc[0][nt4]);
        oacc[1][nt4] = MFMA(P0[1 * 4 + kt], bt, oacc[1][nt4]);
        oacc[1][nt4] = MFMA(P1[1 * 4 + kt], bt, oacc[1][nt4]);
      }
    }
    __syncthreads();   // Tn reads done before next head's combine overwrites
  }
  #pragma unroll
  for (int mt = 0; mt < 2; ++mt) {
    #pragma unroll
    for (int nt4 = 0; nt4 < 4; ++nt4) {
      #pragma unroll
      for (int r = 0; r < 4; ++r) {
        const int o = w * 32 + mt * 16 + lq * 4 + r;
        const int xx = x0 + nt4 * 16 + l15;
        outp[((size_t)b * DIMC + o) * XLEN + xx] = oacc[mt][nt4][r] + outb[o];
      }
    }
  }
}

// ---------------------------------------------------------------------------
extern "C" void kernel_launch(void* const* d_in, const int* in_sizes, int n_in,
                              void* d_out, int out_size, void* d_ws, size_t ws_size,
                              hipStream_t stream) {
  (void)in_sizes; (void)n_in; (void)out_size;
  const float* x = (const float*)d_in[0];
  // q: 1..6, k: 7..12, v: 13..18 (dw,g,b,m,v,pw), gt: 19..24, out_w:25, out_b:26

  char* ws = (char*)d_ws;
  short* katpk = (short*)(ws);                       // 2 MB
  short* Wpk   = (short*)(ws + 2097152);             // 1.5 MB
  short* Opk   = (short*)(ws + 3670016);             // 512 KB
  short* Gpk   = (short*)(ws + 4194304);             // 256 KB
  float* WgF   = (float*)(ws + 4456448);             // 512 KB
  float* Gt    = (float*)(ws + 4980736);             // 64 KB
  float* c0    = (float*)(ws + 5046272);             // 512 B
  float* dwf   = (float*)(ws + 5046784);             // 4.6 KB
  float* bfl   = (float*)(ws + 5051392);             // 1.5 KB
  constexpr size_t BASE = 5052928;
  const int splits = (ws_size >= (size_t)38607360) ? 8 : 4;
  short* part16 = (short*)(ws + BASE);
  short* qT = (short*)(ws + BASE + (size_t)splits * 2097152);
  short* sT = (short*)((char*)qT + 8388608);
  if (ws_size < (size_t)30218752) return;   // loud-fail (proven bound)

  k_prep1<<<4, 128, 0, stream>>>(
      (const float*)d_in[1],  (const float*)d_in[2],  (const float*)d_in[3],
      (const float*)d_in[4],  (const float*)d_in[5],
      (const float*)d_in[7],  (const float*)d_in[8],  (const float*)d_in[9],
      (const float*)d_in[10], (const float*)d_in[11],
      (const float*)d_in[13], (const float*)d_in[14], (const float*)d_in[15],
      (const float*)d_in[16], (const float*)d_in[17],
      (const float*)d_in[24], (const float*)d_in[19], (const float*)d_in[20],
      (const float*)d_in[21], (const float*)d_in[22], (const float*)d_in[23],
      dwf, bfl, Gt, c0);

  k_wg<<<dim3(8, 8), 256, 0, stream>>>((const float*)d_in[6], Gt, WgF);

  k_pack<<<72, 256, 0, stream>>>((const float*)d_in[6], (const float*)d_in[12],
                                 (const float*)d_in[18], (const float*)d_in[25],
                                 WgF, Wpk, Opk, Gpk);

  for (int b = 0; b < BATCH; ++b) {
    k_proj<<<dim3(XLEN / TX, HEADS), 256, 0, stream>>>(x, dwf, bfl, Wpk, qT, sT, b);
    k_katg<<<dim3(splits, HEADS, 4), 256, 0, stream>>>(qT, sT, part16, b);
  }
  k_red<<<NHEAD, 256, 0, stream>>>(part16, katpk, splits);
  k_out10<<<dim3(XLEN / TX, BATCH), 256, 0, stream>>>(x, dwf, bfl, Wpk, Gpk, katpk,
                                                      Opk, c0, (const float*)d_in[26],
                                                      (float*)d_out);
}

// Round 20
// 409.490 us; speedup vs baseline: 2.5144x; 1.0676x over previous
//
#include <hip/hip_runtime.h>
#include <hip/hip_bf16.h>

#define DIMC   128
#define HEADS  8
#define BATCH  8
#define XLEN   4096
#define NHEAD  64
#define EPSV   1e-5f
#define SCALEF 0.08838834764831845f   // 128^-0.5
#define TX     64

typedef __attribute__((ext_vector_type(8))) short bf16x8;
typedef __attribute__((ext_vector_type(4))) float f32x4;
#define MFMA(a,b,c) __builtin_amdgcn_mfma_f32_16x16x32_bf16((a),(b),(c),0,0,0)
// weight B-frag load from GLOBAL table laid out [(kt*8+nt)][lane][8]
#define LDW(tbl, kt, nt) (*(const bf16x8*)&(tbl)[(((kt) * 8 + (nt)) * 64 + l) * 8])

__device__ __forceinline__ short f2bf(float f) {
  union { float f; unsigned u; } v; v.f = f;
  return (short)((v.u + 0x7fffu + ((v.u >> 16) & 1u)) >> 16);
}
__device__ __forceinline__ float bf2f(short h) {
  union { unsigned u; float f; } v; v.u = ((unsigned)(unsigned short)h) << 16;
  return v.f;
}
__device__ __forceinline__ unsigned pk2(float a, float b) {
  return (unsigned)(unsigned short)f2bf(a) | ((unsigned)(unsigned short)f2bf(b) << 16);
}

// LDS fragment loads. Row-major bf16 tiles, XOR-swizzled: byte ^= (row&7)<<4.
__device__ __forceinline__ bf16x8 ldY(const short* Y, int row, int kcb) {
  return *(const bf16x8*)((const char*)Y + row*256 + (kcb ^ ((row&7)<<4)));
}

// ---------------------------------------------------------------------------
// prep kernels (merged: 3 launches total) — unchanged from round 11
// ---------------------------------------------------------------------------
__global__ void k_prep1(const float* dw0, const float* g0, const float* b0, const float* m0, const float* v0,
                        const float* dw1, const float* g1, const float* b1, const float* m1, const float* v1,
                        const float* dw2, const float* g2, const float* b2, const float* m2, const float* v2,
                        const float* gt_pw, const float* gt_dw, const float* gt_g,
                        const float* gt_b, const float* gt_m, const float* gt_v,
                        float* __restrict__ dwf, float* __restrict__ bfl,
                        float* __restrict__ Gt, float* __restrict__ c0) {
  int p = blockIdx.x, c = threadIdx.x;
  if (p < 3) {
    const float* dw = p == 0 ? dw0 : p == 1 ? dw1 : dw2;
    const float* g  = p == 0 ? g0  : p == 1 ? g1  : g2;
    const float* bb = p == 0 ? b0  : p == 1 ? b1  : b2;
    const float* m  = p == 0 ? m0  : p == 1 ? m1  : m2;
    const float* vv = p == 0 ? v0  : p == 1 ? v1  : v2;
    float a = g[c] * rsqrtf(vv[c] + EPSV);
    dwf[(p * DIMC + c) * 3 + 0] = dw[c * 3 + 0] * a;
    dwf[(p * DIMC + c) * 3 + 1] = dw[c * 3 + 1] * a;
    dwf[(p * DIMC + c) * 3 + 2] = dw[c * 3 + 2] * a;
    bfl[p * DIMC + c] = bb[c] - m[c] * a;
  } else {
    int d = c;
    float s = 0.f;
    for (int i = 0; i < DIMC; ++i) {
      float a  = gt_g[i] * rsqrtf(gt_v[i] + EPSV);
      float w1 = gt_dw[i] * a;
      float w0 = gt_b[i] - gt_m[i] * a;
      float pw = gt_pw[d * DIMC + i];
      Gt[i * DIMC + d] = pw * w1;
      s += pw * w0;
    }
    c0[d] = s;
  }
}

__global__ void k_wg(const float* __restrict__ q_pw, const float* __restrict__ Gt,
                     float* __restrict__ WgF) {
  const int h = blockIdx.x, cb = blockIdx.y, t = threadIdx.x;
  const int c = cb * 16 + (t >> 4);
  const int e0 = (t & 15) * 8;
  float acc[8] = {0.f,0.f,0.f,0.f,0.f,0.f,0.f,0.f};
  for (int d = 0; d < DIMC; ++d) {
    float wq = q_pw[((size_t)(h * DIMC + d)) * DIMC + c];
    const float* gr = Gt + d * DIMC + e0;
    #pragma unroll
    for (int j = 0; j < 8; ++j) acc[j] += wq * gr[j];
  }
  float* out = WgF + ((size_t)h * DIMC + c) * DIMC + e0;
  #pragma unroll
  for (int j = 0; j < 8; ++j) out[j] = acc[j];
}

__global__ void k_pack(const float* __restrict__ q_pw, const float* __restrict__ k_pw,
                       const float* __restrict__ v_pw, const float* __restrict__ out_w,
                       const float* __restrict__ WgF,
                       short* __restrict__ Wpk, short* __restrict__ Opk,
                       short* __restrict__ Gpk) {
  const int blk = blockIdx.x, t = threadIdx.x;
  if (blk < 48) {
    const int p = blk / 16, h = (blk / 2) & 7, hl = blk & 1;
    const float* pw = p == 0 ? q_pw : p == 1 ? k_pw : v_pw;
    short* dst = Wpk + (size_t)((p * 8 + h) * 2 + hl) * 16384;
    for (int s = t; s < 2048; s += 256) {
      const int l = s & 63, kt = (s >> 6) >> 3, nt = (s >> 6) & 7;
      const int o = h * DIMC + nt * 16 + (l & 15);
      const int cb = kt * 32 + (l >> 4) * 8;
      #pragma unroll
      for (int j = 0; j < 8; ++j) {
        float wv = pw[(size_t)o * DIMC + cb + j];
        short hi = f2bf(wv);
        dst[s * 8 + j] = (hl == 0) ? hi : f2bf(wv - bf2f(hi));
      }
    }
  } else if (blk < 64) {
    const int m = blk - 48, h = m >> 1, hl = m & 1;
    short* dst = Opk + (size_t)(h * 2 + hl) * 16384;
    for (int s = t; s < 2048; s += 256) {
      const int l = s & 63, mt = (s >> 6) >> 2, kt = (s >> 6) & 3;
      const int o = mt * 16 + (l & 15);
      const int ib = h * DIMC + kt * 32 + (l >> 4) * 8;
      #pragma unroll
      for (int j = 0; j < 8; ++j) {
        float wv = out_w[(size_t)o * (DIMC * HEADS) + ib + j];
        short hi = f2bf(wv);
        dst[s * 8 + j] = (hl == 0) ? hi : f2bf(wv - bf2f(hi));
      }
    }
  } else {
    const int h = blk - 64;
    const float* src = WgF + (size_t)h * 16384;
    short* dst = Gpk + (size_t)h * 16384;
    for (int s = t; s < 2048; s += 256) {
      const int l = s & 63, kt = (s >> 6) >> 3, nt = (s >> 6) & 7;
      const int cb = kt * 32 + (l >> 4) * 8, e = nt * 16 + (l & 15);
      #pragma unroll
      for (int j = 0; j < 8; ++j) dst[s * 8 + j] = f2bf(src[(size_t)(cb + j) * DIMC + e]);
    }
  }
}

// sum `splits` bf16 partial kat tiles, scale, pack frags. grid(64)
__global__ __launch_bounds__(256) void k_red(const short* __restrict__ part16,
                                             short* __restrict__ katpk, int splits) {
  __shared__ float sm[DIMC * DIMC];
  const int n = blockIdx.x, t = threadIdx.x;
  for (int i0 = t * 8; i0 < DIMC * DIMC; i0 += 256 * 8) {
    float a[8] = {0.f,0.f,0.f,0.f,0.f,0.f,0.f,0.f};
    for (int s8 = 0; s8 < splits; ++s8) {
      bf16x8 pv = *(const bf16x8*)&part16[((size_t)(s8 * NHEAD + n)) * 16384 + i0];
      #pragma unroll
      for (int j = 0; j < 8; ++j) a[j] += bf2f(pv[j]);
    }
    #pragma unroll
    for (int j = 0; j < 8; ++j) sm[i0 + j] = a[j] * SCALEF;
  }
  __syncthreads();
  short* dst = katpk + (size_t)n * 16384;
  for (int s = t; s < 2048; s += 256) {
    const int l = s & 63, kt = (s >> 6) >> 3, nt = (s >> 6) & 7;
    const int db = kt * 32 + (l >> 4) * 8, e = nt * 16 + (l & 15);
    #pragma unroll
    for (int j = 0; j < 8; ++j) dst[s * 8 + j] = f2bf(sm[(db + j) * DIMC + e]);
  }
}

// ---------------------------------------------------------------------------
// stage Y tiles: dwconv+BN for two projections -> swizzled bf16 LDS [64 x][128 c]
// ---------------------------------------------------------------------------
__device__ __forceinline__ void stage2(const float* __restrict__ x,
    const float* __restrict__ dwf, const float* __restrict__ bfl,
    int b, int xg0, int t, short* Y0, short* Y1, int p0, int p1)
{
  const int xl = t & 63, cg = t >> 6;
  const int xg = xg0 + xl;
  #pragma unroll
  for (int i = 0; i < 16; ++i) {
    const int c = 2 * (cg + 4 * i);
    float v0[2], v1[2];
    #pragma unroll
    for (int u = 0; u < 2; ++u) {
      const int cc = c + u;
      const float* xr = x + ((size_t)b * DIMC + cc) * XLEN + xg;
      float xm = (xg > 0) ? xr[-1] : 0.f;
      float xc = xr[0];
      float xp = (xg < XLEN - 1) ? xr[1] : 0.f;
      const float* d0 = dwf + (p0 * DIMC + cc) * 3;
      const float* d1 = dwf + (p1 * DIMC + cc) * 3;
      v0[u] = xm * d0[0] + xc * d0[1] + xp * d0[2] + bfl[p0 * DIMC + cc];
      v1[u] = xm * d1[0] + xc * d1[1] + xp * d1[2] + bfl[p1 * DIMC + cc];
    }
    const unsigned off = xl * 256 + ((c * 2) ^ ((xl & 7) << 4));
    *(unsigned*)((char*)Y0 + off) = pk2(v0[0], v0[1]);
    *(unsigned*)((char*)Y1 + off) = pk2(v1[0], v1[1]);
  }
}

// ---------------------------------------------------------------------------
// Phase 1: k_proj — Q/K GEMM with HI-ONLY weights (r19-validated), softmax;
// dump qT[h][d][x], sT[h][e][x]. grid (64, 8), 256 thr.
// ---------------------------------------------------------------------------
__global__ __launch_bounds__(256) void k_proj(
    const float* __restrict__ x, const float* __restrict__ dwf,
    const float* __restrict__ bfl, const short* __restrict__ Wpk,
    short* __restrict__ qT, short* __restrict__ sT, int b)
{
  __shared__ __align__(16) short Yq[TX * 128], Yk[TX * 128];
  __shared__ __align__(16) short QT[128 * TX], ST[128 * TX];
  const int t = threadIdx.x, w = t >> 6, l = t & 63;
  const int l15 = l & 15, lq = l >> 4;
  const int h = blockIdx.y;
  const int x0 = blockIdx.x * TX;

  stage2(x, dwf, bfl, b, x0, t, Yq, Yk, 0, 1);
  __syncthreads();

  const short* WqHi = Wpk + (size_t)((0 * 8 + h) * 2 + 0) * 16384;
  const short* WkHi = Wpk + (size_t)((1 * 8 + h) * 2 + 0) * 16384;

  f32x4 qa[8];

  // ---- Q GEMM (hi only), register-prefetched ----
  #pragma unroll
  for (int j = 0; j < 8; ++j) qa[j] = {0.f, 0.f, 0.f, 0.f};
  {
    bf16x8 a0 = ldY(Yq, w * 16 + l15, 0 * 64 + lq * 16);
    bf16x8 a1 = ldY(Yq, w * 16 + l15, 1 * 64 + lq * 16);
    bf16x8 a2 = ldY(Yq, w * 16 + l15, 2 * 64 + lq * 16);
    bf16x8 a3 = ldY(Yq, w * 16 + l15, 3 * 64 + lq * 16);
    bf16x8 h0[8], h1[8];
    #pragma unroll
    for (int nt = 0; nt < 8; ++nt) h0[nt] = LDW(WqHi, 0, nt);
    #pragma unroll
    for (int nt = 0; nt < 8; ++nt) h1[nt] = LDW(WqHi, 1, nt);
    #pragma unroll
    for (int nt = 0; nt < 8; ++nt) qa[nt] = MFMA(a0, h0[nt], qa[nt]);
    #pragma unroll
    for (int nt = 0; nt < 8; ++nt) h0[nt] = LDW(WqHi, 2, nt);
    #pragma unroll
    for (int nt = 0; nt < 8; ++nt) qa[nt] = MFMA(a1, h1[nt], qa[nt]);
    #pragma unroll
    for (int nt = 0; nt < 8; ++nt) h1[nt] = LDW(WqHi, 3, nt);
    #pragma unroll
    for (int nt = 0; nt < 8; ++nt) qa[nt] = MFMA(a2, h0[nt], qa[nt]);
    #pragma unroll
    for (int nt = 0; nt < 8; ++nt) qa[nt] = MFMA(a3, h1[nt], qa[nt]);
  }
  #pragma unroll
  for (int nt = 0; nt < 8; ++nt) {
    const int d = nt * 16 + l15;
    #pragma unroll
    for (int rp = 0; rp < 2; ++rp) {
      const int x2 = w * 16 + lq * 4 + rp * 2;
      *(unsigned*)((char*)QT + d * 128 + ((x2 * 2) ^ ((d & 7) << 4))) =
          pk2(qa[nt][rp * 2], qa[nt][rp * 2 + 1]);
    }
  }

  // ---- K GEMM (hi only), same pattern ----
  #pragma unroll
  for (int j = 0; j < 8; ++j) qa[j] = {0.f, 0.f, 0.f, 0.f};
  {
    bf16x8 a0 = ldY(Yk, w * 16 + l15, 0 * 64 + lq * 16);
    bf16x8 a1 = ldY(Yk, w * 16 + l15, 1 * 64 + lq * 16);
    bf16x8 a2 = ldY(Yk, w * 16 + l15, 2 * 64 + lq * 16);
    bf16x8 a3 = ldY(Yk, w * 16 + l15, 3 * 64 + lq * 16);
    bf16x8 h0[8], h1[8];
    #pragma unroll
    for (int nt = 0; nt < 8; ++nt) h0[nt] = LDW(WkHi, 0, nt);
    #pragma unroll
    for (int nt = 0; nt < 8; ++nt) h1[nt] = LDW(WkHi, 1, nt);
    #pragma unroll
    for (int nt = 0; nt < 8; ++nt) qa[nt] = MFMA(a0, h0[nt], qa[nt]);
    #pragma unroll
    for (int nt = 0; nt < 8; ++nt) h0[nt] = LDW(WkHi, 2, nt);
    #pragma unroll
    for (int nt = 0; nt < 8; ++nt) qa[nt] = MFMA(a1, h1[nt], qa[nt]);
    #pragma unroll
    for (int nt = 0; nt < 8; ++nt) h1[nt] = LDW(WkHi, 3, nt);
    #pragma unroll
    for (int nt = 0; nt < 8; ++nt) qa[nt] = MFMA(a2, h0[nt], qa[nt]);
    #pragma unroll
    for (int nt = 0; nt < 8; ++nt) qa[nt] = MFMA(a3, h1[nt], qa[nt]);
  }
  // in-register row softmax over e
  float inv[4];
  #pragma unroll
  for (int r = 0; r < 4; ++r) {
    float m = qa[0][r];
    #pragma unroll
    for (int nt = 1; nt < 8; ++nt) m = fmaxf(m, qa[nt][r]);
    m = fmaxf(m, __shfl_xor(m, 1)); m = fmaxf(m, __shfl_xor(m, 2));
    m = fmaxf(m, __shfl_xor(m, 4)); m = fmaxf(m, __shfl_xor(m, 8));
    float s = 0.f;
    #pragma unroll
    for (int nt = 0; nt < 8; ++nt) { float e = __expf(qa[nt][r] - m); qa[nt][r] = e; s += e; }
    s += __shfl_xor(s, 1); s += __shfl_xor(s, 2); s += __shfl_xor(s, 4); s += __shfl_xor(s, 8);
    inv[r] = 1.f / s;
  }
  #pragma unroll
  for (int nt = 0; nt < 8; ++nt) {
    const int e = nt * 16 + l15;
    #pragma unroll
    for (int rp = 0; rp < 2; ++rp) {
      const int x2 = w * 16 + lq * 4 + rp * 2;
      *(unsigned*)((char*)ST + e * 128 + ((x2 * 2) ^ ((e & 7) << 4))) =
          pk2(qa[nt][rp * 2] * inv[rp * 2], qa[nt][rp * 2 + 1] * inv[rp * 2 + 1]);
    }
  }
  __syncthreads();

  // coalesced dump: thread t handles row r = t>>1, half = t&1 (64 B each)
  {
    const int r = t >> 1, half = t & 1;
    const size_t row = ((size_t)h * DIMC + r) * XLEN + x0 + half * 32;
    #pragma unroll
    for (int i = 0; i < 4; ++i) {
      const int off = r * 128 + (((half * 64) + i * 16) ^ ((r & 7) << 4));
      *(int4*)(qT + row + i * 8) = *(const int4*)((const char*)QT + off);
      *(int4*)(sT + row + i * 8) = *(const int4*)((const char*)ST + off);
    }
  }
}

// ---------------------------------------------------------------------------
// Phase 2: k_katg — kat partial GEMM over x. grid (splits, 8 h, 4 eq).
// ---------------------------------------------------------------------------
__global__ __launch_bounds__(256) void k_katg(
    const short* __restrict__ qT, const short* __restrict__ sT,
    short* __restrict__ part16, int b)
{
  __shared__ __align__(16) short QL[128 * 128];   // 32 KB
  __shared__ __align__(16) short SL[32 * 128];    //  8 KB
  const int t = threadIdx.x, w = t >> 6, l = t & 63;
  const int l15 = l & 15, lq = l >> 4;
  const int h = blockIdx.y, eq = blockIdx.z;
  const int n = b * HEADS + h;
  const int xspan = XLEN / gridDim.x;

  f32x4 ka[2][2];
  #pragma unroll
  for (int i = 0; i < 2; ++i)
    #pragma unroll
    for (int j = 0; j < 2; ++j) ka[i][j] = {0.f, 0.f, 0.f, 0.f};

  for (int ch = 0; ch < xspan / 128; ++ch) {
    const int xl0 = blockIdx.x * xspan + ch * 128;
    __syncthreads();
    #pragma unroll
    for (int R = 0; R < 8; ++R) {
      const int idx = R * 256 + t;
      const int d = idx >> 4, c = idx & 15;
      const size_t rb = (((size_t)h * DIMC + d) * XLEN + xl0) * 2;
      *(int4*)((char*)QL + idx * 16) =
          *(const int4*)((const char*)qT + rb + ((c * 16) ^ ((d & 7) << 4)));
    }
    #pragma unroll
    for (int R = 0; R < 2; ++R) {
      const int idx = R * 256 + t;
      const int er = idx >> 4, c = idx & 15;
      const size_t rb = (((size_t)h * DIMC + eq * 32 + er) * XLEN + xl0) * 2;
      *(int4*)((char*)SL + idx * 16) =
          *(const int4*)((const char*)sT + rb + ((c * 16) ^ ((er & 7) << 4)));
    }
    __syncthreads();
    #pragma unroll
    for (int kt2 = 0; kt2 < 4; ++kt2) {
      bf16x8 a0 = ldY(QL, w * 32 + l15,      kt2 * 64 + lq * 16);
      bf16x8 a1 = ldY(QL, w * 32 + 16 + l15, kt2 * 64 + lq * 16);
      #pragma unroll
      for (int nt = 0; nt < 2; ++nt) {
        bf16x8 bs = ldY(SL, nt * 16 + l15, kt2 * 64 + lq * 16);
        ka[0][nt] = MFMA(a0, bs, ka[0][nt]);
        ka[1][nt] = MFMA(a1, bs, ka[1][nt]);
      }
    }
  }
  short* dst = part16 + ((size_t)(blockIdx.x * NHEAD + n)) * 16384;
  #pragma unroll
  for (int mt = 0; mt < 2; ++mt)
    #pragma unroll
    for (int nt = 0; nt < 2; ++nt)
      #pragma unroll
      for (int r = 0; r < 4; ++r) {
        const int d = w * 32 + mt * 16 + lq * 4 + r;
        const int e = eq * 32 + nt * 16 + l15;
        dst[d * DIMC + e] = f2bf(ka[mt][nt][r]);
      }
}

// ---------------------------------------------------------------------------
// Phase 3: k_out11 — r16 rotation with V and out-proj HI-ONLY (Wg/Kp already
// single): 4 GEMM phases/head (128 MFMAs vs 192), rotation V->Wg->Kp->OHi.
// 2 barriers/head. 256 thr, grid (64, 8).
// ---------------------------------------------------------------------------
__global__ __launch_bounds__(256) void k_out11(
    const float* __restrict__ x, const float* __restrict__ dwf,
    const float* __restrict__ bfl, const short* __restrict__ Wpk,
    const short* __restrict__ Gpk, const short* __restrict__ katpk,
    const short* __restrict__ Opk, const float* __restrict__ c0,
    const float* __restrict__ outb, float* __restrict__ outp)
{
  __shared__ __align__(16) short Yq[TX * 128], Yv[TX * 128];
  __shared__ __align__(16) short Vx[TX * 128], Tn[TX * 128];
  const int t = threadIdx.x, w = t >> 6, l = t & 63;
  const int l15 = l & 15, lq = l >> 4;
  const int b = blockIdx.y;
  const int x0 = blockIdx.x * TX;

  f32x4 oacc[2][4];
  #pragma unroll
  for (int i = 0; i < 2; ++i)
    #pragma unroll
    for (int j = 0; j < 4; ++j) oacc[i][j] = {0.f, 0.f, 0.f, 0.f};
  float c0v[8];
  #pragma unroll
  for (int nt = 0; nt < 8; ++nt) c0v[nt] = c0[nt * 16 + l15];

  stage2(x, dwf, bfl, b, x0, t, Yq, Yv, 0, 2);
  __syncthreads();

  for (int h = 0; h < HEADS; ++h) {
    const int n = b * HEADS + h;
    const short* WvHi = Wpk + (size_t)((2 * 8 + h) * 2 + 0) * 16384;
    const short* Wg   = Gpk + (size_t)h * 16384;
    const short* Kp   = katpk + (size_t)n * 16384;
    const short* OHi  = Opk + (size_t)(h * 2 + 0) * 16384;

    bf16x8 P0[8], P1[8], Q0[8], Q1[8];
    // head-entry fill: WvHi kt0..3 (only uncovered burst this head)
    #pragma unroll
    for (int i = 0; i < 8; ++i) P0[i] = LDW(WvHi, 0, i);
    #pragma unroll
    for (int i = 0; i < 8; ++i) P1[i] = LDW(WvHi, 1, i);
    #pragma unroll
    for (int i = 0; i < 8; ++i) Q0[i] = LDW(WvHi, 2, i);
    #pragma unroll
    for (int i = 0; i < 8; ++i) Q1[i] = LDW(WvHi, 3, i);

    // ---- V GEMM (hi only; rotate -> Wg) ----
    f32x4 va[8];
    #pragma unroll
    for (int j = 0; j < 8; ++j) va[j] = {0.f, 0.f, 0.f, 0.f};
    {
      bf16x8 a = ldY(Yv, w * 16 + l15, 0 * 64 + lq * 16);
      #pragma unroll
      for (int nt = 0; nt < 8; ++nt) va[nt] = MFMA(a, P0[nt], va[nt]);
    }
    #pragma unroll
    for (int i = 0; i < 8; ++i) P0[i] = LDW(Wg, 0, i);
    {
      bf16x8 a = ldY(Yv, w * 16 + l15, 1 * 64 + lq * 16);
      #pragma unroll
      for (int nt = 0; nt < 8; ++nt) va[nt] = MFMA(a, P1[nt], va[nt]);
    }
    #pragma unroll
    for (int i = 0; i < 8; ++i) P1[i] = LDW(Wg, 1, i);
    {
      bf16x8 a = ldY(Yv, w * 16 + l15, 2 * 64 + lq * 16);
      #pragma unroll
      for (int nt = 0; nt < 8; ++nt) va[nt] = MFMA(a, Q0[nt], va[nt]);
    }
    #pragma unroll
    for (int i = 0; i < 8; ++i) Q0[i] = LDW(Wg, 2, i);
    {
      bf16x8 a = ldY(Yv, w * 16 + l15, 3 * 64 + lq * 16);
      #pragma unroll
      for (int nt = 0; nt < 8; ++nt) va[nt] = MFMA(a, Q1[nt], va[nt]);
    }
    #pragma unroll
    for (int i = 0; i < 8; ++i) Q1[i] = LDW(Wg, 3, i);

    // ---- write V[x][d] (own wave rows; va dies here) ----
    #pragma unroll
    for (int nt = 0; nt < 8; ++nt) {
      const int dd = nt * 16 + l15;
      #pragma unroll
      for (int r = 0; r < 4; ++r) {
        const int xr = w * 16 + lq * 4 + r;
        *(short*)((char*)Vx + xr * 256 + ((dd * 2) ^ ((xr & 7) << 4))) = f2bf(va[nt][r]);
      }
    }

    // ---- gate GEMM (rotate -> Kp) ----
    f32x4 ga[8];
    #pragma unroll
    for (int j = 0; j < 8; ++j) ga[j] = {0.f, 0.f, 0.f, 0.f};
    {
      bf16x8 a = ldY(Yq, w * 16 + l15, 0 * 64 + lq * 16);
      #pragma unroll
      for (int nt = 0; nt < 8; ++nt) ga[nt] = MFMA(a, P0[nt], ga[nt]);
    }
    #pragma unroll
    for (int i = 0; i < 8; ++i) P0[i] = LDW(Kp, 0, i);
    {
      bf16x8 a = ldY(Yq, w * 16 + l15, 1 * 64 + lq * 16);
      #pragma unroll
      for (int nt = 0; nt < 8; ++nt) ga[nt] = MFMA(a, P1[nt], ga[nt]);
    }
    #pragma unroll
    for (int i = 0; i < 8; ++i) P1[i] = LDW(Kp, 1, i);
    {
      bf16x8 a = ldY(Yq, w * 16 + l15, 2 * 64 + lq * 16);
      #pragma unroll
      for (int nt = 0; nt < 8; ++nt) ga[nt] = MFMA(a, Q0[nt], ga[nt]);
    }
    #pragma unroll
    for (int i = 0; i < 8; ++i) Q0[i] = LDW(Kp, 2, i);
    {
      bf16x8 a = ldY(Yq, w * 16 + l15, 3 * 64 + lq * 16);
      #pragma unroll
      for (int nt = 0; nt < 8; ++nt) ga[nt] = MFMA(a, Q1[nt], ga[nt]);
    }
    #pragma unroll
    for (int i = 0; i < 8; ++i) Q1[i] = LDW(Kp, 3, i);

    // ---- fold sigmoid into ga ----
    #pragma unroll
    for (int nt = 0; nt < 8; ++nt)
      #pragma unroll
      for (int r = 0; r < 4; ++r)
        ga[nt][r] = 1.f / (1.f + __expf(-(ga[nt][r] + c0v[nt])));

    // ---- KV GEMM (A = own Vx rows; rotate P0 -> OHi frags) ----
    f32x4 kv[8];
    #pragma unroll
    for (int j = 0; j < 8; ++j) kv[j] = {0.f, 0.f, 0.f, 0.f};
    {
      bf16x8 a = ldY(Vx, w * 16 + l15, 0 * 64 + lq * 16);
      #pragma unroll
      for (int nt = 0; nt < 8; ++nt) kv[nt] = MFMA(a, P0[nt], kv[nt]);
    }
    #pragma unroll
    for (int i = 0; i < 8; ++i)   // P0[mt*4+kt] = OHi slice (hi only)
      P0[i] = (*(const bf16x8*)&OHi[((((w * 2 + (i >> 2)) * 4 + (i & 3))) * 64 + l) * 8]);
    {
      bf16x8 a = ldY(Vx, w * 16 + l15, 1 * 64 + lq * 16);
      #pragma unroll
      for (int nt = 0; nt < 8; ++nt) kv[nt] = MFMA(a, P1[nt], kv[nt]);
    }
    {
      bf16x8 a = ldY(Vx, w * 16 + l15, 2 * 64 + lq * 16);
      #pragma unroll
      for (int nt = 0; nt < 8; ++nt) kv[nt] = MFMA(a, Q0[nt], kv[nt]);
    }
    {
      bf16x8 a = ldY(Vx, w * 16 + l15, 3 * 64 + lq * 16);
      #pragma unroll
      for (int nt = 0; nt < 8; ++nt) kv[nt] = MFMA(a, Q1[nt], kv[nt]);
    }

    // ---- combine: T = KV + sig * V (V re-read from own Vx rows) ----
    #pragma unroll
    for (int nt = 0; nt < 8; ++nt) {
      const int e = nt * 16 + l15;
      #pragma unroll
      for (int r = 0; r < 4; ++r) {
        const int xr = w * 16 + lq * 4 + r;
        float vv = bf2f(*(const short*)((const char*)Vx + xr * 256 + ((e * 2) ^ ((xr & 7) << 4))));
        *(short*)((char*)Tn + xr * 256 + ((e * 2) ^ ((xr & 7) << 4))) =
            f2bf(kv[nt][r] + ga[nt][r] * vv);
      }
    }
    __syncthreads();                                   // Tn complete

    // ---- out-projection accumulate from P0 (hi only) ----
    #pragma unroll
    for (int kt = 0; kt < 4; ++kt) {
      #pragma unroll
      for (int nt4 = 0; nt4 < 4; ++nt4) {
        bf16x8 bt = ldY(Tn, nt4 * 16 + l15, kt * 64 + lq * 16);
        oacc[0][nt4] = MFMA(P0[0 * 4 + kt], bt, oacc[0][nt4]);
        oacc[1][nt4] = MFMA(P0[1 * 4 + kt], bt, oacc[1][nt4]);
      }
    }
    __syncthreads();   // Tn reads done before next head's combine overwrites
  }
  #pragma unroll
  for (int mt = 0; mt < 2; ++mt) {
    #pragma unroll
    for (int nt4 = 0; nt4 < 4; ++nt4) {
      #pragma unroll
      for (int r = 0; r < 4; ++r) {
        const int o = w * 32 + mt * 16 + lq * 4 + r;
        const int xx = x0 + nt4 * 16 + l15;
        outp[((size_t)b * DIMC + o) * XLEN + xx] = oacc[mt][nt4][r] + outb[o];
      }
    }
  }
}

// ---------------------------------------------------------------------------
extern "C" void kernel_launch(void* const* d_in, const int* in_sizes, int n_in,
                              void* d_out, int out_size, void* d_ws, size_t ws_size,
                              hipStream_t stream) {
  (void)in_sizes; (void)n_in; (void)out_size;
  const float* x = (const float*)d_in[0];
  // q: 1..6, k: 7..12, v: 13..18 (dw,g,b,m,v,pw), gt: 19..24, out_w:25, out_b:26

  char* ws = (char*)d_ws;
  short* katpk = (short*)(ws);                       // 2 MB
  short* Wpk   = (short*)(ws + 2097152);             // 1.5 MB
  short* Opk   = (short*)(ws + 3670016);             // 512 KB
  short* Gpk   = (short*)(ws + 4194304);             // 256 KB
  float* WgF   = (float*)(ws + 4456448);             // 512 KB
  float* Gt    = (float*)(ws + 4980736);             // 64 KB
  float* c0    = (float*)(ws + 5046272);             // 512 B
  float* dwf   = (float*)(ws + 5046784);             // 4.6 KB
  float* bfl   = (float*)(ws + 5051392);             // 1.5 KB
  constexpr size_t BASE = 5052928;
  const int splits = (ws_size >= (size_t)38607360) ? 8 : 4;
  short* part16 = (short*)(ws + BASE);
  short* qT = (short*)(ws + BASE + (size_t)splits * 2097152);
  short* sT = (short*)((char*)qT + 8388608);
  if (ws_size < (size_t)30218752) return;   // loud-fail (proven bound)

  k_prep1<<<4, 128, 0, stream>>>(
      (const float*)d_in[1],  (const float*)d_in[2],  (const float*)d_in[3],
      (const float*)d_in[4],  (const float*)d_in[5],
      (const float*)d_in[7],  (const float*)d_in[8],  (const float*)d_in[9],
      (const float*)d_in[10], (const float*)d_in[11],
      (const float*)d_in[13], (const float*)d_in[14], (const float*)d_in[15],
      (const float*)d_in[16], (const float*)d_in[17],
      (const float*)d_in[24], (const float*)d_in[19], (const float*)d_in[20],
      (const float*)d_in[21], (const float*)d_in[22], (const float*)d_in[23],
      dwf, bfl, Gt, c0);

  k_wg<<<dim3(8, 8), 256, 0, stream>>>((const float*)d_in[6], Gt, WgF);

  k_pack<<<72, 256, 0, stream>>>((const float*)d_in[6], (const float*)d_in[12],
                                 (const float*)d_in[18], (const float*)d_in[25],
                                 WgF, Wpk, Opk, Gpk);

  for (int b = 0; b < BATCH; ++b) {
    k_proj<<<dim3(XLEN / TX, HEADS), 256, 0, stream>>>(x, dwf, bfl, Wpk, qT, sT, b);
    k_katg<<<dim3(splits, HEADS, 4), 256, 0, stream>>>(qT, sT, part16, b);
  }
  k_red<<<NHEAD, 256, 0, stream>>>(part16, katpk, splits);
  k_out11<<<dim3(XLEN / TX, BATCH), 256, 0, stream>>>(x, dwf, bfl, Wpk, Gpk, katpk,
                                                      Opk, c0, (const float*)d_in[26],
                                                      (float*)d_out);
}

// Round 21
// 399.550 us; speedup vs baseline: 2.5770x; 1.0249x over previous
//
#include <hip/hip_runtime.h>
#include <hip/hip_bf16.h>

#define DIMC   128
#define HEADS  8
#define BATCH  8
#define XLEN   4096
#define NHEAD  64
#define EPSV   1e-5f
#define SCALEF 0.08838834764831845f   // 128^-0.5
#define TX     64

typedef __attribute__((ext_vector_type(8))) short bf16x8;
typedef __attribute__((ext_vector_type(4))) float f32x4;
#define MFMA(a,b,c) __builtin_amdgcn_mfma_f32_16x16x32_bf16((a),(b),(c),0,0,0)
// weight B-frag load from GLOBAL table laid out [(kt*8+nt)][lane][8]
#define LDW(tbl, kt, nt) (*(const bf16x8*)&(tbl)[(((kt) * 8 + (nt)) * 64 + l) * 8])

__device__ __forceinline__ short f2bf(float f) {
  union { float f; unsigned u; } v; v.f = f;
  return (short)((v.u + 0x7fffu + ((v.u >> 16) & 1u)) >> 16);
}
__device__ __forceinline__ float bf2f(short h) {
  union { unsigned u; float f; } v; v.u = ((unsigned)(unsigned short)h) << 16;
  return v.f;
}
__device__ __forceinline__ unsigned pk2(float a, float b) {
  return (unsigned)(unsigned short)f2bf(a) | ((unsigned)(unsigned short)f2bf(b) << 16);
}

// LDS fragment loads. Row-major bf16 tiles, XOR-swizzled: byte ^= (row&7)<<4.
__device__ __forceinline__ bf16x8 ldY(const short* Y, int row, int kcb) {
  return *(const bf16x8*)((const char*)Y + row*256 + (kcb ^ ((row&7)<<4)));
}

// ---------------------------------------------------------------------------
// prep kernels (merged: 3 launches total)
// ---------------------------------------------------------------------------
__global__ void k_prep1(const float* dw0, const float* g0, const float* b0, const float* m0, const float* v0,
                        const float* dw1, const float* g1, const float* b1, const float* m1, const float* v1,
                        const float* dw2, const float* g2, const float* b2, const float* m2, const float* v2,
                        const float* gt_pw, const float* gt_dw, const float* gt_g,
                        const float* gt_b, const float* gt_m, const float* gt_v,
                        float* __restrict__ dwf, float* __restrict__ bfl,
                        float* __restrict__ Gt, float* __restrict__ c0) {
  int p = blockIdx.x, c = threadIdx.x;
  if (p < 3) {
    const float* dw = p == 0 ? dw0 : p == 1 ? dw1 : dw2;
    const float* g  = p == 0 ? g0  : p == 1 ? g1  : g2;
    const float* bb = p == 0 ? b0  : p == 1 ? b1  : b2;
    const float* m  = p == 0 ? m0  : p == 1 ? m1  : m2;
    const float* vv = p == 0 ? v0  : p == 1 ? v1  : v2;
    float a = g[c] * rsqrtf(vv[c] + EPSV);
    dwf[(p * DIMC + c) * 3 + 0] = dw[c * 3 + 0] * a;
    dwf[(p * DIMC + c) * 3 + 1] = dw[c * 3 + 1] * a;
    dwf[(p * DIMC + c) * 3 + 2] = dw[c * 3 + 2] * a;
    bfl[p * DIMC + c] = bb[c] - m[c] * a;
  } else {
    int d = c;
    float s = 0.f;
    for (int i = 0; i < DIMC; ++i) {
      float a  = gt_g[i] * rsqrtf(gt_v[i] + EPSV);
      float w1 = gt_dw[i] * a;
      float w0 = gt_b[i] - gt_m[i] * a;
      float pw = gt_pw[d * DIMC + i];
      Gt[i * DIMC + d] = pw * w1;
      s += pw * w0;
    }
    c0[d] = s;
  }
}

__global__ void k_wg(const float* __restrict__ q_pw, const float* __restrict__ Gt,
                     float* __restrict__ WgF) {
  const int h = blockIdx.x, cb = blockIdx.y, t = threadIdx.x;
  const int c = cb * 16 + (t >> 4);
  const int e0 = (t & 15) * 8;
  float acc[8] = {0.f,0.f,0.f,0.f,0.f,0.f,0.f,0.f};
  for (int d = 0; d < DIMC; ++d) {
    float wq = q_pw[((size_t)(h * DIMC + d)) * DIMC + c];
    const float* gr = Gt + d * DIMC + e0;
    #pragma unroll
    for (int j = 0; j < 8; ++j) acc[j] += wq * gr[j];
  }
  float* out = WgF + ((size_t)h * DIMC + c) * DIMC + e0;
  #pragma unroll
  for (int j = 0; j < 8; ++j) out[j] = acc[j];
}

// hi-only packing (lo tables unused since r19/r20): blk<24 proj hi;
// 24..31 out_w hi; 32..39 Wg. Table offsets unchanged (lo slots unwritten).
__global__ void k_pack(const float* __restrict__ q_pw, const float* __restrict__ k_pw,
                       const float* __restrict__ v_pw, const float* __restrict__ out_w,
                       const float* __restrict__ WgF,
                       short* __restrict__ Wpk, short* __restrict__ Opk,
                       short* __restrict__ Gpk) {
  const int blk = blockIdx.x, t = threadIdx.x;
  if (blk < 24) {
    const int p = blk / 8, h = blk & 7;
    const float* pw = p == 0 ? q_pw : p == 1 ? k_pw : v_pw;
    short* dst = Wpk + (size_t)((p * 8 + h) * 2 + 0) * 16384;
    for (int s = t; s < 2048; s += 256) {
      const int l = s & 63, kt = (s >> 6) >> 3, nt = (s >> 6) & 7;
      const int o = h * DIMC + nt * 16 + (l & 15);
      const int cb = kt * 32 + (l >> 4) * 8;
      #pragma unroll
      for (int j = 0; j < 8; ++j)
        dst[s * 8 + j] = f2bf(pw[(size_t)o * DIMC + cb + j]);
    }
  } else if (blk < 32) {
    const int h = blk - 24;
    short* dst = Opk + (size_t)(h * 2 + 0) * 16384;
    for (int s = t; s < 2048; s += 256) {
      const int l = s & 63, mt = (s >> 6) >> 2, kt = (s >> 6) & 3;
      const int o = mt * 16 + (l & 15);
      const int ib = h * DIMC + kt * 32 + (l >> 4) * 8;
      #pragma unroll
      for (int j = 0; j < 8; ++j)
        dst[s * 8 + j] = f2bf(out_w[(size_t)o * (DIMC * HEADS) + ib + j]);
    }
  } else {
    const int h = blk - 32;
    const float* src = WgF + (size_t)h * 16384;
    short* dst = Gpk + (size_t)h * 16384;
    for (int s = t; s < 2048; s += 256) {
      const int l = s & 63, kt = (s >> 6) >> 3, nt = (s >> 6) & 7;
      const int cb = kt * 32 + (l >> 4) * 8, e = nt * 16 + (l & 15);
      #pragma unroll
      for (int j = 0; j < 8; ++j) dst[s * 8 + j] = f2bf(src[(size_t)(cb + j) * DIMC + e]);
    }
  }
}

// sum `splits` bf16 partial kat tiles, scale, pack frags. grid(64)
__global__ __launch_bounds__(256) void k_red(const short* __restrict__ part16,
                                             short* __restrict__ katpk, int splits) {
  __shared__ float sm[DIMC * DIMC];
  const int n = blockIdx.x, t = threadIdx.x;
  for (int i0 = t * 8; i0 < DIMC * DIMC; i0 += 256 * 8) {
    float a[8] = {0.f,0.f,0.f,0.f,0.f,0.f,0.f,0.f};
    for (int s8 = 0; s8 < splits; ++s8) {
      bf16x8 pv = *(const bf16x8*)&part16[((size_t)(s8 * NHEAD + n)) * 16384 + i0];
      #pragma unroll
      for (int j = 0; j < 8; ++j) a[j] += bf2f(pv[j]);
    }
    #pragma unroll
    for (int j = 0; j < 8; ++j) sm[i0 + j] = a[j] * SCALEF;
  }
  __syncthreads();
  short* dst = katpk + (size_t)n * 16384;
  for (int s = t; s < 2048; s += 256) {
    const int l = s & 63, kt = (s >> 6) >> 3, nt = (s >> 6) & 7;
    const int db = kt * 32 + (l >> 4) * 8, e = nt * 16 + (l & 15);
    #pragma unroll
    for (int j = 0; j < 8; ++j) dst[s * 8 + j] = f2bf(sm[(db + j) * DIMC + e]);
  }
}

// ---------------------------------------------------------------------------
// stage Y tiles: dwconv+BN for two projections -> swizzled bf16 LDS [64 x][128 c]
// ---------------------------------------------------------------------------
__device__ __forceinline__ void stage2(const float* __restrict__ x,
    const float* __restrict__ dwf, const float* __restrict__ bfl,
    int b, int xg0, int t, short* Y0, short* Y1, int p0, int p1)
{
  const int xl = t & 63, cg = t >> 6;
  const int xg = xg0 + xl;
  #pragma unroll
  for (int i = 0; i < 16; ++i) {
    const int c = 2 * (cg + 4 * i);
    float v0[2], v1[2];
    #pragma unroll
    for (int u = 0; u < 2; ++u) {
      const int cc = c + u;
      const float* xr = x + ((size_t)b * DIMC + cc) * XLEN + xg;
      float xm = (xg > 0) ? xr[-1] : 0.f;
      float xc = xr[0];
      float xp = (xg < XLEN - 1) ? xr[1] : 0.f;
      const float* d0 = dwf + (p0 * DIMC + cc) * 3;
      const float* d1 = dwf + (p1 * DIMC + cc) * 3;
      v0[u] = xm * d0[0] + xc * d0[1] + xp * d0[2] + bfl[p0 * DIMC + cc];
      v1[u] = xm * d1[0] + xc * d1[1] + xp * d1[2] + bfl[p1 * DIMC + cc];
    }
    const unsigned off = xl * 256 + ((c * 2) ^ ((xl & 7) << 4));
    *(unsigned*)((char*)Y0 + off) = pk2(v0[0], v0[1]);
    *(unsigned*)((char*)Y1 + off) = pk2(v1[0], v1[1]);
  }
}

// ---------------------------------------------------------------------------
// Phase 1: k_proj — Q/K GEMM with hi-only weights (r19-validated), softmax;
// dump qT[h][d][x], sT[h][e][x]. grid (64, 8), 256 thr. Unchanged from r20.
// ---------------------------------------------------------------------------
__global__ __launch_bounds__(256) void k_proj(
    const float* __restrict__ x, const float* __restrict__ dwf,
    const float* __restrict__ bfl, const short* __restrict__ Wpk,
    short* __restrict__ qT, short* __restrict__ sT, int b)
{
  __shared__ __align__(16) short Yq[TX * 128], Yk[TX * 128];
  __shared__ __align__(16) short QT[128 * TX], ST[128 * TX];
  const int t = threadIdx.x, w = t >> 6, l = t & 63;
  const int l15 = l & 15, lq = l >> 4;
  const int h = blockIdx.y;
  const int x0 = blockIdx.x * TX;

  stage2(x, dwf, bfl, b, x0, t, Yq, Yk, 0, 1);
  __syncthreads();

  const short* WqHi = Wpk + (size_t)((0 * 8 + h) * 2 + 0) * 16384;
  const short* WkHi = Wpk + (size_t)((1 * 8 + h) * 2 + 0) * 16384;

  f32x4 qa[8];

  // ---- Q GEMM (hi only), register-prefetched ----
  #pragma unroll
  for (int j = 0; j < 8; ++j) qa[j] = {0.f, 0.f, 0.f, 0.f};
  {
    bf16x8 a0 = ldY(Yq, w * 16 + l15, 0 * 64 + lq * 16);
    bf16x8 a1 = ldY(Yq, w * 16 + l15, 1 * 64 + lq * 16);
    bf16x8 a2 = ldY(Yq, w * 16 + l15, 2 * 64 + lq * 16);
    bf16x8 a3 = ldY(Yq, w * 16 + l15, 3 * 64 + lq * 16);
    bf16x8 h0[8], h1[8];
    #pragma unroll
    for (int nt = 0; nt < 8; ++nt) h0[nt] = LDW(WqHi, 0, nt);
    #pragma unroll
    for (int nt = 0; nt < 8; ++nt) h1[nt] = LDW(WqHi, 1, nt);
    #pragma unroll
    for (int nt = 0; nt < 8; ++nt) qa[nt] = MFMA(a0, h0[nt], qa[nt]);
    #pragma unroll
    for (int nt = 0; nt < 8; ++nt) h0[nt] = LDW(WqHi, 2, nt);
    #pragma unroll
    for (int nt = 0; nt < 8; ++nt) qa[nt] = MFMA(a1, h1[nt], qa[nt]);
    #pragma unroll
    for (int nt = 0; nt < 8; ++nt) h1[nt] = LDW(WqHi, 3, nt);
    #pragma unroll
    for (int nt = 0; nt < 8; ++nt) qa[nt] = MFMA(a2, h0[nt], qa[nt]);
    #pragma unroll
    for (int nt = 0; nt < 8; ++nt) qa[nt] = MFMA(a3, h1[nt], qa[nt]);
  }
  #pragma unroll
  for (int nt = 0; nt < 8; ++nt) {
    const int d = nt * 16 + l15;
    #pragma unroll
    for (int rp = 0; rp < 2; ++rp) {
      const int x2 = w * 16 + lq * 4 + rp * 2;
      *(unsigned*)((char*)QT + d * 128 + ((x2 * 2) ^ ((d & 7) << 4))) =
          pk2(qa[nt][rp * 2], qa[nt][rp * 2 + 1]);
    }
  }

  // ---- K GEMM (hi only), same pattern ----
  #pragma unroll
  for (int j = 0; j < 8; ++j) qa[j] = {0.f, 0.f, 0.f, 0.f};
  {
    bf16x8 a0 = ldY(Yk, w * 16 + l15, 0 * 64 + lq * 16);
    bf16x8 a1 = ldY(Yk, w * 16 + l15, 1 * 64 + lq * 16);
    bf16x8 a2 = ldY(Yk, w * 16 + l15, 2 * 64 + lq * 16);
    bf16x8 a3 = ldY(Yk, w * 16 + l15, 3 * 64 + lq * 16);
    bf16x8 h0[8], h1[8];
    #pragma unroll
    for (int nt = 0; nt < 8; ++nt) h0[nt] = LDW(WkHi, 0, nt);
    #pragma unroll
    for (int nt = 0; nt < 8; ++nt) h1[nt] = LDW(WkHi, 1, nt);
    #pragma unroll
    for (int nt = 0; nt < 8; ++nt) qa[nt] = MFMA(a0, h0[nt], qa[nt]);
    #pragma unroll
    for (int nt = 0; nt < 8; ++nt) h0[nt] = LDW(WkHi, 2, nt);
    #pragma unroll
    for (int nt = 0; nt < 8; ++nt) qa[nt] = MFMA(a1, h1[nt], qa[nt]);
    #pragma unroll
    for (int nt = 0; nt < 8; ++nt) h1[nt] = LDW(WkHi, 3, nt);
    #pragma unroll
    for (int nt = 0; nt < 8; ++nt) qa[nt] = MFMA(a2, h0[nt], qa[nt]);
    #pragma unroll
    for (int nt = 0; nt < 8; ++nt) qa[nt] = MFMA(a3, h1[nt], qa[nt]);
  }
  // in-register row softmax over e
  float inv[4];
  #pragma unroll
  for (int r = 0; r < 4; ++r) {
    float m = qa[0][r];
    #pragma unroll
    for (int nt = 1; nt < 8; ++nt) m = fmaxf(m, qa[nt][r]);
    m = fmaxf(m, __shfl_xor(m, 1)); m = fmaxf(m, __shfl_xor(m, 2));
    m = fmaxf(m, __shfl_xor(m, 4)); m = fmaxf(m, __shfl_xor(m, 8));
    float s = 0.f;
    #pragma unroll
    for (int nt = 0; nt < 8; ++nt) { float e = __expf(qa[nt][r] - m); qa[nt][r] = e; s += e; }
    s += __shfl_xor(s, 1); s += __shfl_xor(s, 2); s += __shfl_xor(s, 4); s += __shfl_xor(s, 8);
    inv[r] = 1.f / s;
  }
  #pragma unroll
  for (int nt = 0; nt < 8; ++nt) {
    const int e = nt * 16 + l15;
    #pragma unroll
    for (int rp = 0; rp < 2; ++rp) {
      const int x2 = w * 16 + lq * 4 + rp * 2;
      *(unsigned*)((char*)ST + e * 128 + ((x2 * 2) ^ ((e & 7) << 4))) =
          pk2(qa[nt][rp * 2] * inv[rp * 2], qa[nt][rp * 2 + 1] * inv[rp * 2 + 1]);
    }
  }
  __syncthreads();

  // coalesced dump: thread t handles row r = t>>1, half = t&1 (64 B each)
  {
    const int r = t >> 1, half = t & 1;
    const size_t row = ((size_t)h * DIMC + r) * XLEN + x0 + half * 32;
    #pragma unroll
    for (int i = 0; i < 4; ++i) {
      const int off = r * 128 + (((half * 64) + i * 16) ^ ((r & 7) << 4));
      *(int4*)(qT + row + i * 8) = *(const int4*)((const char*)QT + off);
      *(int4*)(sT + row + i * 8) = *(const int4*)((const char*)ST + off);
    }
  }
}

// ---------------------------------------------------------------------------
// Phase 2: k_katg — kat partial GEMM over x. grid (splits, 8 h, 8 e-eighths):
// >=256 blocks at splits=4 (was 128 = half-idle device). SL = 16 e-rows (4 KB).
// ---------------------------------------------------------------------------
__global__ __launch_bounds__(256) void k_katg(
    const short* __restrict__ qT, const short* __restrict__ sT,
    short* __restrict__ part16, int b)
{
  __shared__ __align__(16) short QL[128 * 128];   // 32 KB
  __shared__ __align__(16) short SL[16 * 128];    //  4 KB
  const int t = threadIdx.x, w = t >> 6, l = t & 63;
  const int l15 = l & 15, lq = l >> 4;
  const int h = blockIdx.y, eq = blockIdx.z;      // eq in 0..7
  const int n = b * HEADS + h;
  const int xspan = XLEN / gridDim.x;

  f32x4 ka[2];
  ka[0] = {0.f, 0.f, 0.f, 0.f};
  ka[1] = {0.f, 0.f, 0.f, 0.f};

  for (int ch = 0; ch < xspan / 128; ++ch) {
    const int xl0 = blockIdx.x * xspan + ch * 128;
    __syncthreads();
    #pragma unroll
    for (int R = 0; R < 8; ++R) {
      const int idx = R * 256 + t;
      const int d = idx >> 4, c = idx & 15;
      const size_t rb = (((size_t)h * DIMC + d) * XLEN + xl0) * 2;
      *(int4*)((char*)QL + idx * 16) =
          *(const int4*)((const char*)qT + rb + ((c * 16) ^ ((d & 7) << 4)));
    }
    {
      const int idx = t;                          // 256 x 16 B = 4096 B exactly
      const int er = idx >> 4, c = idx & 15;
      const size_t rb = (((size_t)h * DIMC + eq * 16 + er) * XLEN + xl0) * 2;
      *(int4*)((char*)SL + idx * 16) =
          *(const int4*)((const char*)sT + rb + ((c * 16) ^ ((er & 7) << 4)));
    }
    __syncthreads();
    #pragma unroll
    for (int kt2 = 0; kt2 < 4; ++kt2) {
      bf16x8 a0 = ldY(QL, w * 32 + l15,      kt2 * 64 + lq * 16);
      bf16x8 a1 = ldY(QL, w * 32 + 16 + l15, kt2 * 64 + lq * 16);
      bf16x8 bs = ldY(SL, l15, kt2 * 64 + lq * 16);
      ka[0] = MFMA(a0, bs, ka[0]);
      ka[1] = MFMA(a1, bs, ka[1]);
    }
  }
  short* dst = part16 + ((size_t)(blockIdx.x * NHEAD + n)) * 16384;
  #pragma unroll
  for (int mt = 0; mt < 2; ++mt)
    #pragma unroll
    for (int r = 0; r < 4; ++r) {
      const int d = w * 32 + mt * 16 + lq * 4 + r;
      const int e = eq * 16 + l15;
      dst[d * DIMC + e] = f2bf(ka[mt][r]);
    }
}

// ---------------------------------------------------------------------------
// Phase 3: k_out11 — r20 (best, 140 us): 4 GEMM phases/head, rotation
// V->Wg->Kp->OHi, 2 barriers/head. 256 thr, grid (64, 8). Unchanged.
// ---------------------------------------------------------------------------
__global__ __launch_bounds__(256) void k_out11(
    const float* __restrict__ x, const float* __restrict__ dwf,
    const float* __restrict__ bfl, const short* __restrict__ Wpk,
    const short* __restrict__ Gpk, const short* __restrict__ katpk,
    const short* __restrict__ Opk, const float* __restrict__ c0,
    const float* __restrict__ outb, float* __restrict__ outp)
{
  __shared__ __align__(16) short Yq[TX * 128], Yv[TX * 128];
  __shared__ __align__(16) short Vx[TX * 128], Tn[TX * 128];
  const int t = threadIdx.x, w = t >> 6, l = t & 63;
  const int l15 = l & 15, lq = l >> 4;
  const int b = blockIdx.y;
  const int x0 = blockIdx.x * TX;

  f32x4 oacc[2][4];
  #pragma unroll
  for (int i = 0; i < 2; ++i)
    #pragma unroll
    for (int j = 0; j < 4; ++j) oacc[i][j] = {0.f, 0.f, 0.f, 0.f};
  float c0v[8];
  #pragma unroll
  for (int nt = 0; nt < 8; ++nt) c0v[nt] = c0[nt * 16 + l15];

  stage2(x, dwf, bfl, b, x0, t, Yq, Yv, 0, 2);
  __syncthreads();

  for (int h = 0; h < HEADS; ++h) {
    const int n = b * HEADS + h;
    const short* WvHi = Wpk + (size_t)((2 * 8 + h) * 2 + 0) * 16384;
    const short* Wg   = Gpk + (size_t)h * 16384;
    const short* Kp   = katpk + (size_t)n * 16384;
    const short* OHi  = Opk + (size_t)(h * 2 + 0) * 16384;

    bf16x8 P0[8], P1[8], Q0[8], Q1[8];
    #pragma unroll
    for (int i = 0; i < 8; ++i) P0[i] = LDW(WvHi, 0, i);
    #pragma unroll
    for (int i = 0; i < 8; ++i) P1[i] = LDW(WvHi, 1, i);
    #pragma unroll
    for (int i = 0; i < 8; ++i) Q0[i] = LDW(WvHi, 2, i);
    #pragma unroll
    for (int i = 0; i < 8; ++i) Q1[i] = LDW(WvHi, 3, i);

    // ---- V GEMM (hi only; rotate -> Wg) ----
    f32x4 va[8];
    #pragma unroll
    for (int j = 0; j < 8; ++j) va[j] = {0.f, 0.f, 0.f, 0.f};
    {
      bf16x8 a = ldY(Yv, w * 16 + l15, 0 * 64 + lq * 16);
      #pragma unroll
      for (int nt = 0; nt < 8; ++nt) va[nt] = MFMA(a, P0[nt], va[nt]);
    }
    #pragma unroll
    for (int i = 0; i < 8; ++i) P0[i] = LDW(Wg, 0, i);
    {
      bf16x8 a = ldY(Yv, w * 16 + l15, 1 * 64 + lq * 16);
      #pragma unroll
      for (int nt = 0; nt < 8; ++nt) va[nt] = MFMA(a, P1[nt], va[nt]);
    }
    #pragma unroll
    for (int i = 0; i < 8; ++i) P1[i] = LDW(Wg, 1, i);
    {
      bf16x8 a = ldY(Yv, w * 16 + l15, 2 * 64 + lq * 16);
      #pragma unroll
      for (int nt = 0; nt < 8; ++nt) va[nt] = MFMA(a, Q0[nt], va[nt]);
    }
    #pragma unroll
    for (int i = 0; i < 8; ++i) Q0[i] = LDW(Wg, 2, i);
    {
      bf16x8 a = ldY(Yv, w * 16 + l15, 3 * 64 + lq * 16);
      #pragma unroll
      for (int nt = 0; nt < 8; ++nt) va[nt] = MFMA(a, Q1[nt], va[nt]);
    }
    #pragma unroll
    for (int i = 0; i < 8; ++i) Q1[i] = LDW(Wg, 3, i);

    // ---- write V[x][d] (own wave rows; va dies here) ----
    #pragma unroll
    for (int nt = 0; nt < 8; ++nt) {
      const int dd = nt * 16 + l15;
      #pragma unroll
      for (int r = 0; r < 4; ++r) {
        const int xr = w * 16 + lq * 4 + r;
        *(short*)((char*)Vx + xr * 256 + ((dd * 2) ^ ((xr & 7) << 4))) = f2bf(va[nt][r]);
      }
    }

    // ---- gate GEMM (rotate -> Kp) ----
    f32x4 ga[8];
    #pragma unroll
    for (int j = 0; j < 8; ++j) ga[j] = {0.f, 0.f, 0.f, 0.f};
    {
      bf16x8 a = ldY(Yq, w * 16 + l15, 0 * 64 + lq * 16);
      #pragma unroll
      for (int nt = 0; nt < 8; ++nt) ga[nt] = MFMA(a, P0[nt], ga[nt]);
    }
    #pragma unroll
    for (int i = 0; i < 8; ++i) P0[i] = LDW(Kp, 0, i);
    {
      bf16x8 a = ldY(Yq, w * 16 + l15, 1 * 64 + lq * 16);
      #pragma unroll
      for (int nt = 0; nt < 8; ++nt) ga[nt] = MFMA(a, P1[nt], ga[nt]);
    }
    #pragma unroll
    for (int i = 0; i < 8; ++i) P1[i] = LDW(Kp, 1, i);
    {
      bf16x8 a = ldY(Yq, w * 16 + l15, 2 * 64 + lq * 16);
      #pragma unroll
      for (int nt = 0; nt < 8; ++nt) ga[nt] = MFMA(a, Q0[nt], ga[nt]);
    }
    #pragma unroll
    for (int i = 0; i < 8; ++i) Q0[i] = LDW(Kp, 2, i);
    {
      bf16x8 a = ldY(Yq, w * 16 + l15, 3 * 64 + lq * 16);
      #pragma unroll
      for (int nt = 0; nt < 8; ++nt) ga[nt] = MFMA(a, Q1[nt], ga[nt]);
    }
    #pragma unroll
    for (int i = 0; i < 8; ++i) Q1[i] = LDW(Kp, 3, i);

    // ---- fold sigmoid into ga ----
    #pragma unroll
    for (int nt = 0; nt < 8; ++nt)
      #pragma unroll
      for (int r = 0; r < 4; ++r)
        ga[nt][r] = 1.f / (1.f + __expf(-(ga[nt][r] + c0v[nt])));

    // ---- KV GEMM (A = own Vx rows; rotate P0 -> OHi frags) ----
    f32x4 kv[8];
    #pragma unroll
    for (int j = 0; j < 8; ++j) kv[j] = {0.f, 0.f, 0.f, 0.f};
    {
      bf16x8 a = ldY(Vx, w * 16 + l15, 0 * 64 + lq * 16);
      #pragma unroll
      for (int nt = 0; nt < 8; ++nt) kv[nt] = MFMA(a, P0[nt], kv[nt]);
    }
    #pragma unroll
    for (int i = 0; i < 8; ++i)   // P0[mt*4+kt] = OHi slice (hi only)
      P0[i] = (*(const bf16x8*)&OHi[((((w * 2 + (i >> 2)) * 4 + (i & 3))) * 64 + l) * 8]);
    {
      bf16x8 a = ldY(Vx, w * 16 + l15, 1 * 64 + lq * 16);
      #pragma unroll
      for (int nt = 0; nt < 8; ++nt) kv[nt] = MFMA(a, P1[nt], kv[nt]);
    }
    {
      bf16x8 a = ldY(Vx, w * 16 + l15, 2 * 64 + lq * 16);
      #pragma unroll
      for (int nt = 0; nt < 8; ++nt) kv[nt] = MFMA(a, Q0[nt], kv[nt]);
    }
    {
      bf16x8 a = ldY(Vx, w * 16 + l15, 3 * 64 + lq * 16);
      #pragma unroll
      for (int nt = 0; nt < 8; ++nt) kv[nt] = MFMA(a, Q1[nt], kv[nt]);
    }

    // ---- combine: T = KV + sig * V (V re-read from own Vx rows) ----
    #pragma unroll
    for (int nt = 0; nt < 8; ++nt) {
      const int e = nt * 16 + l15;
      #pragma unroll
      for (int r = 0; r < 4; ++r) {
        const int xr = w * 16 + lq * 4 + r;
        float vv = bf2f(*(const short*)((const char*)Vx + xr * 256 + ((e * 2) ^ ((xr & 7) << 4))));
        *(short*)((char*)Tn + xr * 256 + ((e * 2) ^ ((xr & 7) << 4))) =
            f2bf(kv[nt][r] + ga[nt][r] * vv);
      }
    }
    __syncthreads();                                   // Tn complete

    // ---- out-projection accumulate from P0 (hi only) ----
    #pragma unroll
    for (int kt = 0; kt < 4; ++kt) {
      #pragma unroll
      for (int nt4 = 0; nt4 < 4; ++nt4) {
        bf16x8 bt = ldY(Tn, nt4 * 16 + l15, kt * 64 + lq * 16);
        oacc[0][nt4] = MFMA(P0[0 * 4 + kt], bt, oacc[0][nt4]);
        oacc[1][nt4] = MFMA(P0[1 * 4 + kt], bt, oacc[1][nt4]);
      }
    }
    __syncthreads();   // Tn reads done before next head's combine overwrites
  }
  #pragma unroll
  for (int mt = 0; mt < 2; ++mt) {
    #pragma unroll
    for (int nt4 = 0; nt4 < 4; ++nt4) {
      #pragma unroll
      for (int r = 0; r < 4; ++r) {
        const int o = w * 32 + mt * 16 + lq * 4 + r;
        const int xx = x0 + nt4 * 16 + l15;
        outp[((size_t)b * DIMC + o) * XLEN + xx] = oacc[mt][nt4][r] + outb[o];
      }
    }
  }
}

// ---------------------------------------------------------------------------
extern "C" void kernel_launch(void* const* d_in, const int* in_sizes, int n_in,
                              void* d_out, int out_size, void* d_ws, size_t ws_size,
                              hipStream_t stream) {
  (void)in_sizes; (void)n_in; (void)out_size;
  const float* x = (const float*)d_in[0];
  // q: 1..6, k: 7..12, v: 13..18 (dw,g,b,m,v,pw), gt: 19..24, out_w:25, out_b:26

  char* ws = (char*)d_ws;
  short* katpk = (short*)(ws);                       // 2 MB
  short* Wpk   = (short*)(ws + 2097152);             // 1.5 MB
  short* Opk   = (short*)(ws + 3670016);             // 512 KB
  short* Gpk   = (short*)(ws + 4194304);             // 256 KB
  float* WgF   = (float*)(ws + 4456448);             // 512 KB
  float* Gt    = (float*)(ws + 4980736);             // 64 KB
  float* c0    = (float*)(ws + 5046272);             // 512 B
  float* dwf   = (float*)(ws + 5046784);             // 4.6 KB
  float* bfl   = (float*)(ws + 5051392);             // 1.5 KB
  constexpr size_t BASE = 5052928;
  const int splits = (ws_size >= (size_t)38607360) ? 8 : 4;
  short* part16 = (short*)(ws + BASE);
  short* qT = (short*)(ws + BASE + (size_t)splits * 2097152);
  short* sT = (short*)((char*)qT + 8388608);
  if (ws_size < (size_t)30218752) return;   // loud-fail (proven bound)

  k_prep1<<<4, 128, 0, stream>>>(
      (const float*)d_in[1],  (const float*)d_in[2],  (const float*)d_in[3],
      (const float*)d_in[4],  (const float*)d_in[5],
      (const float*)d_in[7],  (const float*)d_in[8],  (const float*)d_in[9],
      (const float*)d_in[10], (const float*)d_in[11],
      (const float*)d_in[13], (const float*)d_in[14], (const float*)d_in[15],
      (const float*)d_in[16], (const float*)d_in[17],
      (const float*)d_in[24], (const float*)d_in[19], (const float*)d_in[20],
      (const float*)d_in[21], (const float*)d_in[22], (const float*)d_in[23],
      dwf, bfl, Gt, c0);

  k_wg<<<dim3(8, 8), 256, 0, stream>>>((const float*)d_in[6], Gt, WgF);

  k_pack<<<40, 256, 0, stream>>>((const float*)d_in[6], (const float*)d_in[12],
                                 (const float*)d_in[18], (const float*)d_in[25],
                                 WgF, Wpk, Opk, Gpk);

  for (int b = 0; b < BATCH; ++b) {
    k_proj<<<dim3(XLEN / TX, HEADS), 256, 0, stream>>>(x, dwf, bfl, Wpk, qT, sT, b);
    k_katg<<<dim3(splits, HEADS, 8), 256, 0, stream>>>(qT, sT, part16, b);
  }
  k_red<<<NHEAD, 256, 0, stream>>>(part16, katpk, splits);
  k_out11<<<dim3(XLEN / TX, BATCH), 256, 0, stream>>>(x, dwf, bfl, Wpk, Gpk, katpk,
                                                      Opk, c0, (const float*)d_in[26],
                                                      (float*)d_out);
}

// Round 22
// 361.585 us; speedup vs baseline: 2.8475x; 1.1050x over previous
//
#include <hip/hip_runtime.h>
#include <hip/hip_bf16.h>

#define DIMC   128
#define HEADS  8
#define BATCH  8
#define XLEN   4096
#define NHEAD  64
#define EPSV   1e-5f
#define SCALEF 0.08838834764831845f   // 128^-0.5
#define TX     64

typedef __attribute__((ext_vector_type(8))) short bf16x8;
typedef __attribute__((ext_vector_type(4))) float f32x4;
#define MFMA(a,b,c) __builtin_amdgcn_mfma_f32_16x16x32_bf16((a),(b),(c),0,0,0)
// weight B-frag load from GLOBAL table laid out [(kt*8+nt)][lane][8]
#define LDW(tbl, kt, nt) (*(const bf16x8*)&(tbl)[(((kt) * 8 + (nt)) * 64 + l) * 8])

__device__ __forceinline__ short f2bf(float f) {
  union { float f; unsigned u; } v; v.f = f;
  return (short)((v.u + 0x7fffu + ((v.u >> 16) & 1u)) >> 16);
}
__device__ __forceinline__ float bf2f(short h) {
  union { unsigned u; float f; } v; v.u = ((unsigned)(unsigned short)h) << 16;
  return v.f;
}
__device__ __forceinline__ unsigned pk2(float a, float b) {
  return (unsigned)(unsigned short)f2bf(a) | ((unsigned)(unsigned short)f2bf(b) << 16);
}

// LDS fragment loads. Row-major bf16 tiles, XOR-swizzled: byte ^= (row&7)<<4.
__device__ __forceinline__ bf16x8 ldY(const short* Y, int row, int kcb) {
  return *(const bf16x8*)((const char*)Y + row*256 + (kcb ^ ((row&7)<<4)));
}

// ---------------------------------------------------------------------------
// prep kernels (3 launches)
// ---------------------------------------------------------------------------
__global__ void k_prep1(const float* dw0, const float* g0, const float* b0, const float* m0, const float* v0,
                        const float* dw1, const float* g1, const float* b1, const float* m1, const float* v1,
                        const float* dw2, const float* g2, const float* b2, const float* m2, const float* v2,
                        const float* gt_pw, const float* gt_dw, const float* gt_g,
                        const float* gt_b, const float* gt_m, const float* gt_v,
                        float* __restrict__ dwf, float* __restrict__ bfl,
                        float* __restrict__ Gt, float* __restrict__ c0) {
  int p = blockIdx.x, c = threadIdx.x;
  if (p < 3) {
    const float* dw = p == 0 ? dw0 : p == 1 ? dw1 : dw2;
    const float* g  = p == 0 ? g0  : p == 1 ? g1  : g2;
    const float* bb = p == 0 ? b0  : p == 1 ? b1  : b2;
    const float* m  = p == 0 ? m0  : p == 1 ? m1  : m2;
    const float* vv = p == 0 ? v0  : p == 1 ? v1  : v2;
    float a = g[c] * rsqrtf(vv[c] + EPSV);
    dwf[(p * DIMC + c) * 3 + 0] = dw[c * 3 + 0] * a;
    dwf[(p * DIMC + c) * 3 + 1] = dw[c * 3 + 1] * a;
    dwf[(p * DIMC + c) * 3 + 2] = dw[c * 3 + 2] * a;
    bfl[p * DIMC + c] = bb[c] - m[c] * a;
  } else {
    int d = c;
    float s = 0.f;
    for (int i = 0; i < DIMC; ++i) {
      float a  = gt_g[i] * rsqrtf(gt_v[i] + EPSV);
      float w1 = gt_dw[i] * a;
      float w0 = gt_b[i] - gt_m[i] * a;
      float pw = gt_pw[d * DIMC + i];
      Gt[i * DIMC + d] = pw * w1;
      s += pw * w0;
    }
    c0[d] = s;
  }
}

__global__ void k_wg(const float* __restrict__ q_pw, const float* __restrict__ Gt,
                     float* __restrict__ WgF) {
  const int h = blockIdx.x, cb = blockIdx.y, t = threadIdx.x;
  const int c = cb * 16 + (t >> 4);
  const int e0 = (t & 15) * 8;
  float acc[8] = {0.f,0.f,0.f,0.f,0.f,0.f,0.f,0.f};
  for (int d = 0; d < DIMC; ++d) {
    float wq = q_pw[((size_t)(h * DIMC + d)) * DIMC + c];
    const float* gr = Gt + d * DIMC + e0;
    #pragma unroll
    for (int j = 0; j < 8; ++j) acc[j] += wq * gr[j];
  }
  float* out = WgF + ((size_t)h * DIMC + c) * DIMC + e0;
  #pragma unroll
  for (int j = 0; j < 8; ++j) out[j] = acc[j];
}

// COMPACT hi-only packing: Wpk table i=(p*8+h) at i*16384 (24 tables);
// Opk table h at h*16384 (8); Gpk table h at h*16384 (8). 40 blocks.
__global__ void k_pack(const float* __restrict__ q_pw, const float* __restrict__ k_pw,
                       const float* __restrict__ v_pw, const float* __restrict__ out_w,
                       const float* __restrict__ WgF,
                       short* __restrict__ Wpk, short* __restrict__ Opk,
                       short* __restrict__ Gpk) {
  const int blk = blockIdx.x, t = threadIdx.x;
  if (blk < 24) {
    const int p = blk / 8, h = blk & 7;
    const float* pw = p == 0 ? q_pw : p == 1 ? k_pw : v_pw;
    short* dst = Wpk + (size_t)(p * 8 + h) * 16384;
    for (int s = t; s < 2048; s += 256) {
      const int l = s & 63, kt = (s >> 6) >> 3, nt = (s >> 6) & 7;
      const int o = h * DIMC + nt * 16 + (l & 15);
      const int cb = kt * 32 + (l >> 4) * 8;
      #pragma unroll
      for (int j = 0; j < 8; ++j)
        dst[s * 8 + j] = f2bf(pw[(size_t)o * DIMC + cb + j]);
    }
  } else if (blk < 32) {
    const int h = blk - 24;
    short* dst = Opk + (size_t)h * 16384;
    for (int s = t; s < 2048; s += 256) {
      const int l = s & 63, mt = (s >> 6) >> 2, kt = (s >> 6) & 3;
      const int o = mt * 16 + (l & 15);
      const int ib = h * DIMC + kt * 32 + (l >> 4) * 8;
      #pragma unroll
      for (int j = 0; j < 8; ++j)
        dst[s * 8 + j] = f2bf(out_w[(size_t)o * (DIMC * HEADS) + ib + j]);
    }
  } else {
    const int h = blk - 32;
    const float* src = WgF + (size_t)h * 16384;
    short* dst = Gpk + (size_t)h * 16384;
    for (int s = t; s < 2048; s += 256) {
      const int l = s & 63, kt = (s >> 6) >> 3, nt = (s >> 6) & 7;
      const int cb = kt * 32 + (l >> 4) * 8, e = nt * 16 + (l & 15);
      #pragma unroll
      for (int j = 0; j < 8; ++j) dst[s * 8 + j] = f2bf(src[(size_t)(cb + j) * DIMC + e]);
    }
  }
}

// sum `splits` bf16 partial kat tiles, scale, pack frags. grid(64)
__global__ __launch_bounds__(256) void k_red(const short* __restrict__ part16,
                                             short* __restrict__ katpk, int splits) {
  __shared__ float sm[DIMC * DIMC];
  const int n = blockIdx.x, t = threadIdx.x;
  for (int i0 = t * 8; i0 < DIMC * DIMC; i0 += 256 * 8) {
    float a[8] = {0.f,0.f,0.f,0.f,0.f,0.f,0.f,0.f};
    for (int s8 = 0; s8 < splits; ++s8) {
      bf16x8 pv = *(const bf16x8*)&part16[((size_t)(s8 * NHEAD + n)) * 16384 + i0];
      #pragma unroll
      for (int j = 0; j < 8; ++j) a[j] += bf2f(pv[j]);
    }
    #pragma unroll
    for (int j = 0; j < 8; ++j) sm[i0 + j] = a[j] * SCALEF;
  }
  __syncthreads();
  short* dst = katpk + (size_t)n * 16384;
  for (int s = t; s < 2048; s += 256) {
    const int l = s & 63, kt = (s >> 6) >> 3, nt = (s >> 6) & 7;
    const int db = kt * 32 + (l >> 4) * 8, e = nt * 16 + (l & 15);
    #pragma unroll
    for (int j = 0; j < 8; ++j) dst[s * 8 + j] = f2bf(sm[(db + j) * DIMC + e]);
  }
}

// ---------------------------------------------------------------------------
// stage Y tiles: dwconv+BN for two projections -> swizzled bf16 LDS [64 x][128 c]
// ---------------------------------------------------------------------------
__device__ __forceinline__ void stage2(const float* __restrict__ x,
    const float* __restrict__ dwf, const float* __restrict__ bfl,
    int b, int xg0, int t, short* Y0, short* Y1, int p0, int p1)
{
  const int xl = t & 63, cg = t >> 6;
  const int xg = xg0 + xl;
  #pragma unroll
  for (int i = 0; i < 16; ++i) {
    const int c = 2 * (cg + 4 * i);
    float v0[2], v1[2];
    #pragma unroll
    for (int u = 0; u < 2; ++u) {
      const int cc = c + u;
      const float* xr = x + ((size_t)b * DIMC + cc) * XLEN + xg;
      float xm = (xg > 0) ? xr[-1] : 0.f;
      float xc = xr[0];
      float xp = (xg < XLEN - 1) ? xr[1] : 0.f;
      const float* d0 = dwf + (p0 * DIMC + cc) * 3;
      const float* d1 = dwf + (p1 * DIMC + cc) * 3;
      v0[u] = xm * d0[0] + xc * d0[1] + xp * d0[2] + bfl[p0 * DIMC + cc];
      v1[u] = xm * d1[0] + xc * d1[1] + xp * d1[2] + bfl[p1 * DIMC + cc];
    }
    const unsigned off = xl * 256 + ((c * 2) ^ ((xl & 7) << 4));
    *(unsigned*)((char*)Y0 + off) = pk2(v0[0], v0[1]);
    *(unsigned*)((char*)Y1 + off) = pk2(v1[0], v1[1]);
  }
}

// ---------------------------------------------------------------------------
// Phase 1: k_proj — Q/K GEMM (hi-only), softmax; dump qT/sT by slot.
// grid (64, 8*BPL): slot = blockIdx.y, b = b0 + slot>>3, h = slot&7.
// At BPL=1 this is byte-equivalent to the r21 kernel.
// ---------------------------------------------------------------------------
__global__ __launch_bounds__(256) void k_proj(
    const float* __restrict__ x, const float* __restrict__ dwf,
    const float* __restrict__ bfl, const short* __restrict__ Wpk,
    short* __restrict__ qT, short* __restrict__ sT, int b0)
{
  __shared__ __align__(16) short Yq[TX * 128], Yk[TX * 128];
  __shared__ __align__(16) short QT[128 * TX], ST[128 * TX];
  const int t = threadIdx.x, w = t >> 6, l = t & 63;
  const int l15 = l & 15, lq = l >> 4;
  const int slot = blockIdx.y;
  const int b = b0 + (slot >> 3), h = slot & 7;
  const int x0 = blockIdx.x * TX;

  stage2(x, dwf, bfl, b, x0, t, Yq, Yk, 0, 1);
  __syncthreads();

  const short* WqHi = Wpk + (size_t)(0 * 8 + h) * 16384;
  const short* WkHi = Wpk + (size_t)(1 * 8 + h) * 16384;

  f32x4 qa[8];

  // ---- Q GEMM (hi only), register-prefetched ----
  #pragma unroll
  for (int j = 0; j < 8; ++j) qa[j] = {0.f, 0.f, 0.f, 0.f};
  {
    bf16x8 a0 = ldY(Yq, w * 16 + l15, 0 * 64 + lq * 16);
    bf16x8 a1 = ldY(Yq, w * 16 + l15, 1 * 64 + lq * 16);
    bf16x8 a2 = ldY(Yq, w * 16 + l15, 2 * 64 + lq * 16);
    bf16x8 a3 = ldY(Yq, w * 16 + l15, 3 * 64 + lq * 16);
    bf16x8 h0[8], h1[8];
    #pragma unroll
    for (int nt = 0; nt < 8; ++nt) h0[nt] = LDW(WqHi, 0, nt);
    #pragma unroll
    for (int nt = 0; nt < 8; ++nt) h1[nt] = LDW(WqHi, 1, nt);
    #pragma unroll
    for (int nt = 0; nt < 8; ++nt) qa[nt] = MFMA(a0, h0[nt], qa[nt]);
    #pragma unroll
    for (int nt = 0; nt < 8; ++nt) h0[nt] = LDW(WqHi, 2, nt);
    #pragma unroll
    for (int nt = 0; nt < 8; ++nt) qa[nt] = MFMA(a1, h1[nt], qa[nt]);
    #pragma unroll
    for (int nt = 0; nt < 8; ++nt) h1[nt] = LDW(WqHi, 3, nt);
    #pragma unroll
    for (int nt = 0; nt < 8; ++nt) qa[nt] = MFMA(a2, h0[nt], qa[nt]);
    #pragma unroll
    for (int nt = 0; nt < 8; ++nt) qa[nt] = MFMA(a3, h1[nt], qa[nt]);
  }
  #pragma unroll
  for (int nt = 0; nt < 8; ++nt) {
    const int d = nt * 16 + l15;
    #pragma unroll
    for (int rp = 0; rp < 2; ++rp) {
      const int x2 = w * 16 + lq * 4 + rp * 2;
      *(unsigned*)((char*)QT + d * 128 + ((x2 * 2) ^ ((d & 7) << 4))) =
          pk2(qa[nt][rp * 2], qa[nt][rp * 2 + 1]);
    }
  }

  // ---- K GEMM (hi only), same pattern ----
  #pragma unroll
  for (int j = 0; j < 8; ++j) qa[j] = {0.f, 0.f, 0.f, 0.f};
  {
    bf16x8 a0 = ldY(Yk, w * 16 + l15, 0 * 64 + lq * 16);
    bf16x8 a1 = ldY(Yk, w * 16 + l15, 1 * 64 + lq * 16);
    bf16x8 a2 = ldY(Yk, w * 16 + l15, 2 * 64 + lq * 16);
    bf16x8 a3 = ldY(Yk, w * 16 + l15, 3 * 64 + lq * 16);
    bf16x8 h0[8], h1[8];
    #pragma unroll
    for (int nt = 0; nt < 8; ++nt) h0[nt] = LDW(WkHi, 0, nt);
    #pragma unroll
    for (int nt = 0; nt < 8; ++nt) h1[nt] = LDW(WkHi, 1, nt);
    #pragma unroll
    for (int nt = 0; nt < 8; ++nt) qa[nt] = MFMA(a0, h0[nt], qa[nt]);
    #pragma unroll
    for (int nt = 0; nt < 8; ++nt) h0[nt] = LDW(WkHi, 2, nt);
    #pragma unroll
    for (int nt = 0; nt < 8; ++nt) qa[nt] = MFMA(a1, h1[nt], qa[nt]);
    #pragma unroll
    for (int nt = 0; nt < 8; ++nt) h1[nt] = LDW(WkHi, 3, nt);
    #pragma unroll
    for (int nt = 0; nt < 8; ++nt) qa[nt] = MFMA(a2, h0[nt], qa[nt]);
    #pragma unroll
    for (int nt = 0; nt < 8; ++nt) qa[nt] = MFMA(a3, h1[nt], qa[nt]);
  }
  // in-register row softmax over e
  float inv[4];
  #pragma unroll
  for (int r = 0; r < 4; ++r) {
    float m = qa[0][r];
    #pragma unroll
    for (int nt = 1; nt < 8; ++nt) m = fmaxf(m, qa[nt][r]);
    m = fmaxf(m, __shfl_xor(m, 1)); m = fmaxf(m, __shfl_xor(m, 2));
    m = fmaxf(m, __shfl_xor(m, 4)); m = fmaxf(m, __shfl_xor(m, 8));
    float s = 0.f;
    #pragma unroll
    for (int nt = 0; nt < 8; ++nt) { float e = __expf(qa[nt][r] - m); qa[nt][r] = e; s += e; }
    s += __shfl_xor(s, 1); s += __shfl_xor(s, 2); s += __shfl_xor(s, 4); s += __shfl_xor(s, 8);
    inv[r] = 1.f / s;
  }
  #pragma unroll
  for (int nt = 0; nt < 8; ++nt) {
    const int e = nt * 16 + l15;
    #pragma unroll
    for (int rp = 0; rp < 2; ++rp) {
      const int x2 = w * 16 + lq * 4 + rp * 2;
      *(unsigned*)((char*)ST + e * 128 + ((x2 * 2) ^ ((e & 7) << 4))) =
          pk2(qa[nt][rp * 2] * inv[rp * 2], qa[nt][rp * 2 + 1] * inv[rp * 2 + 1]);
    }
  }
  __syncthreads();

  // coalesced dump: thread t handles row r = t>>1, half = t&1 (64 B each)
  {
    const int r = t >> 1, half = t & 1;
    const size_t row = ((size_t)slot * DIMC + r) * XLEN + x0 + half * 32;
    #pragma unroll
    for (int i = 0; i < 4; ++i) {
      const int off = r * 128 + (((half * 64) + i * 16) ^ ((r & 7) << 4));
      *(int4*)(qT + row + i * 8) = *(const int4*)((const char*)QT + off);
      *(int4*)(sT + row + i * 8) = *(const int4*)((const char*)ST + off);
    }
  }
}

// ---------------------------------------------------------------------------
// Phase 2: k_katg — kat partial GEMM over x. grid (splits, 8*BPL, 8 eighths).
// slot = blockIdx.y indexes qT/sT; n = n0 + slot. SL = 16 e-rows (4 KB).
// ---------------------------------------------------------------------------
__global__ __launch_bounds__(256) void k_katg(
    const short* __restrict__ qT, const short* __restrict__ sT,
    short* __restrict__ part16, int n0)
{
  __shared__ __align__(16) short QL[128 * 128];   // 32 KB
  __shared__ __align__(16) short SL[16 * 128];    //  4 KB
  const int t = threadIdx.x, w = t >> 6, l = t & 63;
  const int l15 = l & 15, lq = l >> 4;
  const int slot = blockIdx.y, eq = blockIdx.z;   // eq in 0..7
  const int xspan = XLEN / gridDim.x;

  f32x4 ka[2];
  ka[0] = {0.f, 0.f, 0.f, 0.f};
  ka[1] = {0.f, 0.f, 0.f, 0.f};

  for (int ch = 0; ch < xspan / 128; ++ch) {
    const int xl0 = blockIdx.x * xspan + ch * 128;
    __syncthreads();
    #pragma unroll
    for (int R = 0; R < 8; ++R) {
      const int idx = R * 256 + t;
      const int d = idx >> 4, c = idx & 15;
      const size_t rb = (((size_t)slot * DIMC + d) * XLEN + xl0) * 2;
      *(int4*)((char*)QL + idx * 16) =
          *(const int4*)((const char*)qT + rb + ((c * 16) ^ ((d & 7) << 4)));
    }
    {
      const int idx = t;                          // 256 x 16 B = 4096 B exactly
      const int er = idx >> 4, c = idx & 15;
      const size_t rb = (((size_t)slot * DIMC + eq * 16 + er) * XLEN + xl0) * 2;
      *(int4*)((char*)SL + idx * 16) =
          *(const int4*)((const char*)sT + rb + ((c * 16) ^ ((er & 7) << 4)));
    }
    __syncthreads();
    #pragma unroll
    for (int kt2 = 0; kt2 < 4; ++kt2) {
      bf16x8 a0 = ldY(QL, w * 32 + l15,      kt2 * 64 + lq * 16);
      bf16x8 a1 = ldY(QL, w * 32 + 16 + l15, kt2 * 64 + lq * 16);
      bf16x8 bs = ldY(SL, l15, kt2 * 64 + lq * 16);
      ka[0] = MFMA(a0, bs, ka[0]);
      ka[1] = MFMA(a1, bs, ka[1]);
    }
  }
  short* dst = part16 + ((size_t)(blockIdx.x * NHEAD + n0 + slot)) * 16384;
  #pragma unroll
  for (int mt = 0; mt < 2; ++mt)
    #pragma unroll
    for (int r = 0; r < 4; ++r) {
      const int d = w * 32 + mt * 16 + lq * 4 + r;
      const int e = eq * 16 + l15;
      dst[d * DIMC + e] = f2bf(ka[mt][r]);
    }
}

// ---------------------------------------------------------------------------
// Phase 3: k_out11 — r20/r21 best (140 us): 4 GEMM phases/head, rotation
// V->Wg->Kp->OHi, 2 barriers/head. Compacted table offsets. grid (64, 8).
// ---------------------------------------------------------------------------
__global__ __launch_bounds__(256) void k_out11(
    const float* __restrict__ x, const float* __restrict__ dwf,
    const float* __restrict__ bfl, const short* __restrict__ Wpk,
    const short* __restrict__ Gpk, const short* __restrict__ katpk,
    const short* __restrict__ Opk, const float* __restrict__ c0,
    const float* __restrict__ outb, float* __restrict__ outp)
{
  __shared__ __align__(16) short Yq[TX * 128], Yv[TX * 128];
  __shared__ __align__(16) short Vx[TX * 128], Tn[TX * 128];
  const int t = threadIdx.x, w = t >> 6, l = t & 63;
  const int l15 = l & 15, lq = l >> 4;
  const int b = blockIdx.y;
  const int x0 = blockIdx.x * TX;

  f32x4 oacc[2][4];
  #pragma unroll
  for (int i = 0; i < 2; ++i)
    #pragma unroll
    for (int j = 0; j < 4; ++j) oacc[i][j] = {0.f, 0.f, 0.f, 0.f};
  float c0v[8];
  #pragma unroll
  for (int nt = 0; nt < 8; ++nt) c0v[nt] = c0[nt * 16 + l15];

  stage2(x, dwf, bfl, b, x0, t, Yq, Yv, 0, 2);
  __syncthreads();

  for (int h = 0; h < HEADS; ++h) {
    const int n = b * HEADS + h;
    const short* WvHi = Wpk + (size_t)(2 * 8 + h) * 16384;
    const short* Wg   = Gpk + (size_t)h * 16384;
    const short* Kp   = katpk + (size_t)n * 16384;
    const short* OHi  = Opk + (size_t)h * 16384;

    bf16x8 P0[8], P1[8], Q0[8], Q1[8];
    #pragma unroll
    for (int i = 0; i < 8; ++i) P0[i] = LDW(WvHi, 0, i);
    #pragma unroll
    for (int i = 0; i < 8; ++i) P1[i] = LDW(WvHi, 1, i);
    #pragma unroll
    for (int i = 0; i < 8; ++i) Q0[i] = LDW(WvHi, 2, i);
    #pragma unroll
    for (int i = 0; i < 8; ++i) Q1[i] = LDW(WvHi, 3, i);

    // ---- V GEMM (hi only; rotate -> Wg) ----
    f32x4 va[8];
    #pragma unroll
    for (int j = 0; j < 8; ++j) va[j] = {0.f, 0.f, 0.f, 0.f};
    {
      bf16x8 a = ldY(Yv, w * 16 + l15, 0 * 64 + lq * 16);
      #pragma unroll
      for (int nt = 0; nt < 8; ++nt) va[nt] = MFMA(a, P0[nt], va[nt]);
    }
    #pragma unroll
    for (int i = 0; i < 8; ++i) P0[i] = LDW(Wg, 0, i);
    {
      bf16x8 a = ldY(Yv, w * 16 + l15, 1 * 64 + lq * 16);
      #pragma unroll
      for (int nt = 0; nt < 8; ++nt) va[nt] = MFMA(a, P1[nt], va[nt]);
    }
    #pragma unroll
    for (int i = 0; i < 8; ++i) P1[i] = LDW(Wg, 1, i);
    {
      bf16x8 a = ldY(Yv, w * 16 + l15, 2 * 64 + lq * 16);
      #pragma unroll
      for (int nt = 0; nt < 8; ++nt) va[nt] = MFMA(a, Q0[nt], va[nt]);
    }
    #pragma unroll
    for (int i = 0; i < 8; ++i) Q0[i] = LDW(Wg, 2, i);
    {
      bf16x8 a = ldY(Yv, w * 16 + l15, 3 * 64 + lq * 16);
      #pragma unroll
      for (int nt = 0; nt < 8; ++nt) va[nt] = MFMA(a, Q1[nt], va[nt]);
    }
    #pragma unroll
    for (int i = 0; i < 8; ++i) Q1[i] = LDW(Wg, 3, i);

    // ---- write V[x][d] (own wave rows; va dies here) ----
    #pragma unroll
    for (int nt = 0; nt < 8; ++nt) {
      const int dd = nt * 16 + l15;
      #pragma unroll
      for (int r = 0; r < 4; ++r) {
        const int xr = w * 16 + lq * 4 + r;
        *(short*)((char*)Vx + xr * 256 + ((dd * 2) ^ ((xr & 7) << 4))) = f2bf(va[nt][r]);
      }
    }

    // ---- gate GEMM (rotate -> Kp) ----
    f32x4 ga[8];
    #pragma unroll
    for (int j = 0; j < 8; ++j) ga[j] = {0.f, 0.f, 0.f, 0.f};
    {
      bf16x8 a = ldY(Yq, w * 16 + l15, 0 * 64 + lq * 16);
      #pragma unroll
      for (int nt = 0; nt < 8; ++nt) ga[nt] = MFMA(a, P0[nt], ga[nt]);
    }
    #pragma unroll
    for (int i = 0; i < 8; ++i) P0[i] = LDW(Kp, 0, i);
    {
      bf16x8 a = ldY(Yq, w * 16 + l15, 1 * 64 + lq * 16);
      #pragma unroll
      for (int nt = 0; nt < 8; ++nt) ga[nt] = MFMA(a, P1[nt], ga[nt]);
    }
    #pragma unroll
    for (int i = 0; i < 8; ++i) P1[i] = LDW(Kp, 1, i);
    {
      bf16x8 a = ldY(Yq, w * 16 + l15, 2 * 64 + lq * 16);
      #pragma unroll
      for (int nt = 0; nt < 8; ++nt) ga[nt] = MFMA(a, Q0[nt], ga[nt]);
    }
    #pragma unroll
    for (int i = 0; i < 8; ++i) Q0[i] = LDW(Kp, 2, i);
    {
      bf16x8 a = ldY(Yq, w * 16 + l15, 3 * 64 + lq * 16);
      #pragma unroll
      for (int nt = 0; nt < 8; ++nt) ga[nt] = MFMA(a, Q1[nt], ga[nt]);
    }
    #pragma unroll
    for (int i = 0; i < 8; ++i) Q1[i] = LDW(Kp, 3, i);

    // ---- fold sigmoid into ga ----
    #pragma unroll
    for (int nt = 0; nt < 8; ++nt)
      #pragma unroll
      for (int r = 0; r < 4; ++r)
        ga[nt][r] = 1.f / (1.f + __expf(-(ga[nt][r] + c0v[nt])));

    // ---- KV GEMM (A = own Vx rows; rotate P0 -> OHi frags) ----
    f32x4 kv[8];
    #pragma unroll
    for (int j = 0; j < 8; ++j) kv[j] = {0.f, 0.f, 0.f, 0.f};
    {
      bf16x8 a = ldY(Vx, w * 16 + l15, 0 * 64 + lq * 16);
      #pragma unroll
      for (int nt = 0; nt < 8; ++nt) kv[nt] = MFMA(a, P0[nt], kv[nt]);
    }
    #pragma unroll
    for (int i = 0; i < 8; ++i)   // P0[mt*4+kt] = OHi slice (hi only)
      P0[i] = (*(const bf16x8*)&OHi[((((w * 2 + (i >> 2)) * 4 + (i & 3))) * 64 + l) * 8]);
    {
      bf16x8 a = ldY(Vx, w * 16 + l15, 1 * 64 + lq * 16);
      #pragma unroll
      for (int nt = 0; nt < 8; ++nt) kv[nt] = MFMA(a, P1[nt], kv[nt]);
    }
    {
      bf16x8 a = ldY(Vx, w * 16 + l15, 2 * 64 + lq * 16);
      #pragma unroll
      for (int nt = 0; nt < 8; ++nt) kv[nt] = MFMA(a, Q0[nt], kv[nt]);
    }
    {
      bf16x8 a = ldY(Vx, w * 16 + l15, 3 * 64 + lq * 16);
      #pragma unroll
      for (int nt = 0; nt < 8; ++nt) kv[nt] = MFMA(a, Q1[nt], kv[nt]);
    }

    // ---- combine: T = KV + sig * V (V re-read from own Vx rows) ----
    #pragma unroll
    for (int nt = 0; nt < 8; ++nt) {
      const int e = nt * 16 + l15;
      #pragma unroll
      for (int r = 0; r < 4; ++r) {
        const int xr = w * 16 + lq * 4 + r;
        float vv = bf2f(*(const short*)((const char*)Vx + xr * 256 + ((e * 2) ^ ((xr & 7) << 4))));
        *(short*)((char*)Tn + xr * 256 + ((e * 2) ^ ((xr & 7) << 4))) =
            f2bf(kv[nt][r] + ga[nt][r] * vv);
      }
    }
    __syncthreads();                                   // Tn complete

    // ---- out-projection accumulate from P0 (hi only) ----
    #pragma unroll
    for (int kt = 0; kt < 4; ++kt) {
      #pragma unroll
      for (int nt4 = 0; nt4 < 4; ++nt4) {
        bf16x8 bt = ldY(Tn, nt4 * 16 + l15, kt * 64 + lq * 16);
        oacc[0][nt4] = MFMA(P0[0 * 4 + kt], bt, oacc[0][nt4]);
        oacc[1][nt4] = MFMA(P0[1 * 4 + kt], bt, oacc[1][nt4]);
      }
    }
    __syncthreads();   // Tn reads done before next head's combine overwrites
  }
  #pragma unroll
  for (int mt = 0; mt < 2; ++mt) {
    #pragma unroll
    for (int nt4 = 0; nt4 < 4; ++nt4) {
      #pragma unroll
      for (int r = 0; r < 4; ++r) {
        const int o = w * 32 + mt * 16 + lq * 4 + r;
        const int xx = x0 + nt4 * 16 + l15;
        outp[((size_t)b * DIMC + o) * XLEN + xx] = oacc[mt][nt4][r] + outb[o];
      }
    }
  }
}

// ---------------------------------------------------------------------------
extern "C" void kernel_launch(void* const* d_in, const int* in_sizes, int n_in,
                              void* d_out, int out_size, void* d_ws, size_t ws_size,
                              hipStream_t stream) {
  (void)in_sizes; (void)n_in; (void)out_size;
  const float* x = (const float*)d_in[0];
  // q: 1..6, k: 7..12, v: 13..18 (dw,g,b,m,v,pw), gt: 19..24, out_w:25, out_b:26

  // compact layout (hi-only tables):
  char* ws = (char*)d_ws;
  short* katpk = (short*)(ws);                       // 2,097,152
  short* Wpk   = (short*)(ws + 2097152);             //   786,432 (24 tables)
  short* Opk   = (short*)(ws + 2883584);             //   262,144 (8 tables)
  short* Gpk   = (short*)(ws + 3145728);             //   262,144 (8 tables)
  float* Gt    = (float*)(ws + 3407872);             //    65,536
  float* c0    = (float*)(ws + 3473408);             //       512
  float* dwf   = (float*)(ws + 3473920);             //     4,608
  float* bfl   = (float*)(ws + 3478528);             //     1,536
  constexpr size_t BASE = 3480064;
  // WgF aliases the part16 region: written by k_wg, read by k_pack, both
  // strictly before any k_katg writes part16. 512 KB < min part16 (4 MB).
  float* WgF   = (float*)(ws + BASE);

  // BPL=2 (2 batches per chain launch) when ws allows; else r21-equivalent.
  int BPL, splits;
  if (ws_size >= (size_t)(BASE + 2u*2097152 + 2u*8388608 + 2u*8388608 + 16777216)) {
    // BASE + part16(2 splits=4MB) + qT(16MB) + sT(16MB) = 41,234,432
    BPL = 2; splits = 2;
  } else if (ws_size >= (size_t)(BASE + 8u*2097152 + 8388608 + 8388608)) {
    BPL = 1; splits = 8;                              // 37,034,496
  } else {
    BPL = 1; splits = 4;                              // 28,645,888 (proven fits)
  }
  short* part16 = (short*)(ws + BASE);
  short* qT = (short*)(ws + BASE + (size_t)splits * 2097152);
  short* sT = (short*)((char*)qT + (size_t)BPL * 8388608);
  if (ws_size < (size_t)28645888) return;   // loud-fail (below proven bound)

  k_prep1<<<4, 128, 0, stream>>>(
      (const float*)d_in[1],  (const float*)d_in[2],  (const float*)d_in[3],
      (const float*)d_in[4],  (const float*)d_in[5],
      (const float*)d_in[7],  (const float*)d_in[8],  (const float*)d_in[9],
      (const float*)d_in[10], (const float*)d_in[11],
      (const float*)d_in[13], (const float*)d_in[14], (const float*)d_in[15],
      (const float*)d_in[16], (const float*)d_in[17],
      (const float*)d_in[24], (const float*)d_in[19], (const float*)d_in[20],
      (const float*)d_in[21], (const float*)d_in[22], (const float*)d_in[23],
      dwf, bfl, Gt, c0);

  k_wg<<<dim3(8, 8), 256, 0, stream>>>((const float*)d_in[6], Gt, WgF);

  k_pack<<<40, 256, 0, stream>>>((const float*)d_in[6], (const float*)d_in[12],
                                 (const float*)d_in[18], (const float*)d_in[25],
                                 WgF, Wpk, Opk, Gpk);

  for (int b0 = 0; b0 < BATCH; b0 += BPL) {
    k_proj<<<dim3(XLEN / TX, HEADS * BPL), 256, 0, stream>>>(x, dwf, bfl, Wpk,
                                                             qT, sT, b0);
    k_katg<<<dim3(splits, HEADS * BPL, 8), 256, 0, stream>>>(qT, sT, part16,
                                                             b0 * HEADS);
  }
  k_red<<<NHEAD, 256, 0, stream>>>(part16, katpk, splits);
  k_out11<<<dim3(XLEN / TX, BATCH), 256, 0, stream>>>(x, dwf, bfl, Wpk, Gpk, katpk,
                                                      Opk, c0, (const float*)d_in[26],
                                                      (float*)d_out);
}

// Round 23
// 361.257 us; speedup vs baseline: 2.8501x; 1.0009x over previous
//
#include <hip/hip_runtime.h>
#include <hip/hip_bf16.h>

#define DIMC   128
#define HEADS  8
#define BATCH  8
#define XLEN   4096
#define NHEAD  64
#define EPSV   1e-5f
#define SCALEF 0.08838834764831845f   // 128^-0.5
#define TX     64

typedef __attribute__((ext_vector_type(8))) short bf16x8;
typedef __attribute__((ext_vector_type(4))) float f32x4;
#define MFMA(a,b,c) __builtin_amdgcn_mfma_f32_16x16x32_bf16((a),(b),(c),0,0,0)
// weight B-frag load from GLOBAL table laid out [(kt*8+nt)][lane][8]
#define LDW(tbl, kt, nt) (*(const bf16x8*)&(tbl)[(((kt) * 8 + (nt)) * 64 + l) * 8])

__device__ __forceinline__ short f2bf(float f) {
  union { float f; unsigned u; } v; v.f = f;
  return (short)((v.u + 0x7fffu + ((v.u >> 16) & 1u)) >> 16);
}
__device__ __forceinline__ float bf2f(short h) {
  union { unsigned u; float f; } v; v.u = ((unsigned)(unsigned short)h) << 16;
  return v.f;
}
__device__ __forceinline__ unsigned pk2(float a, float b) {
  return (unsigned)(unsigned short)f2bf(a) | ((unsigned)(unsigned short)f2bf(b) << 16);
}

// LDS fragment loads. Row-major bf16 tiles, XOR-swizzled: byte ^= (row&7)<<4.
__device__ __forceinline__ bf16x8 ldY(const short* Y, int row, int kcb) {
  return *(const bf16x8*)((const char*)Y + row*256 + (kcb ^ ((row&7)<<4)));
}

// ---------------------------------------------------------------------------
// prep kernels (3 launches)
// ---------------------------------------------------------------------------
__global__ void k_prep1(const float* dw0, const float* g0, const float* b0, const float* m0, const float* v0,
                        const float* dw1, const float* g1, const float* b1, const float* m1, const float* v1,
                        const float* dw2, const float* g2, const float* b2, const float* m2, const float* v2,
                        const float* gt_pw, const float* gt_dw, const float* gt_g,
                        const float* gt_b, const float* gt_m, const float* gt_v,
                        float* __restrict__ dwf, float* __restrict__ bfl,
                        float* __restrict__ Gt, float* __restrict__ c0) {
  int p = blockIdx.x, c = threadIdx.x;
  if (p < 3) {
    const float* dw = p == 0 ? dw0 : p == 1 ? dw1 : dw2;
    const float* g  = p == 0 ? g0  : p == 1 ? g1  : g2;
    const float* bb = p == 0 ? b0  : p == 1 ? b1  : b2;
    const float* m  = p == 0 ? m0  : p == 1 ? m1  : m2;
    const float* vv = p == 0 ? v0  : p == 1 ? v1  : v2;
    float a = g[c] * rsqrtf(vv[c] + EPSV);
    dwf[(p * DIMC + c) * 3 + 0] = dw[c * 3 + 0] * a;
    dwf[(p * DIMC + c) * 3 + 1] = dw[c * 3 + 1] * a;
    dwf[(p * DIMC + c) * 3 + 2] = dw[c * 3 + 2] * a;
    bfl[p * DIMC + c] = bb[c] - m[c] * a;
  } else {
    int d = c;
    float s = 0.f;
    for (int i = 0; i < DIMC; ++i) {
      float a  = gt_g[i] * rsqrtf(gt_v[i] + EPSV);
      float w1 = gt_dw[i] * a;
      float w0 = gt_b[i] - gt_m[i] * a;
      float pw = gt_pw[d * DIMC + i];
      Gt[i * DIMC + d] = pw * w1;
      s += pw * w0;
    }
    c0[d] = s;
  }
}

__global__ void k_wg(const float* __restrict__ q_pw, const float* __restrict__ Gt,
                     float* __restrict__ WgF) {
  const int h = blockIdx.x, cb = blockIdx.y, t = threadIdx.x;
  const int c = cb * 16 + (t >> 4);
  const int e0 = (t & 15) * 8;
  float acc[8] = {0.f,0.f,0.f,0.f,0.f,0.f,0.f,0.f};
  for (int d = 0; d < DIMC; ++d) {
    float wq = q_pw[((size_t)(h * DIMC + d)) * DIMC + c];
    const float* gr = Gt + d * DIMC + e0;
    #pragma unroll
    for (int j = 0; j < 8; ++j) acc[j] += wq * gr[j];
  }
  float* out = WgF + ((size_t)h * DIMC + c) * DIMC + e0;
  #pragma unroll
  for (int j = 0; j < 8; ++j) out[j] = acc[j];
}

// COMPACT hi-only packing: Wpk table i=(p*8+h) at i*16384 (24 tables);
// Opk table h at h*16384 (8); Gpk table h at h*16384 (8). 40 blocks.
__global__ void k_pack(const float* __restrict__ q_pw, const float* __restrict__ k_pw,
                       const float* __restrict__ v_pw, const float* __restrict__ out_w,
                       const float* __restrict__ WgF,
                       short* __restrict__ Wpk, short* __restrict__ Opk,
                       short* __restrict__ Gpk) {
  const int blk = blockIdx.x, t = threadIdx.x;
  if (blk < 24) {
    const int p = blk / 8, h = blk & 7;
    const float* pw = p == 0 ? q_pw : p == 1 ? k_pw : v_pw;
    short* dst = Wpk + (size_t)(p * 8 + h) * 16384;
    for (int s = t; s < 2048; s += 256) {
      const int l = s & 63, kt = (s >> 6) >> 3, nt = (s >> 6) & 7;
      const int o = h * DIMC + nt * 16 + (l & 15);
      const int cb = kt * 32 + (l >> 4) * 8;
      #pragma unroll
      for (int j = 0; j < 8; ++j)
        dst[s * 8 + j] = f2bf(pw[(size_t)o * DIMC + cb + j]);
    }
  } else if (blk < 32) {
    const int h = blk - 24;
    short* dst = Opk + (size_t)h * 16384;
    for (int s = t; s < 2048; s += 256) {
      const int l = s & 63, mt = (s >> 6) >> 2, kt = (s >> 6) & 3;
      const int o = mt * 16 + (l & 15);
      const int ib = h * DIMC + kt * 32 + (l >> 4) * 8;
      #pragma unroll
      for (int j = 0; j < 8; ++j)
        dst[s * 8 + j] = f2bf(out_w[(size_t)o * (DIMC * HEADS) + ib + j]);
    }
  } else {
    const int h = blk - 32;
    const float* src = WgF + (size_t)h * 16384;
    short* dst = Gpk + (size_t)h * 16384;
    for (int s = t; s < 2048; s += 256) {
      const int l = s & 63, kt = (s >> 6) >> 3, nt = (s >> 6) & 7;
      const int cb = kt * 32 + (l >> 4) * 8, e = nt * 16 + (l & 15);
      #pragma unroll
      for (int j = 0; j < 8; ++j) dst[s * 8 + j] = f2bf(src[(size_t)(cb + j) * DIMC + e]);
    }
  }
}

// sum `splits` bf16 partial kat tiles, scale, pack frags. grid(64)
__global__ __launch_bounds__(256) void k_red(const short* __restrict__ part16,
                                             short* __restrict__ katpk, int splits) {
  __shared__ float sm[DIMC * DIMC];
  const int n = blockIdx.x, t = threadIdx.x;
  for (int i0 = t * 8; i0 < DIMC * DIMC; i0 += 256 * 8) {
    float a[8] = {0.f,0.f,0.f,0.f,0.f,0.f,0.f,0.f};
    for (int s8 = 0; s8 < splits; ++s8) {
      bf16x8 pv = *(const bf16x8*)&part16[((size_t)(s8 * NHEAD + n)) * 16384 + i0];
      #pragma unroll
      for (int j = 0; j < 8; ++j) a[j] += bf2f(pv[j]);
    }
    #pragma unroll
    for (int j = 0; j < 8; ++j) sm[i0 + j] = a[j] * SCALEF;
  }
  __syncthreads();
  short* dst = katpk + (size_t)n * 16384;
  for (int s = t; s < 2048; s += 256) {
    const int l = s & 63, kt = (s >> 6) >> 3, nt = (s >> 6) & 7;
    const int db = kt * 32 + (l >> 4) * 8, e = nt * 16 + (l & 15);
    #pragma unroll
    for (int j = 0; j < 8; ++j) dst[s * 8 + j] = f2bf(sm[(db + j) * DIMC + e]);
  }
}

// ---------------------------------------------------------------------------
// stage Y tiles: dwconv+BN for two projections -> swizzled bf16 LDS [64 x][128 c]
// ---------------------------------------------------------------------------
__device__ __forceinline__ void stage2(const float* __restrict__ x,
    const float* __restrict__ dwf, const float* __restrict__ bfl,
    int b, int xg0, int t, short* Y0, short* Y1, int p0, int p1)
{
  const int xl = t & 63, cg = t >> 6;
  const int xg = xg0 + xl;
  #pragma unroll
  for (int i = 0; i < 16; ++i) {
    const int c = 2 * (cg + 4 * i);
    float v0[2], v1[2];
    #pragma unroll
    for (int u = 0; u < 2; ++u) {
      const int cc = c + u;
      const float* xr = x + ((size_t)b * DIMC + cc) * XLEN + xg;
      float xm = (xg > 0) ? xr[-1] : 0.f;
      float xc = xr[0];
      float xp = (xg < XLEN - 1) ? xr[1] : 0.f;
      const float* d0 = dwf + (p0 * DIMC + cc) * 3;
      const float* d1 = dwf + (p1 * DIMC + cc) * 3;
      v0[u] = xm * d0[0] + xc * d0[1] + xp * d0[2] + bfl[p0 * DIMC + cc];
      v1[u] = xm * d1[0] + xc * d1[1] + xp * d1[2] + bfl[p1 * DIMC + cc];
    }
    const unsigned off = xl * 256 + ((c * 2) ^ ((xl & 7) << 4));
    *(unsigned*)((char*)Y0 + off) = pk2(v0[0], v0[1]);
    *(unsigned*)((char*)Y1 + off) = pk2(v1[0], v1[1]);
  }
}

// ---------------------------------------------------------------------------
// Phase 1: k_proj — Q/K GEMM (hi-only), softmax; dump qT/sT by slot.
// LDS 32 KB: QT aliases Yq (Abuf), ST aliases Yk (Bbuf); phase-separated by
// barriers (r10-validated pattern). grid (64, 8*BPL), 256 thr.
// ---------------------------------------------------------------------------
__global__ __launch_bounds__(256) void k_proj(
    const float* __restrict__ x, const float* __restrict__ dwf,
    const float* __restrict__ bfl, const short* __restrict__ Wpk,
    short* __restrict__ qT, short* __restrict__ sT, int b0)
{
  __shared__ __align__(16) short Abuf[TX * 128], Bbuf[TX * 128];  // 16 KB each
  short* Yq = Abuf;  short* QT = Abuf;   // aliased
  short* Yk = Bbuf;  short* ST = Bbuf;   // aliased
  const int t = threadIdx.x, w = t >> 6, l = t & 63;
  const int l15 = l & 15, lq = l >> 4;
  const int slot = blockIdx.y;
  const int b = b0 + (slot >> 3), h = slot & 7;
  const int x0 = blockIdx.x * TX;

  stage2(x, dwf, bfl, b, x0, t, Yq, Yk, 0, 1);
  __syncthreads();                       // b1: Y ready

  const short* WqHi = Wpk + (size_t)(0 * 8 + h) * 16384;
  const short* WkHi = Wpk + (size_t)(1 * 8 + h) * 16384;

  f32x4 qa[8];

  // ---- Q GEMM (hi only), register-prefetched; reads Yq own-wave rows ----
  #pragma unroll
  for (int j = 0; j < 8; ++j) qa[j] = {0.f, 0.f, 0.f, 0.f};
  {
    bf16x8 a0 = ldY(Yq, w * 16 + l15, 0 * 64 + lq * 16);
    bf16x8 a1 = ldY(Yq, w * 16 + l15, 1 * 64 + lq * 16);
    bf16x8 a2 = ldY(Yq, w * 16 + l15, 2 * 64 + lq * 16);
    bf16x8 a3 = ldY(Yq, w * 16 + l15, 3 * 64 + lq * 16);
    bf16x8 h0[8], h1[8];
    #pragma unroll
    for (int nt = 0; nt < 8; ++nt) h0[nt] = LDW(WqHi, 0, nt);
    #pragma unroll
    for (int nt = 0; nt < 8; ++nt) h1[nt] = LDW(WqHi, 1, nt);
    #pragma unroll
    for (int nt = 0; nt < 8; ++nt) qa[nt] = MFMA(a0, h0[nt], qa[nt]);
    #pragma unroll
    for (int nt = 0; nt < 8; ++nt) h0[nt] = LDW(WqHi, 2, nt);
    #pragma unroll
    for (int nt = 0; nt < 8; ++nt) qa[nt] = MFMA(a1, h1[nt], qa[nt]);
    #pragma unroll
    for (int nt = 0; nt < 8; ++nt) h1[nt] = LDW(WqHi, 3, nt);
    #pragma unroll
    for (int nt = 0; nt < 8; ++nt) qa[nt] = MFMA(a2, h0[nt], qa[nt]);
    #pragma unroll
    for (int nt = 0; nt < 8; ++nt) qa[nt] = MFMA(a3, h1[nt], qa[nt]);
  }
  __syncthreads();                       // b2: ALL waves' Yq reads done
  // QT write (over Yq region)
  #pragma unroll
  for (int nt = 0; nt < 8; ++nt) {
    const int d = nt * 16 + l15;
    #pragma unroll
    for (int rp = 0; rp < 2; ++rp) {
      const int x2 = w * 16 + lq * 4 + rp * 2;
      *(unsigned*)((char*)QT + d * 128 + ((x2 * 2) ^ ((d & 7) << 4))) =
          pk2(qa[nt][rp * 2], qa[nt][rp * 2 + 1]);
    }
  }

  // ---- K GEMM (hi only); reads Yk own-wave rows (Bbuf untouched) ----
  #pragma unroll
  for (int j = 0; j < 8; ++j) qa[j] = {0.f, 0.f, 0.f, 0.f};
  {
    bf16x8 a0 = ldY(Yk, w * 16 + l15, 0 * 64 + lq * 16);
    bf16x8 a1 = ldY(Yk, w * 16 + l15, 1 * 64 + lq * 16);
    bf16x8 a2 = ldY(Yk, w * 16 + l15, 2 * 64 + lq * 16);
    bf16x8 a3 = ldY(Yk, w * 16 + l15, 3 * 64 + lq * 16);
    bf16x8 h0[8], h1[8];
    #pragma unroll
    for (int nt = 0; nt < 8; ++nt) h0[nt] = LDW(WkHi, 0, nt);
    #pragma unroll
    for (int nt = 0; nt < 8; ++nt) h1[nt] = LDW(WkHi, 1, nt);
    #pragma unroll
    for (int nt = 0; nt < 8; ++nt) qa[nt] = MFMA(a0, h0[nt], qa[nt]);
    #pragma unroll
    for (int nt = 0; nt < 8; ++nt) h0[nt] = LDW(WkHi, 2, nt);
    #pragma unroll
    for (int nt = 0; nt < 8; ++nt) qa[nt] = MFMA(a1, h1[nt], qa[nt]);
    #pragma unroll
    for (int nt = 0; nt < 8; ++nt) h1[nt] = LDW(WkHi, 3, nt);
    #pragma unroll
    for (int nt = 0; nt < 8; ++nt) qa[nt] = MFMA(a2, h0[nt], qa[nt]);
    #pragma unroll
    for (int nt = 0; nt < 8; ++nt) qa[nt] = MFMA(a3, h1[nt], qa[nt]);
  }
  __syncthreads();                       // b3: ALL waves' Yk reads done

  // in-register row softmax over e
  float inv[4];
  #pragma unroll
  for (int r = 0; r < 4; ++r) {
    float m = qa[0][r];
    #pragma unroll
    for (int nt = 1; nt < 8; ++nt) m = fmaxf(m, qa[nt][r]);
    m = fmaxf(m, __shfl_xor(m, 1)); m = fmaxf(m, __shfl_xor(m, 2));
    m = fmaxf(m, __shfl_xor(m, 4)); m = fmaxf(m, __shfl_xor(m, 8));
    float s = 0.f;
    #pragma unroll
    for (int nt = 0; nt < 8; ++nt) { float e = __expf(qa[nt][r] - m); qa[nt][r] = e; s += e; }
    s += __shfl_xor(s, 1); s += __shfl_xor(s, 2); s += __shfl_xor(s, 4); s += __shfl_xor(s, 8);
    inv[r] = 1.f / s;
  }
  // ST write (over Yk region)
  #pragma unroll
  for (int nt = 0; nt < 8; ++nt) {
    const int e = nt * 16 + l15;
    #pragma unroll
    for (int rp = 0; rp < 2; ++rp) {
      const int x2 = w * 16 + lq * 4 + rp * 2;
      *(unsigned*)((char*)ST + e * 128 + ((x2 * 2) ^ ((e & 7) << 4))) =
          pk2(qa[nt][rp * 2] * inv[rp * 2], qa[nt][rp * 2 + 1] * inv[rp * 2 + 1]);
    }
  }
  __syncthreads();                       // b4: QT/ST complete

  // coalesced dump: thread t handles row r = t>>1, half = t&1 (64 B each)
  {
    const int r = t >> 1, half = t & 1;
    const size_t row = ((size_t)slot * DIMC + r) * XLEN + x0 + half * 32;
    #pragma unroll
    for (int i = 0; i < 4; ++i) {
      const int off = r * 128 + (((half * 64) + i * 16) ^ ((r & 7) << 4));
      *(int4*)(qT + row + i * 8) = *(const int4*)((const char*)QT + off);
      *(int4*)(sT + row + i * 8) = *(const int4*)((const char*)ST + off);
    }
  }
}

// ---------------------------------------------------------------------------
// Phase 2: k_katg — kat partial GEMM over x. grid (splits, 8*BPL, 8 eighths).
// slot = blockIdx.y indexes qT/sT; n = n0 + slot. SL = 16 e-rows (4 KB).
// ---------------------------------------------------------------------------
__global__ __launch_bounds__(256) void k_katg(
    const short* __restrict__ qT, const short* __restrict__ sT,
    short* __restrict__ part16, int n0)
{
  __shared__ __align__(16) short QL[128 * 128];   // 32 KB
  __shared__ __align__(16) short SL[16 * 128];    //  4 KB
  const int t = threadIdx.x, w = t >> 6, l = t & 63;
  const int l15 = l & 15, lq = l >> 4;
  const int slot = blockIdx.y, eq = blockIdx.z;   // eq in 0..7
  const int xspan = XLEN / gridDim.x;

  f32x4 ka[2];
  ka[0] = {0.f, 0.f, 0.f, 0.f};
  ka[1] = {0.f, 0.f, 0.f, 0.f};

  for (int ch = 0; ch < xspan / 128; ++ch) {
    const int xl0 = blockIdx.x * xspan + ch * 128;
    __syncthreads();
    #pragma unroll
    for (int R = 0; R < 8; ++R) {
      const int idx = R * 256 + t;
      const int d = idx >> 4, c = idx & 15;
      const size_t rb = (((size_t)slot * DIMC + d) * XLEN + xl0) * 2;
      *(int4*)((char*)QL + idx * 16) =
          *(const int4*)((const char*)qT + rb + ((c * 16) ^ ((d & 7) << 4)));
    }
    {
      const int idx = t;                          // 256 x 16 B = 4096 B exactly
      const int er = idx >> 4, c = idx & 15;
      const size_t rb = (((size_t)slot * DIMC + eq * 16 + er) * XLEN + xl0) * 2;
      *(int4*)((char*)SL + idx * 16) =
          *(const int4*)((const char*)sT + rb + ((c * 16) ^ ((er & 7) << 4)));
    }
    __syncthreads();
    #pragma unroll
    for (int kt2 = 0; kt2 < 4; ++kt2) {
      bf16x8 a0 = ldY(QL, w * 32 + l15,      kt2 * 64 + lq * 16);
      bf16x8 a1 = ldY(QL, w * 32 + 16 + l15, kt2 * 64 + lq * 16);
      bf16x8 bs = ldY(SL, l15, kt2 * 64 + lq * 16);
      ka[0] = MFMA(a0, bs, ka[0]);
      ka[1] = MFMA(a1, bs, ka[1]);
    }
  }
  short* dst = part16 + ((size_t)(blockIdx.x * NHEAD + n0 + slot)) * 16384;
  #pragma unroll
  for (int mt = 0; mt < 2; ++mt)
    #pragma unroll
    for (int r = 0; r < 4; ++r) {
      const int d = w * 32 + mt * 16 + lq * 4 + r;
      const int e = eq * 16 + l15;
      dst[d * DIMC + e] = f2bf(ka[mt][r]);
    }
}

// ---------------------------------------------------------------------------
// Phase 3: k_out11 — best (140 us): 4 GEMM phases/head, rotation
// V->Wg->Kp->OHi, 2 barriers/head. Compacted table offsets. grid (64, 8).
// ---------------------------------------------------------------------------
__global__ __launch_bounds__(256) void k_out11(
    const float* __restrict__ x, const float* __restrict__ dwf,
    const float* __restrict__ bfl, const short* __restrict__ Wpk,
    const short* __restrict__ Gpk, const short* __restrict__ katpk,
    const short* __restrict__ Opk, const float* __restrict__ c0,
    const float* __restrict__ outb, float* __restrict__ outp)
{
  __shared__ __align__(16) short Yq[TX * 128], Yv[TX * 128];
  __shared__ __align__(16) short Vx[TX * 128], Tn[TX * 128];
  const int t = threadIdx.x, w = t >> 6, l = t & 63;
  const int l15 = l & 15, lq = l >> 4;
  const int b = blockIdx.y;
  const int x0 = blockIdx.x * TX;

  f32x4 oacc[2][4];
  #pragma unroll
  for (int i = 0; i < 2; ++i)
    #pragma unroll
    for (int j = 0; j < 4; ++j) oacc[i][j] = {0.f, 0.f, 0.f, 0.f};
  float c0v[8];
  #pragma unroll
  for (int nt = 0; nt < 8; ++nt) c0v[nt] = c0[nt * 16 + l15];

  stage2(x, dwf, bfl, b, x0, t, Yq, Yv, 0, 2);
  __syncthreads();

  for (int h = 0; h < HEADS; ++h) {
    const int n = b * HEADS + h;
    const short* WvHi = Wpk + (size_t)(2 * 8 + h) * 16384;
    const short* Wg   = Gpk + (size_t)h * 16384;
    const short* Kp   = katpk + (size_t)n * 16384;
    const short* OHi  = Opk + (size_t)h * 16384;

    bf16x8 P0[8], P1[8], Q0[8], Q1[8];
    #pragma unroll
    for (int i = 0; i < 8; ++i) P0[i] = LDW(WvHi, 0, i);
    #pragma unroll
    for (int i = 0; i < 8; ++i) P1[i] = LDW(WvHi, 1, i);
    #pragma unroll
    for (int i = 0; i < 8; ++i) Q0[i] = LDW(WvHi, 2, i);
    #pragma unroll
    for (int i = 0; i < 8; ++i) Q1[i] = LDW(WvHi, 3, i);

    // ---- V GEMM (hi only; rotate -> Wg) ----
    f32x4 va[8];
    #pragma unroll
    for (int j = 0; j < 8; ++j) va[j] = {0.f, 0.f, 0.f, 0.f};
    {
      bf16x8 a = ldY(Yv, w * 16 + l15, 0 * 64 + lq * 16);
      #pragma unroll
      for (int nt = 0; nt < 8; ++nt) va[nt] = MFMA(a, P0[nt], va[nt]);
    }
    #pragma unroll
    for (int i = 0; i < 8; ++i) P0[i] = LDW(Wg, 0, i);
    {
      bf16x8 a = ldY(Yv, w * 16 + l15, 1 * 64 + lq * 16);
      #pragma unroll
      for (int nt = 0; nt < 8; ++nt) va[nt] = MFMA(a, P1[nt], va[nt]);
    }
    #pragma unroll
    for (int i = 0; i < 8; ++i) P1[i] = LDW(Wg, 1, i);
    {
      bf16x8 a = ldY(Yv, w * 16 + l15, 2 * 64 + lq * 16);
      #pragma unroll
      for (int nt = 0; nt < 8; ++nt) va[nt] = MFMA(a, Q0[nt], va[nt]);
    }
    #pragma unroll
    for (int i = 0; i < 8; ++i) Q0[i] = LDW(Wg, 2, i);
    {
      bf16x8 a = ldY(Yv, w * 16 + l15, 3 * 64 + lq * 16);
      #pragma unroll
      for (int nt = 0; nt < 8; ++nt) va[nt] = MFMA(a, Q1[nt], va[nt]);
    }
    #pragma unroll
    for (int i = 0; i < 8; ++i) Q1[i] = LDW(Wg, 3, i);

    // ---- write V[x][d] (own wave rows; va dies here) ----
    #pragma unroll
    for (int nt = 0; nt < 8; ++nt) {
      const int dd = nt * 16 + l15;
      #pragma unroll
      for (int r = 0; r < 4; ++r) {
        const int xr = w * 16 + lq * 4 + r;
        *(short*)((char*)Vx + xr * 256 + ((dd * 2) ^ ((xr & 7) << 4))) = f2bf(va[nt][r]);
      }
    }

    // ---- gate GEMM (rotate -> Kp) ----
    f32x4 ga[8];
    #pragma unroll
    for (int j = 0; j < 8; ++j) ga[j] = {0.f, 0.f, 0.f, 0.f};
    {
      bf16x8 a = ldY(Yq, w * 16 + l15, 0 * 64 + lq * 16);
      #pragma unroll
      for (int nt = 0; nt < 8; ++nt) ga[nt] = MFMA(a, P0[nt], ga[nt]);
    }
    #pragma unroll
    for (int i = 0; i < 8; ++i) P0[i] = LDW(Kp, 0, i);
    {
      bf16x8 a = ldY(Yq, w * 16 + l15, 1 * 64 + lq * 16);
      #pragma unroll
      for (int nt = 0; nt < 8; ++nt) ga[nt] = MFMA(a, P1[nt], ga[nt]);
    }
    #pragma unroll
    for (int i = 0; i < 8; ++i) P1[i] = LDW(Kp, 1, i);
    {
      bf16x8 a = ldY(Yq, w * 16 + l15, 2 * 64 + lq * 16);
      #pragma unroll
      for (int nt = 0; nt < 8; ++nt) ga[nt] = MFMA(a, Q0[nt], ga[nt]);
    }
    #pragma unroll
    for (int i = 0; i < 8; ++i) Q0[i] = LDW(Kp, 2, i);
    {
      bf16x8 a = ldY(Yq, w * 16 + l15, 3 * 64 + lq * 16);
      #pragma unroll
      for (int nt = 0; nt < 8; ++nt) ga[nt] = MFMA(a, Q1[nt], ga[nt]);
    }
    #pragma unroll
    for (int i = 0; i < 8; ++i) Q1[i] = LDW(Kp, 3, i);

    // ---- fold sigmoid into ga ----
    #pragma unroll
    for (int nt = 0; nt < 8; ++nt)
      #pragma unroll
      for (int r = 0; r < 4; ++r)
        ga[nt][r] = 1.f / (1.f + __expf(-(ga[nt][r] + c0v[nt])));

    // ---- KV GEMM (A = own Vx rows; rotate P0 -> OHi frags) ----
    f32x4 kv[8];
    #pragma unroll
    for (int j = 0; j < 8; ++j) kv[j] = {0.f, 0.f, 0.f, 0.f};
    {
      bf16x8 a = ldY(Vx, w * 16 + l15, 0 * 64 + lq * 16);
      #pragma unroll
      for (int nt = 0; nt < 8; ++nt) kv[nt] = MFMA(a, P0[nt], kv[nt]);
    }
    #pragma unroll
    for (int i = 0; i < 8; ++i)   // P0[mt*4+kt] = OHi slice (hi only)
      P0[i] = (*(const bf16x8*)&OHi[((((w * 2 + (i >> 2)) * 4 + (i & 3))) * 64 + l) * 8]);
    {
      bf16x8 a = ldY(Vx, w * 16 + l15, 1 * 64 + lq * 16);
      #pragma unroll
      for (int nt = 0; nt < 8; ++nt) kv[nt] = MFMA(a, P1[nt], kv[nt]);
    }
    {
      bf16x8 a = ldY(Vx, w * 16 + l15, 2 * 64 + lq * 16);
      #pragma unroll
      for (int nt = 0; nt < 8; ++nt) kv[nt] = MFMA(a, Q0[nt], kv[nt]);
    }
    {
      bf16x8 a = ldY(Vx, w * 16 + l15, 3 * 64 + lq * 16);
      #pragma unroll
      for (int nt = 0; nt < 8; ++nt) kv[nt] = MFMA(a, Q1[nt], kv[nt]);
    }

    // ---- combine: T = KV + sig * V (V re-read from own Vx rows) ----
    #pragma unroll
    for (int nt = 0; nt < 8; ++nt) {
      const int e = nt * 16 + l15;
      #pragma unroll
      for (int r = 0; r < 4; ++r) {
        const int xr = w * 16 + lq * 4 + r;
        float vv = bf2f(*(const short*)((const char*)Vx + xr * 256 + ((e * 2) ^ ((xr & 7) << 4))));
        *(short*)((char*)Tn + xr * 256 + ((e * 2) ^ ((xr & 7) << 4))) =
            f2bf(kv[nt][r] + ga[nt][r] * vv);
      }
    }
    __syncthreads();                                   // Tn complete

    // ---- out-projection accumulate from P0 (hi only) ----
    #pragma unroll
    for (int kt = 0; kt < 4; ++kt) {
      #pragma unroll
      for (int nt4 = 0; nt4 < 4; ++nt4) {
        bf16x8 bt = ldY(Tn, nt4 * 16 + l15, kt * 64 + lq * 16);
        oacc[0][nt4] = MFMA(P0[0 * 4 + kt], bt, oacc[0][nt4]);
        oacc[1][nt4] = MFMA(P0[1 * 4 + kt], bt, oacc[1][nt4]);
      }
    }
    __syncthreads();   // Tn reads done before next head's combine overwrites
  }
  #pragma unroll
  for (int mt = 0; mt < 2; ++mt) {
    #pragma unroll
    for (int nt4 = 0; nt4 < 4; ++nt4) {
      #pragma unroll
      for (int r = 0; r < 4; ++r) {
        const int o = w * 32 + mt * 16 + lq * 4 + r;
        const int xx = x0 + nt4 * 16 + l15;
        outp[((size_t)b * DIMC + o) * XLEN + xx] = oacc[mt][nt4][r] + outb[o];
      }
    }
  }
}

// ---------------------------------------------------------------------------
extern "C" void kernel_launch(void* const* d_in, const int* in_sizes, int n_in,
                              void* d_out, int out_size, void* d_ws, size_t ws_size,
                              hipStream_t stream) {
  (void)in_sizes; (void)n_in; (void)out_size;
  const float* x = (const float*)d_in[0];
  // q: 1..6, k: 7..12, v: 13..18 (dw,g,b,m,v,pw), gt: 19..24, out_w:25, out_b:26

  // compact layout (hi-only tables):
  char* ws = (char*)d_ws;
  short* katpk = (short*)(ws);                       // 2,097,152
  short* Wpk   = (short*)(ws + 2097152);             //   786,432 (24 tables)
  short* Opk   = (short*)(ws + 2883584);             //   262,144 (8 tables)
  short* Gpk   = (short*)(ws + 3145728);             //   262,144 (8 tables)
  float* Gt    = (float*)(ws + 3407872);             //    65,536
  float* c0    = (float*)(ws + 3473408);             //       512
  float* dwf   = (float*)(ws + 3473920);             //     4,608
  float* bfl   = (float*)(ws + 3478528);             //     1,536
  constexpr size_t BASE = 3480064;
  // WgF aliases the part16 region: written by k_wg, read by k_pack, both
  // strictly before any k_katg writes part16. 512 KB < min part16 (4 MB).
  float* WgF   = (float*)(ws + BASE);

  // BPL=2 (2 batches per chain launch) when ws allows; else r21-equivalent.
  int BPL, splits;
  if (ws_size >= (size_t)(BASE + 2u*2097152 + 2u*8388608 + 2u*8388608 + 16777216)) {
    // BASE + part16(2 splits=4MB) + qT(16MB) + sT(16MB) = 41,234,432
    BPL = 2; splits = 2;
  } else if (ws_size >= (size_t)(BASE + 8u*2097152 + 8388608 + 8388608)) {
    BPL = 1; splits = 8;                              // 37,034,496
  } else {
    BPL = 1; splits = 4;                              // 28,645,888 (proven fits)
  }
  short* part16 = (short*)(ws + BASE);
  short* qT = (short*)(ws + BASE + (size_t)splits * 2097152);
  short* sT = (short*)((char*)qT + (size_t)BPL * 8388608);
  if (ws_size < (size_t)28645888) return;   // loud-fail (below proven bound)

  k_prep1<<<4, 128, 0, stream>>>(
      (const float*)d_in[1],  (const float*)d_in[2],  (const float*)d_in[3],
      (const float*)d_in[4],  (const float*)d_in[5],
      (const float*)d_in[7],  (const float*)d_in[8],  (const float*)d_in[9],
      (const float*)d_in[10], (const float*)d_in[11],
      (const float*)d_in[13], (const float*)d_in[14], (const float*)d_in[15],
      (const float*)d_in[16], (const float*)d_in[17],
      (const float*)d_in[24], (const float*)d_in[19], (const float*)d_in[20],
      (const float*)d_in[21], (const float*)d_in[22], (const float*)d_in[23],
      dwf, bfl, Gt, c0);

  k_wg<<<dim3(8, 8), 256, 0, stream>>>((const float*)d_in[6], Gt, WgF);

  k_pack<<<40, 256, 0, stream>>>((const float*)d_in[6], (const float*)d_in[12],
                                 (const float*)d_in[18], (const float*)d_in[25],
                                 WgF, Wpk, Opk, Gpk);

  for (int b0 = 0; b0 < BATCH; b0 += BPL) {
    k_proj<<<dim3(XLEN / TX, HEADS * BPL), 256, 0, stream>>>(x, dwf, bfl, Wpk,
                                                             qT, sT, b0);
    k_katg<<<dim3(splits, HEADS * BPL, 8), 256, 0, stream>>>(qT, sT, part16,
                                                             b0 * HEADS);
  }
  k_red<<<NHEAD, 256, 0, stream>>>(part16, katpk, splits);
  k_out11<<<dim3(XLEN / TX, BATCH), 256, 0, stream>>>(x, dwf, bfl, Wpk, Gpk, katpk,
                                                      Opk, c0, (const float*)d_in[26],
                                                      (float*)d_out);
}